// Round 1
// baseline (2353.816 us; speedup 1.0000x reference)
//
#include <hip/hip_runtime.h>
#include <hip/hip_cooperative_groups.h>

namespace cg = cooperative_groups;

#define B_   32
#define L_   1024
#define LH_  512
#define CH_  1000
#define PRED_ 192
#define ITERS_ 50
#define KBL_ 16384   // B_*LH_

// ---------------- K1: per-(b,c) mean / std ----------------
__global__ __launch_bounds__(256) void k1_stats(const float* __restrict__ x,
                                                float* __restrict__ mean,
                                                float* __restrict__ sstd,
                                                float* __restrict__ inv) {
    int c = blockIdx.x * 256 + threadIdx.x;
    int b = blockIdx.y;
    if (c >= CH_) return;
    const float* xp = x + (size_t)b * L_ * CH_ + c;
    float s = 0.f, ss = 0.f;
    for (int l = 0; l < L_; ++l) {
        float v = xp[(size_t)l * CH_];
        s += v; ss += v * v;
    }
    float m = s * (1.0f / L_);
    float var = (ss - (float)L_ * m * m) * (1.0f / (L_ - 1)) + 1e-5f;
    float sd = sqrtf(var);
    mean[b * CH_ + c] = m;
    sstd[b * CH_ + c] = sd;
    inv[b * CH_ + c] = 1.0f / sd;
}

// ---------------- K2: build Z_L / Z_U in [n][b][lh] layout (transpose) ------
__global__ __launch_bounds__(256) void k2_build(const float* __restrict__ x,
                                                const float* __restrict__ mean,
                                                const float* __restrict__ inv,
                                                float* __restrict__ zL,
                                                float* __restrict__ zU) {
    __shared__ float Ls[32][33];
    __shared__ float Us[32][33];
    int tid = threadIdx.x;
    int tx = tid & 31, ty = tid >> 5;
    int n0 = blockIdx.x * 32;
    int lh0 = blockIdx.y * 32;
    int b = blockIdx.z;
    int n = n0 + tx;
    float m = 0.f, iv = 0.f;
    if (n < CH_) { m = mean[b * CH_ + n]; iv = inv[b * CH_ + n]; }
    for (int r = 0; r < 4; ++r) {
        int lh = lh0 + ty + 8 * r;
        float v0 = 0.f, v1 = 0.f;
        if (n < CH_) {
            v0 = x[((size_t)b * L_ + 2 * lh) * CH_ + n];
            v1 = x[((size_t)b * L_ + 2 * lh + 1) * CH_ + n];
        }
        float a = (v0 - m) * iv * 0.5f;
        float c2 = (v1 - m) * iv * 0.5f;
        Ls[ty + 8 * r][tx] = a + c2;
        Us[ty + 8 * r][tx] = a - c2;
    }
    __syncthreads();
    for (int r = 0; r < 4; ++r) {
        int nl = ty + 8 * r;
        int nn = n0 + nl;
        if (nn < CH_) {
            size_t dst = (size_t)nn * KBL_ + (size_t)b * LH_ + lh0 + tx;
            zL[dst] = Ls[tx][nl];
            zU[dst] = Us[tx][nl];
        }
    }
}

// ---------------- K3: Gram = Z_L * Z_L^T, K-split into 8 partials ----------
#define KSEG_ 2048
__global__ __launch_bounds__(256) void k3_gram(const float* __restrict__ zL,
                                               float* __restrict__ gpart) {
    __shared__ float As[32][132];
    __shared__ float Bs[32][132];
    int tid = threadIdx.x;
    int tx = tid & 15, ty = tid >> 4;
    int i0 = blockIdx.x * 128, j0 = blockIdx.y * 128;
    int kb = blockIdx.z * KSEG_;
    float acc[8][8];
#pragma unroll
    for (int a = 0; a < 8; ++a)
#pragma unroll
        for (int bq = 0; bq < 8; ++bq) acc[a][bq] = 0.f;

    for (int c = 0; c < KSEG_ / 32; ++c) {
        int k0 = kb + c * 32;
#pragma unroll
        for (int e = 0; e < 16; ++e) {
            int idx = e * 256 + tid;   // 0..4095
            int r = idx >> 5, kk = idx & 31;
            int ia = i0 + r, ja = j0 + r;
            As[kk][r] = (ia < CH_) ? zL[(size_t)ia * KBL_ + k0 + kk] : 0.f;
            Bs[kk][r] = (ja < CH_) ? zL[(size_t)ja * KBL_ + k0 + kk] : 0.f;
        }
        __syncthreads();
#pragma unroll
        for (int kk = 0; kk < 32; ++kk) {
            float4 a0 = *(const float4*)&As[kk][tx * 4];
            float4 a1 = *(const float4*)&As[kk][64 + tx * 4];
            float4 b0 = *(const float4*)&Bs[kk][ty * 4];
            float4 b1 = *(const float4*)&Bs[kk][64 + ty * 4];
            float av[8] = {a0.x,a0.y,a0.z,a0.w,a1.x,a1.y,a1.z,a1.w};
            float bv[8] = {b0.x,b0.y,b0.z,b0.w,b1.x,b1.y,b1.z,b1.w};
#pragma unroll
            for (int ri = 0; ri < 8; ++ri)
#pragma unroll
                for (int cj = 0; cj < 8; ++cj)
                    acc[ri][cj] += av[ri] * bv[cj];
        }
        __syncthreads();
    }
    float* gp = gpart + (size_t)blockIdx.z * 1000000;
#pragma unroll
    for (int ri = 0; ri < 8; ++ri) {
        int i = i0 + ((ri < 4) ? (tx * 4 + ri) : (64 + tx * 4 + (ri - 4)));
        if (i >= CH_) continue;
#pragma unroll
        for (int cj = 0; cj < 8; ++cj) {
            int j = j0 + ((cj < 4) ? (ty * 4 + cj) : (64 + ty * 4 + (cj - 4)));
            if (j < CH_) gp[(size_t)i * CH_ + j] = acc[ri][cj];
        }
    }
}

__global__ __launch_bounds__(256) void k3b_reduce(const float* __restrict__ gpart,
                                                  float* __restrict__ g) {
    size_t base = ((size_t)blockIdx.x * 256 + threadIdx.x) * 4;
    if (base >= 1000000) return;
    float4 s = {0.f, 0.f, 0.f, 0.f};
#pragma unroll
    for (int p = 0; p < 8; ++p) {
        float4 v = *(const float4*)(gpart + (size_t)p * 1000000 + base);
        s.x += v.x; s.y += v.y; s.z += v.z; s.w += v.w;
    }
    *(float4*)(g + base) = s;
}

// ---------------- K4: cooperative k-means on the Gram matrix ----------------
__global__ __launch_bounds__(256) void k4_kmeans(const float* __restrict__ g,
                                                 int* __restrict__ labels,
                                                 float* __restrict__ tg,
                                                 int* __restrict__ changed) {
    cg::grid_group grid = cg::this_grid();
    __shared__ int   labl[1000];
    __shared__ float sED[16][4];
    __shared__ int   plab[16];
    __shared__ int   cntS[4];
    __shared__ float red[3][256];

    int tid = threadIdx.x;
    int base = blockIdx.x * 16;
    int pt = tid >> 4, sub = tid & 15;
    int i = base + pt;
    bool own = (i < CH_);

    if (tid < 16) plab[tid] = -1;
    if (own && sub == 0) {
        sED[pt][0] = g[(size_t)i * CH_ + 0];
        sED[pt][1] = g[(size_t)i * CH_ + 1];
        sED[pt][2] = g[(size_t)i * CH_ + 2];
    }
    float cc0 = g[0], cc1 = g[1 * CH_ + 1], cc2 = g[2 * CH_ + 2];
    __syncthreads();

    for (int it = 1; it <= ITERS_; ++it) {
        // ---- assign (uses centroid state from previous update) ----
        if (own && sub == 0) {
            float d0 = cc0 - 2.f * sED[pt][0];
            float d1 = cc1 - 2.f * sED[pt][1];
            float d2 = cc2 - 2.f * sED[pt][2];
            int nl = 0; float dm = d0;
            if (d1 < dm) { dm = d1; nl = 1; }
            if (d2 < dm) { dm = d2; nl = 2; }
            if (nl != plab[pt]) atomicAdd(&changed[it], 1);
            plab[pt] = nl;
            labels[i] = nl;
        }
        grid.sync();

        // ---- load labels, count ----
        if (tid < 4) cntS[tid] = 0;
        __syncthreads();
        for (int idx = tid; idx < CH_; idx += 256) {
            int lb = labels[idx];
            labl[idx] = lb;
            atomicAdd(&cntS[lb], 1);
        }
        __syncthreads();

        // ---- t_ik = sum_{j: lab_j=k} G_ij  (16 lanes per point) ----
        float a0 = 0.f, a1 = 0.f, a2 = 0.f;
        if (own) {
            const float* gr = g + (size_t)i * CH_;
            for (int j = sub; j < CH_; j += 16) {
                float gv = gr[j];
                int lb = labl[j];
                a0 += (lb == 0) ? gv : 0.f;
                a1 += (lb == 1) ? gv : 0.f;
                a2 += (lb == 2) ? gv : 0.f;
            }
#pragma unroll
            for (int msk = 1; msk < 16; msk <<= 1) {
                a0 += __shfl_xor(a0, msk, 16);
                a1 += __shfl_xor(a1, msk, 16);
                a2 += __shfl_xor(a2, msk, 16);
            }
            if (sub == 0) {
                tg[i * 4 + 0] = a0; tg[i * 4 + 1] = a1; tg[i * 4 + 2] = a2;
            }
        }
        grid.sync();

        int chg = changed[it];
        int n0c = cntS[0], n1c = cntS[1], n2c = cntS[2];

        // ---- cc_k = (sum_{i in S_k} t_ik) / n_k^2, fixed-order reduce ----
        float p0 = 0.f, p1 = 0.f, p2 = 0.f;
        for (int idx = tid; idx < CH_; idx += 256) {
            int lb = labl[idx];
            float tv = tg[idx * 4 + lb];
            if (lb == 0) p0 += tv; else if (lb == 1) p1 += tv; else p2 += tv;
        }
        red[0][tid] = p0; red[1][tid] = p1; red[2][tid] = p2;
        __syncthreads();
        for (int off = 128; off > 0; off >>= 1) {
            if (tid < off) {
                red[0][tid] += red[0][tid + off];
                red[1][tid] += red[1][tid + off];
                red[2][tid] += red[2][tid + off];
            }
            __syncthreads();
        }
        float s0 = red[0][0], s1 = red[1][0], s2 = red[2][0];

        if (n0c > 0) cc0 = s0 / ((float)n0c * (float)n0c);
        if (n1c > 0) cc1 = s1 / ((float)n1c * (float)n1c);
        if (n2c > 0) cc2 = s2 / ((float)n2c * (float)n2c);
        if (own && sub == 0) {
            if (n0c > 0) sED[pt][0] = a0 / (float)n0c;
            if (n1c > 0) sED[pt][1] = a1 / (float)n1c;
            if (n2c > 0) sED[pt][2] = a2 / (float)n2c;
        }
        __syncthreads();

        if (chg == 0 && it > 1) break;   // converged: identical to running all iters
    }

    // ---- final assign (labels w.r.t. final centroids) ----
    if (own && sub == 0) {
        float d0 = cc0 - 2.f * sED[pt][0];
        float d1 = cc1 - 2.f * sED[pt][1];
        float d2 = cc2 - 2.f * sED[pt][2];
        int nl = 0; float dm = d0;
        if (d1 < dm) { dm = d1; nl = 1; }
        if (d2 < dm) { dm = d2; nl = 2; }
        labels[i] = nl;
    }
}

// ---------------- K5: per-channel GEMM (g + xu) + epilogue ------------------
__global__ __launch_bounds__(256) void k5_main(const float* __restrict__ zL,
                                               const float* __restrict__ zU,
                                               const float* __restrict__ Wg,
                                               const float* __restrict__ bg,
                                               const float* __restrict__ Wu,
                                               const float* __restrict__ bu,
                                               const int* __restrict__ labels,
                                               const float* __restrict__ mean,
                                               const float* __restrict__ sstd,
                                               float* __restrict__ out) {
    __shared__ float As[64][33];
    int n = blockIdx.x;
    int tid = threadIdx.x;
    int b = tid & 31, pg = tid >> 5;
    int lab = labels[n];
    const float* Wsel = Wg + (size_t)lab * PRED_ * LH_;
    float acc[24];
#pragma unroll
    for (int j = 0; j < 24; ++j) acc[j] = 0.f;

    for (int ch = 0; ch < 16; ++ch) {
        const float* src = (ch < 8) ? (zL + (size_t)n * KBL_) : (zU + (size_t)n * KBL_);
        int k0 = (ch & 7) * 64;
#pragma unroll
        for (int e = 0; e < 8; ++e) {
            int idx = e * 256 + tid;
            int bl = idx >> 6, kk = idx & 63;
            As[kk][bl] = src[(size_t)bl * LH_ + k0 + kk];
        }
        __syncthreads();
        const float* Wb = (ch < 8) ? (Wsel + k0) : (Wu + k0);
        for (int kk = 0; kk < 64; ++kk) {
            float a = As[kk][b];
#pragma unroll
            for (int j = 0; j < 24; ++j) {
                acc[j] += a * Wb[(size_t)(pg * 24 + j) * LH_ + kk];
            }
        }
        __syncthreads();
    }
    float sd = sstd[b * CH_ + n], m = mean[b * CH_ + n];
    const float* bgp = bg + lab * PRED_;
#pragma unroll
    for (int j = 0; j < 24; ++j) {
        int p = pg * 24 + j;
        float v = acc[j] + bgp[p] + bu[p];
        out[((size_t)b * PRED_ + p) * CH_ + n] = v * sd + m;
    }
}

extern "C" void kernel_launch(void* const* d_in, const int* in_sizes, int n_in,
                              void* d_out, int out_size, void* d_ws, size_t ws_size,
                              hipStream_t stream) {
    const float* x  = (const float*)d_in[0];
    const float* Wg = (const float*)d_in[4];
    const float* bg = (const float*)d_in[5];
    const float* Wu = (const float*)d_in[6];
    const float* bu = (const float*)d_in[7];
    float* out = (float*)d_out;
    (void)in_sizes; (void)n_in; (void)out_size; (void)ws_size;

    char* ws = (char*)d_ws;
    size_t off = 0;
    auto alloc = [&](size_t bytes) {
        void* p = ws + off;
        off = (off + bytes + 255) & ~(size_t)255;
        return p;
    };
    float* zL   = (float*)alloc((size_t)16384000 * 4);
    float* zU   = (float*)alloc((size_t)16384000 * 4);
    float* G    = (float*)alloc((size_t)1000000 * 4);
    float* Gp   = (float*)alloc((size_t)8000000 * 4);
    float* mean = (float*)alloc((size_t)32000 * 4);
    float* sstd = (float*)alloc((size_t)32000 * 4);
    float* inv  = (float*)alloc((size_t)32000 * 4);
    int*   labels  = (int*)alloc((size_t)1024 * 4);
    float* tg   = (float*)alloc((size_t)4096 * 4);
    int*   changed = (int*)alloc((size_t)64 * 4);

    hipMemsetAsync(changed, 0, 64 * 4, stream);
    k1_stats<<<dim3(4, 32), 256, 0, stream>>>(x, mean, sstd, inv);
    k2_build<<<dim3(32, 16, 32), 256, 0, stream>>>(x, mean, inv, zL, zU);
    k3_gram<<<dim3(8, 8, 8), 256, 0, stream>>>(zL, Gp);
    k3b_reduce<<<977, 256, 0, stream>>>(Gp, G);
    void* args[] = { (void*)&G, (void*)&labels, (void*)&tg, (void*)&changed };
    hipLaunchCooperativeKernel((void*)k4_kmeans, dim3(64), dim3(256), args, 0, stream);
    k5_main<<<1000, 256, 0, stream>>>(zL, zU, Wg, bg, Wu, bu, labels, mean, sstd, out);
}

// Round 2
// 1165.196 us; speedup vs baseline: 2.0201x; 2.0201x over previous
//
#include <hip/hip_runtime.h>
#include <hip/hip_bf16.h>
#include <hip/hip_cooperative_groups.h>

namespace cg = cooperative_groups;

#define B_   32
#define L_   1024
#define LH_  512
#define CH_  1000
#define PRED_ 192
#define ITERS_ 50
#define KBL_ 16384   // B_*LH_

typedef __attribute__((ext_vector_type(8))) short bf16x8;
typedef __attribute__((ext_vector_type(4))) float f32x4;

// ---------------- K1: per-(b,c) mean / std ----------------
__global__ __launch_bounds__(256) void k1_stats(const float* __restrict__ x,
                                                float* __restrict__ mean,
                                                float* __restrict__ sstd,
                                                float* __restrict__ inv) {
    int c = blockIdx.x * 256 + threadIdx.x;
    int b = blockIdx.y;
    if (c >= CH_) return;
    const float* xp = x + (size_t)b * L_ * CH_ + c;
    float s = 0.f, ss = 0.f;
    for (int l = 0; l < L_; ++l) {
        float v = xp[(size_t)l * CH_];
        s += v; ss += v * v;
    }
    float m = s * (1.0f / L_);
    float var = (ss - (float)L_ * m * m) * (1.0f / (L_ - 1)) + 1e-5f;
    float sd = sqrtf(var);
    mean[b * CH_ + c] = m;
    sstd[b * CH_ + c] = sd;
    inv[b * CH_ + c] = 1.0f / sd;
}

// ---------------- K2: build Z_L / Z_U in [n][b][lh] layout (+ bf16 split) ---
__global__ __launch_bounds__(256) void k2_build(const float* __restrict__ x,
                                                const float* __restrict__ mean,
                                                const float* __restrict__ inv,
                                                float* __restrict__ zL,
                                                float* __restrict__ zU,
                                                ushort* __restrict__ zH,
                                                ushort* __restrict__ zR) {
    __shared__ float Ls[32][33];
    __shared__ float Us[32][33];
    int tid = threadIdx.x;
    int tx = tid & 31, ty = tid >> 5;
    int n0 = blockIdx.x * 32;
    int lh0 = blockIdx.y * 32;
    int b = blockIdx.z;
    int n = n0 + tx;
    float m = 0.f, iv = 0.f;
    if (n < CH_) { m = mean[b * CH_ + n]; iv = inv[b * CH_ + n]; }
    for (int r = 0; r < 4; ++r) {
        int lh = lh0 + ty + 8 * r;
        float v0 = 0.f, v1 = 0.f;
        if (n < CH_) {
            v0 = x[((size_t)b * L_ + 2 * lh) * CH_ + n];
            v1 = x[((size_t)b * L_ + 2 * lh + 1) * CH_ + n];
        }
        float a = (v0 - m) * iv * 0.5f;
        float c2 = (v1 - m) * iv * 0.5f;
        Ls[ty + 8 * r][tx] = a + c2;
        Us[ty + 8 * r][tx] = a - c2;
    }
    __syncthreads();
    for (int r = 0; r < 4; ++r) {
        int nl = ty + 8 * r;
        int nn = n0 + nl;
        if (nn < CH_) {
            size_t dst = (size_t)nn * KBL_ + (size_t)b * LH_ + lh0 + tx;
            float lv = Ls[tx][nl];
            zL[dst] = lv;
            zU[dst] = Us[tx][nl];
            __hip_bfloat16 h = __float2bfloat16(lv);
            float hf = __bfloat162float(h);
            __hip_bfloat16 rr = __float2bfloat16(lv - hf);
            zH[dst] = *(ushort*)&h;
            zR[dst] = *(ushort*)&rr;
        }
    }
}

// ---------------- K3: Gram via split-bf16 MFMA, K-split into 16 partials ----
#define ZSPLIT_ 16
#define KSEG_   1024
#define NT_     (KSEG_ / 32)

__global__ __launch_bounds__(256) void k3_mfma(const ushort* __restrict__ zH,
                                               const ushort* __restrict__ zR,
                                               float* __restrict__ gpart) {
    __shared__ __align__(16) ushort AH[128][40];
    __shared__ __align__(16) ushort AR[128][40];
    __shared__ __align__(16) ushort BH[128][40];
    __shared__ __align__(16) ushort BR[128][40];

    int tid = threadIdx.x;
    int lane = tid & 63;
    int wid = tid >> 6;
    int wr = wid >> 1, wc = wid & 1;     // wave owns 64x64 at (wr*64, wc*64)
    int fr = lane & 15;                  // fragment row/col
    int g8 = lane >> 4;                  // k-group (8 bf16 each)

    int i0 = blockIdx.x * 128, j0 = blockIdx.y * 128;
    int kb = blockIdx.z * KSEG_;

    f32x4 acc[4][4];
#pragma unroll
    for (int m = 0; m < 4; ++m)
#pragma unroll
        for (int n = 0; n < 4; ++n) acc[m][n] = (f32x4){0.f, 0.f, 0.f, 0.f};

    int srow = tid >> 2;        // 0..63
    int sseg = tid & 3;         // 0..3 (8 bf16 = 16B segments)

    uint4 pv[8];
    auto stage_load = [&](int kt) {
        int k0 = kb + kt * 32;
#pragma unroll
        for (int s = 0; s < 8; ++s) {
            int tile = s >> 1, rep = s & 1;
            int row = srow + rep * 64;
            int grow = ((tile < 2) ? i0 : j0) + row;
            const ushort* src = (tile & 1) ? zR : zH;
            uint4 v = {0u, 0u, 0u, 0u};
            if (grow < CH_)
                v = *(const uint4*)(src + (size_t)grow * KBL_ + k0 + sseg * 8);
            pv[s] = v;
        }
    };
    auto stage_write = [&]() {
#pragma unroll
        for (int s = 0; s < 8; ++s) {
            int tile = s >> 1, rep = s & 1;
            int row = srow + rep * 64;
            ushort* dst = (tile == 0) ? &AH[row][sseg * 8]
                        : (tile == 1) ? &AR[row][sseg * 8]
                        : (tile == 2) ? &BH[row][sseg * 8]
                                      : &BR[row][sseg * 8];
            *(uint4*)dst = pv[s];
        }
    };

    stage_load(0);
    for (int t = 0; t < NT_; ++t) {
        __syncthreads();
        stage_write();
        __syncthreads();
        if (t + 1 < NT_) stage_load(t + 1);   // in-flight across MFMA phase

        bf16x8 ah[4], ar[4];
#pragma unroll
        for (int m = 0; m < 4; ++m) {
            ah[m] = *(const bf16x8*)&AH[wr * 64 + m * 16 + fr][g8 * 8];
            ar[m] = *(const bf16x8*)&AR[wr * 64 + m * 16 + fr][g8 * 8];
        }
#pragma unroll
        for (int n = 0; n < 4; ++n) {
            bf16x8 bh = *(const bf16x8*)&BH[wc * 64 + n * 16 + fr][g8 * 8];
            bf16x8 br = *(const bf16x8*)&BR[wc * 64 + n * 16 + fr][g8 * 8];
#pragma unroll
            for (int m = 0; m < 4; ++m) {
                acc[m][n] = __builtin_amdgcn_mfma_f32_16x16x32_bf16(ah[m], bh, acc[m][n], 0, 0, 0);
                acc[m][n] = __builtin_amdgcn_mfma_f32_16x16x32_bf16(ah[m], br, acc[m][n], 0, 0, 0);
                acc[m][n] = __builtin_amdgcn_mfma_f32_16x16x32_bf16(ar[m], bh, acc[m][n], 0, 0, 0);
            }
        }
    }

    float* gp = gpart + (size_t)blockIdx.z * 1000000;
#pragma unroll
    for (int m = 0; m < 4; ++m) {
        int orow_base = i0 + wr * 64 + m * 16 + g8 * 4;
#pragma unroll
        for (int n = 0; n < 4; ++n) {
            int ocol = j0 + wc * 64 + n * 16 + fr;
            if (ocol < CH_) {
#pragma unroll
                for (int q = 0; q < 4; ++q) {
                    int orow = orow_base + q;
                    if (orow < CH_) gp[(size_t)orow * CH_ + ocol] = acc[m][n][q];
                }
            }
        }
    }
}

__global__ __launch_bounds__(256) void k3b_reduce(const float* __restrict__ gpart,
                                                  float* __restrict__ g) {
    size_t base = ((size_t)blockIdx.x * 256 + threadIdx.x) * 4;
    if (base >= 1000000) return;
    float4 s = {0.f, 0.f, 0.f, 0.f};
#pragma unroll
    for (int p = 0; p < ZSPLIT_; ++p) {
        float4 v = *(const float4*)(gpart + (size_t)p * 1000000 + base);
        s.x += v.x; s.y += v.y; s.z += v.z; s.w += v.w;
    }
    *(float4*)(g + base) = s;
}

// ---------------- K4: cooperative k-means on the Gram matrix ----------------
__global__ __launch_bounds__(256) void k4_kmeans(const float* __restrict__ g,
                                                 int* __restrict__ labels,
                                                 float* __restrict__ tg,
                                                 int* __restrict__ changed) {
    cg::grid_group grid = cg::this_grid();
    __shared__ int   labl[1000];
    __shared__ float sED[16][4];
    __shared__ int   plab[16];
    __shared__ int   cntS[4];
    __shared__ float red[3][256];

    int tid = threadIdx.x;
    int base = blockIdx.x * 16;
    int pt = tid >> 4, sub = tid & 15;
    int i = base + pt;
    bool own = (i < CH_);

    if (tid < 16) plab[tid] = -1;
    if (own && sub == 0) {
        sED[pt][0] = g[(size_t)i * CH_ + 0];
        sED[pt][1] = g[(size_t)i * CH_ + 1];
        sED[pt][2] = g[(size_t)i * CH_ + 2];
    }
    float cc0 = g[0], cc1 = g[1 * CH_ + 1], cc2 = g[2 * CH_ + 2];
    __syncthreads();

    for (int it = 1; it <= ITERS_; ++it) {
        // ---- assign (uses centroid state from previous update) ----
        if (own && sub == 0) {
            float d0 = cc0 - 2.f * sED[pt][0];
            float d1 = cc1 - 2.f * sED[pt][1];
            float d2 = cc2 - 2.f * sED[pt][2];
            int nl = 0; float dm = d0;
            if (d1 < dm) { dm = d1; nl = 1; }
            if (d2 < dm) { dm = d2; nl = 2; }
            if (nl != plab[pt]) atomicAdd(&changed[it], 1);
            plab[pt] = nl;
            labels[i] = nl;
        }
        grid.sync();

        // ---- load labels, count ----
        if (tid < 4) cntS[tid] = 0;
        __syncthreads();
        for (int idx = tid; idx < CH_; idx += 256) {
            int lb = labels[idx];
            labl[idx] = lb;
            atomicAdd(&cntS[lb], 1);
        }
        __syncthreads();

        // ---- t_ik = sum_{j: lab_j=k} G_ij  (16 lanes per point) ----
        float a0 = 0.f, a1 = 0.f, a2 = 0.f;
        if (own) {
            const float* gr = g + (size_t)i * CH_;
            for (int j = sub; j < CH_; j += 16) {
                float gv = gr[j];
                int lb = labl[j];
                a0 += (lb == 0) ? gv : 0.f;
                a1 += (lb == 1) ? gv : 0.f;
                a2 += (lb == 2) ? gv : 0.f;
            }
#pragma unroll
            for (int msk = 1; msk < 16; msk <<= 1) {
                a0 += __shfl_xor(a0, msk, 16);
                a1 += __shfl_xor(a1, msk, 16);
                a2 += __shfl_xor(a2, msk, 16);
            }
            if (sub == 0) {
                tg[i * 4 + 0] = a0; tg[i * 4 + 1] = a1; tg[i * 4 + 2] = a2;
            }
        }
        grid.sync();

        int chg = changed[it];
        int n0c = cntS[0], n1c = cntS[1], n2c = cntS[2];

        // ---- cc_k = (sum_{i in S_k} t_ik) / n_k^2, fixed-order reduce ----
        float p0 = 0.f, p1 = 0.f, p2 = 0.f;
        for (int idx = tid; idx < CH_; idx += 256) {
            int lb = labl[idx];
            float tv = tg[idx * 4 + lb];
            if (lb == 0) p0 += tv; else if (lb == 1) p1 += tv; else p2 += tv;
        }
        red[0][tid] = p0; red[1][tid] = p1; red[2][tid] = p2;
        __syncthreads();
        for (int off = 128; off > 0; off >>= 1) {
            if (tid < off) {
                red[0][tid] += red[0][tid + off];
                red[1][tid] += red[1][tid + off];
                red[2][tid] += red[2][tid + off];
            }
            __syncthreads();
        }
        float s0 = red[0][0], s1 = red[1][0], s2 = red[2][0];

        if (n0c > 0) cc0 = s0 / ((float)n0c * (float)n0c);
        if (n1c > 0) cc1 = s1 / ((float)n1c * (float)n1c);
        if (n2c > 0) cc2 = s2 / ((float)n2c * (float)n2c);
        if (own && sub == 0) {
            if (n0c > 0) sED[pt][0] = a0 / (float)n0c;
            if (n1c > 0) sED[pt][1] = a1 / (float)n1c;
            if (n2c > 0) sED[pt][2] = a2 / (float)n2c;
        }
        __syncthreads();

        if (chg == 0 && it > 1) break;   // converged: identical to running all iters
    }

    // ---- final assign (labels w.r.t. final centroids) ----
    if (own && sub == 0) {
        float d0 = cc0 - 2.f * sED[pt][0];
        float d1 = cc1 - 2.f * sED[pt][1];
        float d2 = cc2 - 2.f * sED[pt][2];
        int nl = 0; float dm = d0;
        if (d1 < dm) { dm = d1; nl = 1; }
        if (d2 < dm) { dm = d2; nl = 2; }
        labels[i] = nl;
    }
}

// ---------------- K5: per-channel GEMM (g + xu) + epilogue ------------------
__global__ __launch_bounds__(256) void k5_main(const float* __restrict__ zL,
                                               const float* __restrict__ zU,
                                               const float* __restrict__ Wg,
                                               const float* __restrict__ bg,
                                               const float* __restrict__ Wu,
                                               const float* __restrict__ bu,
                                               const int* __restrict__ labels,
                                               const float* __restrict__ mean,
                                               const float* __restrict__ sstd,
                                               float* __restrict__ out) {
    __shared__ float As[64][33];
    int n = blockIdx.x;
    int tid = threadIdx.x;
    int b = tid & 31, pg = tid >> 5;
    int lab = labels[n];
    const float* Wsel = Wg + (size_t)lab * PRED_ * LH_;
    float acc[24];
#pragma unroll
    for (int j = 0; j < 24; ++j) acc[j] = 0.f;

    for (int ch = 0; ch < 16; ++ch) {
        const float* src = (ch < 8) ? (zL + (size_t)n * KBL_) : (zU + (size_t)n * KBL_);
        int k0 = (ch & 7) * 64;
#pragma unroll
        for (int e = 0; e < 8; ++e) {
            int idx = e * 256 + tid;
            int bl = idx >> 6, kk = idx & 63;
            As[kk][bl] = src[(size_t)bl * LH_ + k0 + kk];
        }
        __syncthreads();
        const float* Wb = (ch < 8) ? (Wsel + k0) : (Wu + k0);
        for (int kk = 0; kk < 64; ++kk) {
            float a = As[kk][b];
#pragma unroll
            for (int j = 0; j < 24; ++j) {
                acc[j] += a * Wb[(size_t)(pg * 24 + j) * LH_ + kk];
            }
        }
        __syncthreads();
    }
    float sd = sstd[b * CH_ + n], m = mean[b * CH_ + n];
    const float* bgp = bg + lab * PRED_;
#pragma unroll
    for (int j = 0; j < 24; ++j) {
        int p = pg * 24 + j;
        float v = acc[j] + bgp[p] + bu[p];
        out[((size_t)b * PRED_ + p) * CH_ + n] = v * sd + m;
    }
}

extern "C" void kernel_launch(void* const* d_in, const int* in_sizes, int n_in,
                              void* d_out, int out_size, void* d_ws, size_t ws_size,
                              hipStream_t stream) {
    const float* x  = (const float*)d_in[0];
    const float* Wg = (const float*)d_in[4];
    const float* bg = (const float*)d_in[5];
    const float* Wu = (const float*)d_in[6];
    const float* bu = (const float*)d_in[7];
    float* out = (float*)d_out;
    (void)in_sizes; (void)n_in; (void)out_size; (void)ws_size;

    char* ws = (char*)d_ws;
    size_t off = 0;
    auto alloc = [&](size_t bytes) {
        void* p = ws + off;
        off = (off + bytes + 255) & ~(size_t)255;
        return p;
    };
    float*  zL   = (float*)alloc((size_t)16384000 * 4);
    float*  zU   = (float*)alloc((size_t)16384000 * 4);
    ushort* zH   = (ushort*)alloc((size_t)16384000 * 2);
    ushort* zR   = (ushort*)alloc((size_t)16384000 * 2);
    float*  G    = (float*)alloc((size_t)1000000 * 4);
    float*  Gp   = (float*)alloc((size_t)ZSPLIT_ * 1000000 * 4);
    float*  mean = (float*)alloc((size_t)32000 * 4);
    float*  sstd = (float*)alloc((size_t)32000 * 4);
    float*  inv  = (float*)alloc((size_t)32000 * 4);
    int*    labels  = (int*)alloc((size_t)1024 * 4);
    float*  tg   = (float*)alloc((size_t)4096 * 4);
    int*    changed = (int*)alloc((size_t)64 * 4);

    hipMemsetAsync(changed, 0, 64 * 4, stream);
    k1_stats<<<dim3(4, 32), 256, 0, stream>>>(x, mean, sstd, inv);
    k2_build<<<dim3(32, 16, 32), 256, 0, stream>>>(x, mean, inv, zL, zU, zH, zR);
    k3_mfma<<<dim3(8, 8, ZSPLIT_), 256, 0, stream>>>(zH, zR, Gp);
    k3b_reduce<<<977, 256, 0, stream>>>(Gp, G);
    void* args[] = { (void*)&G, (void*)&labels, (void*)&tg, (void*)&changed };
    hipLaunchCooperativeKernel((void*)k4_kmeans, dim3(64), dim3(256), args, 0, stream);
    k5_main<<<1000, 256, 0, stream>>>(zL, zU, Wg, bg, Wu, bu, labels, mean, sstd, out);
}

// Round 3
// 539.175 us; speedup vs baseline: 4.3656x; 2.1611x over previous
//
#include <hip/hip_runtime.h>
#include <hip/hip_bf16.h>
#include <hip/hip_cooperative_groups.h>

namespace cg = cooperative_groups;

#define B_   32
#define L_   1024
#define LH_  512
#define CH_  1000
#define PRED_ 192
#define ITERS_ 50
#define KBL_ 16384   // B_*LH_
#define NCOL_ 32000  // CH_*B_
#define WROWS_ 896   // 576 Wg + 64 pad + 192 Wu + 64 pad

typedef __attribute__((ext_vector_type(8))) short bf16x8;
typedef __attribute__((ext_vector_type(4))) float f32x4;

// ---------------- K1: per-(b,c) mean / std (transposed [c][b] outputs) ------
__global__ __launch_bounds__(256) void k1_stats(const float* __restrict__ x,
                                                float* __restrict__ meanT,
                                                float* __restrict__ sstdT,
                                                float* __restrict__ invT) {
    int c = blockIdx.x * 256 + threadIdx.x;
    int b = blockIdx.y;
    if (c >= CH_) return;
    const float* xp = x + (size_t)b * L_ * CH_ + c;
    float s = 0.f, ss = 0.f;
    for (int l = 0; l < L_; ++l) {
        float v = xp[(size_t)l * CH_];
        s += v; ss += v * v;
    }
    float m = s * (1.0f / L_);
    float var = (ss - (float)L_ * m * m) * (1.0f / (L_ - 1)) + 1e-5f;
    float sd = sqrtf(var);
    meanT[c * B_ + b] = m;
    sstdT[c * B_ + b] = sd;
    invT[c * B_ + b] = 1.0f / sd;
}

// ---------------- K2: build bf16 z_L (split) + z_U in [n][b][lh] layout -----
__global__ __launch_bounds__(256) void k2_build(const float* __restrict__ x,
                                                const float* __restrict__ meanT,
                                                const float* __restrict__ invT,
                                                ushort* __restrict__ zLH,
                                                ushort* __restrict__ zLR,
                                                ushort* __restrict__ zUH) {
    __shared__ float Ls[32][33];
    __shared__ float Us[32][33];
    int tid = threadIdx.x;
    int tx = tid & 31, ty = tid >> 5;
    int n0 = blockIdx.x * 32;
    int lh0 = blockIdx.y * 32;
    int b = blockIdx.z;
    int n = n0 + tx;
    float m = 0.f, iv = 0.f;
    if (n < CH_) { m = meanT[n * B_ + b]; iv = invT[n * B_ + b]; }
    for (int r = 0; r < 4; ++r) {
        int lh = lh0 + ty + 8 * r;
        float v0 = 0.f, v1 = 0.f;
        if (n < CH_) {
            v0 = x[((size_t)b * L_ + 2 * lh) * CH_ + n];
            v1 = x[((size_t)b * L_ + 2 * lh + 1) * CH_ + n];
        }
        float a = (v0 - m) * iv * 0.5f;
        float c2 = (v1 - m) * iv * 0.5f;
        Ls[ty + 8 * r][tx] = a + c2;
        Us[ty + 8 * r][tx] = a - c2;
    }
    __syncthreads();
    for (int r = 0; r < 4; ++r) {
        int nl = ty + 8 * r;
        int nn = n0 + nl;
        if (nn < CH_) {
            size_t dst = (size_t)nn * KBL_ + (size_t)b * LH_ + lh0 + tx;
            float lv = Ls[tx][nl];
            float uv = Us[tx][nl];
            __hip_bfloat16 h = __float2bfloat16(lv);
            float hf = __bfloat162float(h);
            __hip_bfloat16 rr = __float2bfloat16(lv - hf);
            __hip_bfloat16 uh = __float2bfloat16(uv);
            zLH[dst] = *(ushort*)&h;
            zLR[dst] = *(ushort*)&rr;
            zUH[dst] = *(ushort*)&uh;
        }
    }
}

// ---------------- K0w: pack weights to bf16 [896][512] ----------------------
__global__ __launch_bounds__(256) void k0_wprep(const float* __restrict__ Wg,
                                                const float* __restrict__ Wu,
                                                ushort* __restrict__ WB) {
    int r = blockIdx.x;
    int tid = threadIdx.x;
#pragma unroll
    for (int i = 0; i < 2; ++i) {
        int l = i * 256 + tid;
        float w = 0.f;
        if (r < 576) w = Wg[(size_t)r * LH_ + l];
        else if (r >= 640 && r < 832) w = Wu[(size_t)(r - 640) * LH_ + l];
        __hip_bfloat16 h = __float2bfloat16(w);
        WB[(size_t)r * LH_ + l] = *(ushort*)&h;
    }
}

// ---------------- K3: Gram via split-bf16 MFMA, K-split into 16 partials ----
#define ZSPLIT_ 16
#define KSEG_   1024
#define NT_     (KSEG_ / 32)

__global__ __launch_bounds__(256) void k3_mfma(const ushort* __restrict__ zH,
                                               const ushort* __restrict__ zR,
                                               float* __restrict__ gpart) {
    __shared__ __align__(16) ushort AH[128][40];
    __shared__ __align__(16) ushort AR[128][40];
    __shared__ __align__(16) ushort BH[128][40];
    __shared__ __align__(16) ushort BR[128][40];

    int tid = threadIdx.x;
    int lane = tid & 63;
    int wid = tid >> 6;
    int wr = wid >> 1, wc = wid & 1;
    int fr = lane & 15;
    int g8 = lane >> 4;

    int i0 = blockIdx.x * 128, j0 = blockIdx.y * 128;
    int kb = blockIdx.z * KSEG_;

    f32x4 acc[4][4];
#pragma unroll
    for (int m = 0; m < 4; ++m)
#pragma unroll
        for (int n = 0; n < 4; ++n) acc[m][n] = (f32x4){0.f, 0.f, 0.f, 0.f};

    int srow = tid >> 2;
    int sseg = tid & 3;

    uint4 pv[8];
    auto stage_load = [&](int kt) {
        int k0 = kb + kt * 32;
#pragma unroll
        for (int s = 0; s < 8; ++s) {
            int tile = s >> 1, rep = s & 1;
            int row = srow + rep * 64;
            int grow = ((tile < 2) ? i0 : j0) + row;
            const ushort* src = (tile & 1) ? zR : zH;
            uint4 v = {0u, 0u, 0u, 0u};
            if (grow < CH_)
                v = *(const uint4*)(src + (size_t)grow * KBL_ + k0 + sseg * 8);
            pv[s] = v;
        }
    };
    auto stage_write = [&]() {
#pragma unroll
        for (int s = 0; s < 8; ++s) {
            int tile = s >> 1, rep = s & 1;
            int row = srow + rep * 64;
            ushort* dst = (tile == 0) ? &AH[row][sseg * 8]
                        : (tile == 1) ? &AR[row][sseg * 8]
                        : (tile == 2) ? &BH[row][sseg * 8]
                                      : &BR[row][sseg * 8];
            *(uint4*)dst = pv[s];
        }
    };

    stage_load(0);
    for (int t = 0; t < NT_; ++t) {
        __syncthreads();
        stage_write();
        __syncthreads();
        if (t + 1 < NT_) stage_load(t + 1);

        bf16x8 ah[4], ar[4];
#pragma unroll
        for (int m = 0; m < 4; ++m) {
            ah[m] = *(const bf16x8*)&AH[wr * 64 + m * 16 + fr][g8 * 8];
            ar[m] = *(const bf16x8*)&AR[wr * 64 + m * 16 + fr][g8 * 8];
        }
#pragma unroll
        for (int n = 0; n < 4; ++n) {
            bf16x8 bh = *(const bf16x8*)&BH[wc * 64 + n * 16 + fr][g8 * 8];
            bf16x8 br = *(const bf16x8*)&BR[wc * 64 + n * 16 + fr][g8 * 8];
#pragma unroll
            for (int m = 0; m < 4; ++m) {
                acc[m][n] = __builtin_amdgcn_mfma_f32_16x16x32_bf16(ah[m], bh, acc[m][n], 0, 0, 0);
                acc[m][n] = __builtin_amdgcn_mfma_f32_16x16x32_bf16(ah[m], br, acc[m][n], 0, 0, 0);
                acc[m][n] = __builtin_amdgcn_mfma_f32_16x16x32_bf16(ar[m], bh, acc[m][n], 0, 0, 0);
            }
        }
    }

    float* gp = gpart + (size_t)blockIdx.z * 1000000;
#pragma unroll
    for (int m = 0; m < 4; ++m) {
        int orow_base = i0 + wr * 64 + m * 16 + g8 * 4;
#pragma unroll
        for (int n = 0; n < 4; ++n) {
            int ocol = j0 + wc * 64 + n * 16 + fr;
            if (ocol < CH_) {
#pragma unroll
                for (int q = 0; q < 4; ++q) {
                    int orow = orow_base + q;
                    if (orow < CH_) gp[(size_t)orow * CH_ + ocol] = acc[m][n][q];
                }
            }
        }
    }
}

__global__ __launch_bounds__(256) void k3b_reduce(const float* __restrict__ gpart,
                                                  float* __restrict__ g) {
    size_t base = ((size_t)blockIdx.x * 256 + threadIdx.x) * 4;
    if (base >= 1000000) return;
    float4 s = {0.f, 0.f, 0.f, 0.f};
#pragma unroll
    for (int p = 0; p < ZSPLIT_; ++p) {
        float4 v = *(const float4*)(gpart + (size_t)p * 1000000 + base);
        s.x += v.x; s.y += v.y; s.z += v.z; s.w += v.w;
    }
    *(float4*)(g + base) = s;
}

// ---------------- K4: cooperative k-means on the Gram matrix ----------------
__global__ __launch_bounds__(256) void k4_kmeans(const float* __restrict__ g,
                                                 int* __restrict__ labels,
                                                 float* __restrict__ tg,
                                                 int* __restrict__ changed) {
    cg::grid_group grid = cg::this_grid();
    __shared__ int   labl[1000];
    __shared__ float sED[16][4];
    __shared__ int   plab[16];
    __shared__ int   cntS[4];
    __shared__ float red[3][256];

    int tid = threadIdx.x;
    int base = blockIdx.x * 16;
    int pt = tid >> 4, sub = tid & 15;
    int i = base + pt;
    bool own = (i < CH_);

    if (tid < 16) plab[tid] = -1;
    if (own && sub == 0) {
        sED[pt][0] = g[(size_t)i * CH_ + 0];
        sED[pt][1] = g[(size_t)i * CH_ + 1];
        sED[pt][2] = g[(size_t)i * CH_ + 2];
    }
    float cc0 = g[0], cc1 = g[1 * CH_ + 1], cc2 = g[2 * CH_ + 2];
    __syncthreads();

    for (int it = 1; it <= ITERS_; ++it) {
        if (own && sub == 0) {
            float d0 = cc0 - 2.f * sED[pt][0];
            float d1 = cc1 - 2.f * sED[pt][1];
            float d2 = cc2 - 2.f * sED[pt][2];
            int nl = 0; float dm = d0;
            if (d1 < dm) { dm = d1; nl = 1; }
            if (d2 < dm) { dm = d2; nl = 2; }
            if (nl != plab[pt]) atomicAdd(&changed[it], 1);
            plab[pt] = nl;
            labels[i] = nl;
        }
        grid.sync();

        if (tid < 4) cntS[tid] = 0;
        __syncthreads();
        for (int idx = tid; idx < CH_; idx += 256) {
            int lb = labels[idx];
            labl[idx] = lb;
            atomicAdd(&cntS[lb], 1);
        }
        __syncthreads();

        float a0 = 0.f, a1 = 0.f, a2 = 0.f;
        if (own) {
            const float* gr = g + (size_t)i * CH_;
            for (int j = sub; j < CH_; j += 16) {
                float gv = gr[j];
                int lb = labl[j];
                a0 += (lb == 0) ? gv : 0.f;
                a1 += (lb == 1) ? gv : 0.f;
                a2 += (lb == 2) ? gv : 0.f;
            }
#pragma unroll
            for (int msk = 1; msk < 16; msk <<= 1) {
                a0 += __shfl_xor(a0, msk, 16);
                a1 += __shfl_xor(a1, msk, 16);
                a2 += __shfl_xor(a2, msk, 16);
            }
            if (sub == 0) {
                tg[i * 4 + 0] = a0; tg[i * 4 + 1] = a1; tg[i * 4 + 2] = a2;
            }
        }
        grid.sync();

        int chg = changed[it];
        int n0c = cntS[0], n1c = cntS[1], n2c = cntS[2];

        float p0 = 0.f, p1 = 0.f, p2 = 0.f;
        for (int idx = tid; idx < CH_; idx += 256) {
            int lb = labl[idx];
            float tv = tg[idx * 4 + lb];
            if (lb == 0) p0 += tv; else if (lb == 1) p1 += tv; else p2 += tv;
        }
        red[0][tid] = p0; red[1][tid] = p1; red[2][tid] = p2;
        __syncthreads();
        for (int off = 128; off > 0; off >>= 1) {
            if (tid < off) {
                red[0][tid] += red[0][tid + off];
                red[1][tid] += red[1][tid + off];
                red[2][tid] += red[2][tid + off];
            }
            __syncthreads();
        }
        float s0 = red[0][0], s1 = red[1][0], s2 = red[2][0];

        if (n0c > 0) cc0 = s0 / ((float)n0c * (float)n0c);
        if (n1c > 0) cc1 = s1 / ((float)n1c * (float)n1c);
        if (n2c > 0) cc2 = s2 / ((float)n2c * (float)n2c);
        if (own && sub == 0) {
            if (n0c > 0) sED[pt][0] = a0 / (float)n0c;
            if (n1c > 0) sED[pt][1] = a1 / (float)n1c;
            if (n2c > 0) sED[pt][2] = a2 / (float)n2c;
        }
        __syncthreads();

        if (chg == 0 && it > 1) break;
    }

    if (own && sub == 0) {
        float d0 = cc0 - 2.f * sED[pt][0];
        float d1 = cc1 - 2.f * sED[pt][1];
        float d2 = cc2 - 2.f * sED[pt][2];
        int nl = 0; float dm = d0;
        if (d1 < dm) { dm = d1; nl = 1; }
        if (d2 < dm) { dm = d2; nl = 2; }
        labels[i] = nl;
    }
}

// ---------------- K5: dense bf16 GEMM  U[896 x 32000] = WB * Z^T ------------
__global__ __launch_bounds__(256) void k5_gemm(const ushort* __restrict__ zLH,
                                               const ushort* __restrict__ zUH,
                                               const ushort* __restrict__ WB,
                                               float* __restrict__ U) {
    __shared__ __align__(16) ushort AW[128][40];
    __shared__ __align__(16) ushort BZ[128][40];

    int tid = threadIdx.x;
    int lane = tid & 63, wid = tid >> 6;
    int wr = wid >> 1, wc = wid & 1;
    int fr = lane & 15, g8 = lane >> 4;
    int mt = blockIdx.x, nt = blockIdx.y;
    const ushort* zbuf = (mt < 5) ? zLH : zUH;
    int r0 = mt * 128;
    int c0 = nt * 128;

    f32x4 acc[4][4];
#pragma unroll
    for (int m = 0; m < 4; ++m)
#pragma unroll
        for (int n = 0; n < 4; ++n) acc[m][n] = (f32x4){0.f, 0.f, 0.f, 0.f};

    int srow = tid >> 2, sseg = tid & 3;
    uint4 pa[2], pb[2];
    auto stage_load = [&](int kt) {
        int k0 = kt * 32;
#pragma unroll
        for (int rep = 0; rep < 2; ++rep) {
            int r = srow + rep * 64;
            pa[rep] = *(const uint4*)(WB + (size_t)(r0 + r) * LH_ + k0 + sseg * 8);
            int C = c0 + r;
            int n = C >> 5, b = C & 31;
            pb[rep] = *(const uint4*)(zbuf + (size_t)n * KBL_ + (size_t)b * LH_ + k0 + sseg * 8);
        }
    };
    auto stage_write = [&]() {
#pragma unroll
        for (int rep = 0; rep < 2; ++rep) {
            *(uint4*)&AW[srow + rep * 64][sseg * 8] = pa[rep];
            *(uint4*)&BZ[srow + rep * 64][sseg * 8] = pb[rep];
        }
    };

    stage_load(0);
    for (int t = 0; t < 16; ++t) {
        __syncthreads();
        stage_write();
        __syncthreads();
        if (t + 1 < 16) stage_load(t + 1);

        bf16x8 a[4];
#pragma unroll
        for (int m = 0; m < 4; ++m)
            a[m] = *(const bf16x8*)&AW[wr * 64 + m * 16 + fr][g8 * 8];
#pragma unroll
        for (int n = 0; n < 4; ++n) {
            bf16x8 bv = *(const bf16x8*)&BZ[wc * 64 + n * 16 + fr][g8 * 8];
#pragma unroll
            for (int m = 0; m < 4; ++m)
                acc[m][n] = __builtin_amdgcn_mfma_f32_16x16x32_bf16(a[m], bv, acc[m][n], 0, 0, 0);
        }
    }

#pragma unroll
    for (int m = 0; m < 4; ++m) {
        int row_base = r0 + wr * 64 + m * 16 + g8 * 4;
#pragma unroll
        for (int n = 0; n < 4; ++n) {
            int col = c0 + wc * 64 + n * 16 + fr;
#pragma unroll
            for (int q = 0; q < 4; ++q)
                U[(size_t)(row_base + q) * NCOL_ + col] = acc[m][n][q];
        }
    }
}

// ---------------- K6: gather-epilogue + denorm + transpose ------------------
__global__ __launch_bounds__(256) void k6_epi(const float* __restrict__ U,
                                              const float* __restrict__ bg,
                                              const float* __restrict__ bu,
                                              const int* __restrict__ labels,
                                              const float* __restrict__ meanT,
                                              const float* __restrict__ sstdT,
                                              float* __restrict__ out) {
    __shared__ float T[64][33];
    int p = blockIdx.y;
    int n0 = blockIdx.x * 64;
    int tid = threadIdx.x;
    float bup = bu[p];
#pragma unroll
    for (int i = 0; i < 8; ++i) {
        int idx = i * 256 + tid;
        int nl = idx >> 5, b = idx & 31;
        int n = n0 + nl;
        if (n < CH_) {
            int lab = labels[n];
            float gv = U[(size_t)(lab * PRED_ + p) * NCOL_ + n * B_ + b];
            float uv = U[(size_t)(640 + p) * NCOL_ + n * B_ + b];
            float v = gv + uv + bg[lab * PRED_ + p] + bup;
            T[nl][b] = v * sstdT[n * B_ + b] + meanT[n * B_ + b];
        }
    }
    __syncthreads();
#pragma unroll
    for (int j = 0; j < 8; ++j) {
        int b = j * 4 + (tid >> 6);
        int nl = tid & 63;
        int n = n0 + nl;
        if (n < CH_) out[((size_t)b * PRED_ + p) * CH_ + n] = T[nl][b];
    }
}

extern "C" void kernel_launch(void* const* d_in, const int* in_sizes, int n_in,
                              void* d_out, int out_size, void* d_ws, size_t ws_size,
                              hipStream_t stream) {
    const float* x  = (const float*)d_in[0];
    const float* Wg = (const float*)d_in[4];
    const float* bg = (const float*)d_in[5];
    const float* Wu = (const float*)d_in[6];
    const float* bu = (const float*)d_in[7];
    float* out = (float*)d_out;
    (void)in_sizes; (void)n_in; (void)out_size; (void)ws_size;

    char* ws = (char*)d_ws;
    size_t off = 0;
    auto alloc = [&](size_t bytes) {
        void* p = ws + off;
        off = (off + bytes + 255) & ~(size_t)255;
        return p;
    };
    ushort* zLH  = (ushort*)alloc((size_t)16384000 * 2);
    ushort* zLR  = (ushort*)alloc((size_t)16384000 * 2);
    ushort* zUH  = (ushort*)alloc((size_t)16384000 * 2);
    float*  G    = (float*)alloc((size_t)1000000 * 4);
    ushort* WB   = (ushort*)alloc((size_t)WROWS_ * LH_ * 2);
    float*  meanT = (float*)alloc((size_t)32000 * 4);
    float*  sstdT = (float*)alloc((size_t)32000 * 4);
    float*  invT  = (float*)alloc((size_t)32000 * 4);
    int*    labels  = (int*)alloc((size_t)1024 * 4);
    float*  tg   = (float*)alloc((size_t)4096 * 4);
    int*    changed = (int*)alloc((size_t)64 * 4);
    // union region: Gp (64 MB, dead after k3b) and U (114.7 MB, born in k5_gemm)
    char* unionBase = (char*)alloc((size_t)WROWS_ * NCOL_ * 4);
    float* Gp = (float*)unionBase;
    float* U  = (float*)unionBase;

    hipMemsetAsync(changed, 0, 64 * 4, stream);
    k1_stats<<<dim3(4, 32), 256, 0, stream>>>(x, meanT, sstdT, invT);
    k2_build<<<dim3(32, 16, 32), 256, 0, stream>>>(x, meanT, invT, zLH, zLR, zUH);
    k0_wprep<<<WROWS_, 256, 0, stream>>>(Wg, Wu, WB);
    k3_mfma<<<dim3(8, 8, ZSPLIT_), 256, 0, stream>>>(zLH, zLR, Gp);
    k3b_reduce<<<977, 256, 0, stream>>>(Gp, G);
    void* args[] = { (void*)&G, (void*)&labels, (void*)&tg, (void*)&changed };
    hipLaunchCooperativeKernel((void*)k4_kmeans, dim3(64), dim3(256), args, 0, stream);
    k5_gemm<<<dim3(7, 250), 256, 0, stream>>>(zLH, zUH, WB, U);
    k6_epi<<<dim3(16, 192), 256, 0, stream>>>(U, bg, bu, labels, meanT, sstdT, out);
}

// Round 4
// 408.815 us; speedup vs baseline: 5.7577x; 1.3189x over previous
//
#include <hip/hip_runtime.h>
#include <hip/hip_bf16.h>
#include <hip/hip_cooperative_groups.h>

namespace cg = cooperative_groups;

#define B_   32
#define L_   1024
#define LH_  512
#define CH_  1000
#define PRED_ 192
#define ITERS_ 50
#define KBL_ 16384   // B_*LH_
#define SLOTS_ 1012
#define NTILES_ 253

typedef __attribute__((ext_vector_type(8))) short bf16x8;
typedef __attribute__((ext_vector_type(4))) float f32x4;

// ---------------- K1: per-(b,c) mean / std (transposed [c][b] outputs) ------
__global__ __launch_bounds__(256) void k1_stats(const float* __restrict__ x,
                                                float* __restrict__ meanT,
                                                float* __restrict__ sstdT,
                                                float* __restrict__ invT) {
    int c = blockIdx.x * 256 + threadIdx.x;
    int b = blockIdx.y;
    if (c >= CH_) return;
    const float* xp = x + (size_t)b * L_ * CH_ + c;
    float s = 0.f, ss = 0.f;
    for (int l = 0; l < L_; ++l) {
        float v = xp[(size_t)l * CH_];
        s += v; ss += v * v;
    }
    float m = s * (1.0f / L_);
    float var = (ss - (float)L_ * m * m) * (1.0f / (L_ - 1)) + 1e-5f;
    float sd = sqrtf(var);
    meanT[c * B_ + b] = m;
    sstdT[c * B_ + b] = sd;
    invT[c * B_ + b] = 1.0f / sd;
}

// ---------------- K2: build bf16 z_L (split) + z_U in [n][b][lh] layout -----
__global__ __launch_bounds__(256) void k2_build(const float* __restrict__ x,
                                                const float* __restrict__ meanT,
                                                const float* __restrict__ invT,
                                                ushort* __restrict__ zLH,
                                                ushort* __restrict__ zLR,
                                                ushort* __restrict__ zUH) {
    __shared__ float Ls[32][33];
    __shared__ float Us[32][33];
    int tid = threadIdx.x;
    int tx = tid & 31, ty = tid >> 5;
    int n0 = blockIdx.x * 32;
    int lh0 = blockIdx.y * 32;
    int b = blockIdx.z;
    int n = n0 + tx;
    float m = 0.f, iv = 0.f;
    if (n < CH_) { m = meanT[n * B_ + b]; iv = invT[n * B_ + b]; }
    for (int r = 0; r < 4; ++r) {
        int lh = lh0 + ty + 8 * r;
        float v0 = 0.f, v1 = 0.f;
        if (n < CH_) {
            v0 = x[((size_t)b * L_ + 2 * lh) * CH_ + n];
            v1 = x[((size_t)b * L_ + 2 * lh + 1) * CH_ + n];
        }
        float a = (v0 - m) * iv * 0.5f;
        float c2 = (v1 - m) * iv * 0.5f;
        Ls[ty + 8 * r][tx] = a + c2;
        Us[ty + 8 * r][tx] = a - c2;
    }
    __syncthreads();
    for (int r = 0; r < 4; ++r) {
        int nl = ty + 8 * r;
        int nn = n0 + nl;
        if (nn < CH_) {
            size_t dst = (size_t)nn * KBL_ + (size_t)b * LH_ + lh0 + tx;
            float lv = Ls[tx][nl];
            float uv = Us[tx][nl];
            __hip_bfloat16 h = __float2bfloat16(lv);
            float hf = __bfloat162float(h);
            __hip_bfloat16 rr = __float2bfloat16(lv - hf);
            __hip_bfloat16 uh = __float2bfloat16(uv);
            zLH[dst] = *(ushort*)&h;
            zLR[dst] = *(ushort*)&rr;
            zUH[dst] = *(ushort*)&uh;
        }
    }
}

// ---------------- K0w: stacked weights WB2[lab][192][1024] = [Wg[lab]|Wu] ---
__global__ __launch_bounds__(256) void k0_wprep(const float* __restrict__ Wg,
                                                const float* __restrict__ Wu,
                                                ushort* __restrict__ WB2) {
    int r = blockIdx.x;          // 0..575 = lab*192+p
    int p = r % PRED_;
    int tid = threadIdx.x;
#pragma unroll
    for (int i = 0; i < 4; ++i) {
        int k = i * 256 + tid;   // 0..1023
        float w = (k < 512) ? Wg[(size_t)r * LH_ + k]
                            : Wu[(size_t)p * LH_ + (k - 512)];
        __hip_bfloat16 h = __float2bfloat16(w);
        WB2[(size_t)r * 1024 + k] = *(ushort*)&h;
    }
}

// ---------------- K3: Gram via split-bf16 MFMA, K-split into 16 partials ----
#define ZSPLIT_ 16
#define KSEG_   1024
#define NT_     (KSEG_ / 32)

__global__ __launch_bounds__(256) void k3_mfma(const ushort* __restrict__ zH,
                                               const ushort* __restrict__ zR,
                                               float* __restrict__ gpart) {
    __shared__ __align__(16) ushort AH[128][40];
    __shared__ __align__(16) ushort AR[128][40];
    __shared__ __align__(16) ushort BH[128][40];
    __shared__ __align__(16) ushort BR[128][40];

    int tid = threadIdx.x;
    int lane = tid & 63;
    int wid = tid >> 6;
    int wr = wid >> 1, wc = wid & 1;
    int fr = lane & 15;
    int g8 = lane >> 4;

    int i0 = blockIdx.x * 128, j0 = blockIdx.y * 128;
    int kb = blockIdx.z * KSEG_;

    f32x4 acc[4][4];
#pragma unroll
    for (int m = 0; m < 4; ++m)
#pragma unroll
        for (int n = 0; n < 4; ++n) acc[m][n] = (f32x4){0.f, 0.f, 0.f, 0.f};

    int srow = tid >> 2;
    int sseg = tid & 3;

    uint4 pv[8];
    auto stage_load = [&](int kt) {
        int k0 = kb + kt * 32;
#pragma unroll
        for (int s = 0; s < 8; ++s) {
            int tile = s >> 1, rep = s & 1;
            int row = srow + rep * 64;
            int grow = ((tile < 2) ? i0 : j0) + row;
            const ushort* src = (tile & 1) ? zR : zH;
            uint4 v = {0u, 0u, 0u, 0u};
            if (grow < CH_)
                v = *(const uint4*)(src + (size_t)grow * KBL_ + k0 + sseg * 8);
            pv[s] = v;
        }
    };
    auto stage_write = [&]() {
#pragma unroll
        for (int s = 0; s < 8; ++s) {
            int tile = s >> 1, rep = s & 1;
            int row = srow + rep * 64;
            ushort* dst = (tile == 0) ? &AH[row][sseg * 8]
                        : (tile == 1) ? &AR[row][sseg * 8]
                        : (tile == 2) ? &BH[row][sseg * 8]
                                      : &BR[row][sseg * 8];
            *(uint4*)dst = pv[s];
        }
    };

    stage_load(0);
    for (int t = 0; t < NT_; ++t) {
        __syncthreads();
        stage_write();
        __syncthreads();
        if (t + 1 < NT_) stage_load(t + 1);

        bf16x8 ah[4], ar[4];
#pragma unroll
        for (int m = 0; m < 4; ++m) {
            ah[m] = *(const bf16x8*)&AH[wr * 64 + m * 16 + fr][g8 * 8];
            ar[m] = *(const bf16x8*)&AR[wr * 64 + m * 16 + fr][g8 * 8];
        }
#pragma unroll
        for (int n = 0; n < 4; ++n) {
            bf16x8 bh = *(const bf16x8*)&BH[wc * 64 + n * 16 + fr][g8 * 8];
            bf16x8 br = *(const bf16x8*)&BR[wc * 64 + n * 16 + fr][g8 * 8];
#pragma unroll
            for (int m = 0; m < 4; ++m) {
                acc[m][n] = __builtin_amdgcn_mfma_f32_16x16x32_bf16(ah[m], bh, acc[m][n], 0, 0, 0);
                acc[m][n] = __builtin_amdgcn_mfma_f32_16x16x32_bf16(ah[m], br, acc[m][n], 0, 0, 0);
                acc[m][n] = __builtin_amdgcn_mfma_f32_16x16x32_bf16(ar[m], bh, acc[m][n], 0, 0, 0);
            }
        }
    }

    float* gp = gpart + (size_t)blockIdx.z * 1000000;
#pragma unroll
    for (int m = 0; m < 4; ++m) {
        int orow_base = i0 + wr * 64 + m * 16 + g8 * 4;
#pragma unroll
        for (int n = 0; n < 4; ++n) {
            int ocol = j0 + wc * 64 + n * 16 + fr;
            if (ocol < CH_) {
#pragma unroll
                for (int q = 0; q < 4; ++q) {
                    int orow = orow_base + q;
                    if (orow < CH_) gp[(size_t)orow * CH_ + ocol] = acc[m][n][q];
                }
            }
        }
    }
}

__global__ __launch_bounds__(256) void k3b_reduce(const float* __restrict__ gpart,
                                                  float* __restrict__ g) {
    size_t base = ((size_t)blockIdx.x * 256 + threadIdx.x) * 4;
    if (base >= 1000000) return;
    float4 s = {0.f, 0.f, 0.f, 0.f};
#pragma unroll
    for (int p = 0; p < ZSPLIT_; ++p) {
        float4 v = *(const float4*)(gpart + (size_t)p * 1000000 + base);
        s.x += v.x; s.y += v.y; s.z += v.z; s.w += v.w;
    }
    *(float4*)(g + base) = s;
}

// ---------------- K4: cooperative k-means on the Gram matrix ----------------
__global__ __launch_bounds__(256) void k4_kmeans(const float* __restrict__ g,
                                                 int* __restrict__ labels,
                                                 float* __restrict__ tg,
                                                 int* __restrict__ changed) {
    cg::grid_group grid = cg::this_grid();
    __shared__ int   labl[1000];
    __shared__ float sED[16][4];
    __shared__ int   plab[16];
    __shared__ int   cntS[4];
    __shared__ float red[3][256];

    int tid = threadIdx.x;
    int base = blockIdx.x * 16;
    int pt = tid >> 4, sub = tid & 15;
    int i = base + pt;
    bool own = (i < CH_);

    if (tid < 16) plab[tid] = -1;
    if (own && sub == 0) {
        sED[pt][0] = g[(size_t)i * CH_ + 0];
        sED[pt][1] = g[(size_t)i * CH_ + 1];
        sED[pt][2] = g[(size_t)i * CH_ + 2];
    }
    float cc0 = g[0], cc1 = g[1 * CH_ + 1], cc2 = g[2 * CH_ + 2];
    __syncthreads();

    for (int it = 1; it <= ITERS_; ++it) {
        if (own && sub == 0) {
            float d0 = cc0 - 2.f * sED[pt][0];
            float d1 = cc1 - 2.f * sED[pt][1];
            float d2 = cc2 - 2.f * sED[pt][2];
            int nl = 0; float dm = d0;
            if (d1 < dm) { dm = d1; nl = 1; }
            if (d2 < dm) { dm = d2; nl = 2; }
            if (nl != plab[pt]) atomicAdd(&changed[it], 1);
            plab[pt] = nl;
            labels[i] = nl;
        }
        grid.sync();

        if (tid < 4) cntS[tid] = 0;
        __syncthreads();
        for (int idx = tid; idx < CH_; idx += 256) {
            int lb = labels[idx];
            labl[idx] = lb;
            atomicAdd(&cntS[lb], 1);
        }
        __syncthreads();

        float a0 = 0.f, a1 = 0.f, a2 = 0.f;
        if (own) {
            const float* gr = g + (size_t)i * CH_;
            for (int j = sub; j < CH_; j += 16) {
                float gv = gr[j];
                int lb = labl[j];
                a0 += (lb == 0) ? gv : 0.f;
                a1 += (lb == 1) ? gv : 0.f;
                a2 += (lb == 2) ? gv : 0.f;
            }
#pragma unroll
            for (int msk = 1; msk < 16; msk <<= 1) {
                a0 += __shfl_xor(a0, msk, 16);
                a1 += __shfl_xor(a1, msk, 16);
                a2 += __shfl_xor(a2, msk, 16);
            }
            if (sub == 0) {
                tg[i * 4 + 0] = a0; tg[i * 4 + 1] = a1; tg[i * 4 + 2] = a2;
            }
        }
        grid.sync();

        int chg = changed[it];
        int n0c = cntS[0], n1c = cntS[1], n2c = cntS[2];

        float p0 = 0.f, p1 = 0.f, p2 = 0.f;
        for (int idx = tid; idx < CH_; idx += 256) {
            int lb = labl[idx];
            float tv = tg[idx * 4 + lb];
            if (lb == 0) p0 += tv; else if (lb == 1) p1 += tv; else p2 += tv;
        }
        red[0][tid] = p0; red[1][tid] = p1; red[2][tid] = p2;
        __syncthreads();
        for (int off = 128; off > 0; off >>= 1) {
            if (tid < off) {
                red[0][tid] += red[0][tid + off];
                red[1][tid] += red[1][tid + off];
                red[2][tid] += red[2][tid + off];
            }
            __syncthreads();
        }
        float s0 = red[0][0], s1 = red[1][0], s2 = red[2][0];

        if (n0c > 0) cc0 = s0 / ((float)n0c * (float)n0c);
        if (n1c > 0) cc1 = s1 / ((float)n1c * (float)n1c);
        if (n2c > 0) cc2 = s2 / ((float)n2c * (float)n2c);
        if (own && sub == 0) {
            if (n0c > 0) sED[pt][0] = a0 / (float)n0c;
            if (n1c > 0) sED[pt][1] = a1 / (float)n1c;
            if (n2c > 0) sED[pt][2] = a2 / (float)n2c;
        }
        __syncthreads();

        if (chg == 0 && it > 1) break;
    }

    if (own && sub == 0) {
        float d0 = cc0 - 2.f * sED[pt][0];
        float d1 = cc1 - 2.f * sED[pt][1];
        float d2 = cc2 - 2.f * sED[pt][2];
        int nl = 0; float dm = d0;
        if (d1 < dm) { dm = d1; nl = 1; }
        if (d2 < dm) { dm = d2; nl = 2; }
        labels[i] = nl;
    }
}

// ---------------- K4b: build label-sorted channel permutation ---------------
__global__ __launch_bounds__(256) void k4b_perm(const int* __restrict__ labels,
                                                int* __restrict__ chlist,
                                                int* __restrict__ chpos,
                                                int* __restrict__ slabel) {
    __shared__ int cnt[3], st[4], c2[3];
    int tid = threadIdx.x;
    if (tid < 3) { cnt[tid] = 0; c2[tid] = 0; }
    __syncthreads();
    for (int n = tid; n < CH_; n += 256) atomicAdd(&cnt[labels[n]], 1);
    __syncthreads();
    if (tid == 0) {
        st[0] = 0;
        st[1] = ((cnt[0] + 3) >> 2) << 2;
        st[2] = st[1] + (((cnt[1] + 3) >> 2) << 2);
        st[3] = st[2] + (((cnt[2] + 3) >> 2) << 2);
    }
    __syncthreads();
    for (int s = tid; s < SLOTS_; s += 256) chlist[s] = 0;
    for (int t = tid; t < NTILES_; t += 256) {
        int s = t * 4;
        slabel[t] = (s < st[1]) ? 0 : (s < st[2]) ? 1 : (s < st[3]) ? 2 : 0;
    }
    __syncthreads();
    for (int n = tid; n < CH_; n += 256) {
        int lb = labels[n];
        int r = atomicAdd(&c2[lb], 1);
        int slot = st[lb] + r;
        chlist[slot] = n;
        chpos[n] = slot;
    }
}

// ---------------- K5: grouped GEMM  C[sb=128][p=64] = Z_tile . WB2[lab]^T ---
// Fused bias + denorm epilogue, writes permuted outP[slot][b][p] (p-contig).
__global__ __launch_bounds__(256) void k5_grouped(const ushort* __restrict__ zLH,
                                                  const ushort* __restrict__ zUH,
                                                  const ushort* __restrict__ WB2,
                                                  const int* __restrict__ chlist,
                                                  const int* __restrict__ slabel,
                                                  const float* __restrict__ bg,
                                                  const float* __restrict__ bu,
                                                  const float* __restrict__ meanT,
                                                  const float* __restrict__ sstdT,
                                                  float* __restrict__ outP) {
    __shared__ __align__(16) ushort ZT[128][40];
    __shared__ __align__(16) ushort WT[64][40];
    __shared__ int sch[4];

    int tile = blockIdx.x;
    int p0 = blockIdx.y * 64;
    int tid = threadIdx.x;
    if (tid < 4) sch[tid] = chlist[tile * 4 + tid];
    int lab = slabel[tile];
    __syncthreads();

    int lane = tid & 63, wid = tid >> 6;
    int wr = wid >> 1, wc = wid & 1;
    int fr = lane & 15, g8 = lane >> 4;

    int srow = tid >> 2, sseg = tid & 3;   // srow 0..63
    size_t zb0, zb1;
    {
        int r0 = srow;      zb0 = (size_t)sch[r0 >> 5] * KBL_ + (size_t)(r0 & 31) * LH_;
        int r1 = srow + 64; zb1 = (size_t)sch[r1 >> 5] * KBL_ + (size_t)(r1 & 31) * LH_;
    }
    const ushort* wrow = WB2 + (size_t)(lab * PRED_ + p0 + srow) * 1024;

    f32x4 acc[4][2];
#pragma unroll
    for (int m = 0; m < 4; ++m)
#pragma unroll
        for (int n = 0; n < 2; ++n) acc[m][n] = (f32x4){0.f, 0.f, 0.f, 0.f};

    uint4 pz0, pz1, pw;
    auto stage_load = [&](int t) {
        const ushort* zsrc = (t < 16) ? zLH : zUH;
        int ko = ((t & 15) * 32) + sseg * 8;
        pz0 = *(const uint4*)(zsrc + zb0 + ko);
        pz1 = *(const uint4*)(zsrc + zb1 + ko);
        pw  = *(const uint4*)(wrow + t * 32 + sseg * 8);
    };
    auto stage_write = [&]() {
        *(uint4*)&ZT[srow][sseg * 8] = pz0;
        *(uint4*)&ZT[srow + 64][sseg * 8] = pz1;
        *(uint4*)&WT[srow][sseg * 8] = pw;
    };

    stage_load(0);
    for (int t = 0; t < 32; ++t) {
        __syncthreads();
        stage_write();
        __syncthreads();
        if (t + 1 < 32) stage_load(t + 1);

        bf16x8 a[4];
#pragma unroll
        for (int m = 0; m < 4; ++m)
            a[m] = *(const bf16x8*)&ZT[wr * 64 + m * 16 + fr][g8 * 8];
#pragma unroll
        for (int nf = 0; nf < 2; ++nf) {
            bf16x8 bv = *(const bf16x8*)&WT[wc * 32 + nf * 16 + fr][g8 * 8];
#pragma unroll
            for (int m = 0; m < 4; ++m)
                acc[m][nf] = __builtin_amdgcn_mfma_f32_16x16x32_bf16(a[m], bv, acc[m][nf], 0, 0, 0);
        }
    }

    // epilogue: bias + denorm, write outP[slot][b][p]
#pragma unroll
    for (int m = 0; m < 4; ++m) {
#pragma unroll
        for (int q = 0; q < 4; ++q) {
            int sb = wr * 64 + m * 16 + g8 * 4 + q;
            int sl = sb >> 5, b = sb & 31;
            int n = sch[sl];
            float sd = sstdT[n * B_ + b], mu = meanT[n * B_ + b];
            size_t obase = ((size_t)(tile * 4 + sl) * B_ + b) * PRED_;
#pragma unroll
            for (int nf = 0; nf < 2; ++nf) {
                int p = p0 + wc * 32 + nf * 16 + fr;
                float v = acc[m][nf][q] + bg[lab * PRED_ + p] + bu[p];
                outP[obase + p] = v * sd + mu;
            }
        }
    }
}

// ---------------- K7: unpermute outP -> out[b][p][n] ------------------------
__global__ __launch_bounds__(256) void k7_unperm(const float* __restrict__ outP,
                                                 const int* __restrict__ chpos,
                                                 float* __restrict__ out) {
    int n = blockIdx.x * 256 + threadIdx.x;
    int p0 = blockIdx.y * 32;
    int b = blockIdx.z;
    if (n >= CH_) return;
    const float* src = outP + ((size_t)chpos[n] * B_ + b) * PRED_ + p0;
    float4 v[8];
#pragma unroll
    for (int j = 0; j < 8; ++j) v[j] = *(const float4*)(src + j * 4);
#pragma unroll
    for (int j = 0; j < 8; ++j) {
#pragma unroll
        for (int e = 0; e < 4; ++e) {
            int p = p0 + j * 4 + e;
            out[((size_t)b * PRED_ + p) * CH_ + n] = ((const float*)&v[j])[e];
        }
    }
}

extern "C" void kernel_launch(void* const* d_in, const int* in_sizes, int n_in,
                              void* d_out, int out_size, void* d_ws, size_t ws_size,
                              hipStream_t stream) {
    const float* x  = (const float*)d_in[0];
    const float* Wg = (const float*)d_in[4];
    const float* bg = (const float*)d_in[5];
    const float* Wu = (const float*)d_in[6];
    const float* bu = (const float*)d_in[7];
    float* out = (float*)d_out;
    (void)in_sizes; (void)n_in; (void)out_size; (void)ws_size;

    char* ws = (char*)d_ws;
    size_t off = 0;
    auto alloc = [&](size_t bytes) {
        void* p = ws + off;
        off = (off + bytes + 255) & ~(size_t)255;
        return p;
    };
    ushort* zLH  = (ushort*)alloc((size_t)16384000 * 2);
    ushort* zLR  = (ushort*)alloc((size_t)16384000 * 2);
    ushort* zUH  = (ushort*)alloc((size_t)16384000 * 2);
    float*  G    = (float*)alloc((size_t)1000000 * 4);
    ushort* WB2  = (ushort*)alloc((size_t)576 * 1024 * 2);
    float*  meanT = (float*)alloc((size_t)32000 * 4);
    float*  sstdT = (float*)alloc((size_t)32000 * 4);
    float*  invT  = (float*)alloc((size_t)32000 * 4);
    int*    labels  = (int*)alloc((size_t)1024 * 4);
    float*  tg   = (float*)alloc((size_t)4096 * 4);
    int*    changed = (int*)alloc((size_t)64 * 4);
    int*    chlist = (int*)alloc((size_t)SLOTS_ * 4);
    int*    chpos  = (int*)alloc((size_t)1024 * 4);
    int*    slabel = (int*)alloc((size_t)256 * 4);
    // union region: Gp (64 MB, dead after k3b) then outP (24.9 MB)
    char* unionBase = (char*)alloc((size_t)ZSPLIT_ * 1000000 * 4);
    float* Gp   = (float*)unionBase;
    float* outP = (float*)unionBase;

    hipMemsetAsync(changed, 0, 64 * 4, stream);
    k1_stats<<<dim3(4, 32), 256, 0, stream>>>(x, meanT, sstdT, invT);
    k2_build<<<dim3(32, 16, 32), 256, 0, stream>>>(x, meanT, invT, zLH, zLR, zUH);
    k0_wprep<<<576, 256, 0, stream>>>(Wg, Wu, WB2);
    k3_mfma<<<dim3(8, 8, ZSPLIT_), 256, 0, stream>>>(zLH, zLR, Gp);
    k3b_reduce<<<977, 256, 0, stream>>>(Gp, G);
    void* args[] = { (void*)&G, (void*)&labels, (void*)&tg, (void*)&changed };
    hipLaunchCooperativeKernel((void*)k4_kmeans, dim3(64), dim3(256), args, 0, stream);
    k4b_perm<<<1, 256, 0, stream>>>(labels, chlist, chpos, slabel);
    k5_grouped<<<dim3(NTILES_, 3), 256, 0, stream>>>(zLH, zUH, WB2, chlist, slabel,
                                                     bg, bu, meanT, sstdT, outP);
    k7_unperm<<<dim3(4, 6, 32), 256, 0, stream>>>(outP, chpos, out);
}

// Round 5
// 346.393 us; speedup vs baseline: 6.7952x; 1.1802x over previous
//
#include <hip/hip_runtime.h>
#include <hip/hip_bf16.h>
#include <hip/hip_cooperative_groups.h>

namespace cg = cooperative_groups;

#define B_   32
#define L_   1024
#define LH_  512
#define CH_  1000
#define PRED_ 192
#define ITERS_ 50
#define KBL_ 16384   // B_*LH_
#define SLOTS_ 1012
#define NTILES_ 253
#define NTRI_ 36     // upper-triangle 8x8 tile pairs

typedef __attribute__((ext_vector_type(8))) short bf16x8;
typedef __attribute__((ext_vector_type(4))) float f32x4;

// ---------------- K1: per-(b,c) mean / std (transposed [c][b] outputs) ------
__global__ __launch_bounds__(256) void k1_stats(const float* __restrict__ x,
                                                float* __restrict__ meanT,
                                                float* __restrict__ sstdT,
                                                float* __restrict__ invT) {
    int c = blockIdx.x * 256 + threadIdx.x;
    int b = blockIdx.y;
    if (c >= CH_) return;
    const float* xp = x + (size_t)b * L_ * CH_ + c;
    float s = 0.f, ss = 0.f;
    for (int l = 0; l < L_; ++l) {
        float v = xp[(size_t)l * CH_];
        s += v; ss += v * v;
    }
    float m = s * (1.0f / L_);
    float var = (ss - (float)L_ * m * m) * (1.0f / (L_ - 1)) + 1e-5f;
    float sd = sqrtf(var);
    meanT[c * B_ + b] = m;
    sstdT[c * B_ + b] = sd;
    invT[c * B_ + b] = 1.0f / sd;
}

// ---------------- K2: build bf16 z_L (split) + z_U in [n][b][lh] layout -----
__global__ __launch_bounds__(256) void k2_build(const float* __restrict__ x,
                                                const float* __restrict__ meanT,
                                                const float* __restrict__ invT,
                                                ushort* __restrict__ zLH,
                                                ushort* __restrict__ zLR,
                                                ushort* __restrict__ zUH) {
    __shared__ float Ls[32][33];
    __shared__ float Us[32][33];
    int tid = threadIdx.x;
    int tx = tid & 31, ty = tid >> 5;
    int n0 = blockIdx.x * 32;
    int lh0 = blockIdx.y * 32;
    int b = blockIdx.z;
    int n = n0 + tx;
    float m = 0.f, iv = 0.f;
    if (n < CH_) { m = meanT[n * B_ + b]; iv = invT[n * B_ + b]; }
    for (int r = 0; r < 4; ++r) {
        int lh = lh0 + ty + 8 * r;
        float v0 = 0.f, v1 = 0.f;
        if (n < CH_) {
            v0 = x[((size_t)b * L_ + 2 * lh) * CH_ + n];
            v1 = x[((size_t)b * L_ + 2 * lh + 1) * CH_ + n];
        }
        float a = (v0 - m) * iv * 0.5f;
        float c2 = (v1 - m) * iv * 0.5f;
        Ls[ty + 8 * r][tx] = a + c2;
        Us[ty + 8 * r][tx] = a - c2;
    }
    __syncthreads();
    for (int r = 0; r < 4; ++r) {
        int nl = ty + 8 * r;
        int nn = n0 + nl;
        if (nn < CH_) {
            size_t dst = (size_t)nn * KBL_ + (size_t)b * LH_ + lh0 + tx;
            float lv = Ls[tx][nl];
            float uv = Us[tx][nl];
            __hip_bfloat16 h = __float2bfloat16(lv);
            float hf = __bfloat162float(h);
            __hip_bfloat16 rr = __float2bfloat16(lv - hf);
            __hip_bfloat16 uh = __float2bfloat16(uv);
            zLH[dst] = *(ushort*)&h;
            zLR[dst] = *(ushort*)&rr;
            zUH[dst] = *(ushort*)&uh;
        }
    }
}

// ---------------- K0w: stacked weights WB2[lab][192][1024] = [Wg[lab]|Wu] ---
__global__ __launch_bounds__(256) void k0_wprep(const float* __restrict__ Wg,
                                                const float* __restrict__ Wu,
                                                ushort* __restrict__ WB2) {
    int r = blockIdx.x;          // 0..575 = lab*192+p
    int p = r % PRED_;
    int tid = threadIdx.x;
#pragma unroll
    for (int i = 0; i < 4; ++i) {
        int k = i * 256 + tid;   // 0..1023
        float w = (k < 512) ? Wg[(size_t)r * LH_ + k]
                            : Wu[(size_t)p * LH_ + (k - 512)];
        __hip_bfloat16 h = __float2bfloat16(w);
        WB2[(size_t)r * 1024 + k] = *(ushort*)&h;
    }
}

// ---------------- K3: symmetric Gram via split-bf16 MFMA --------------------
// Upper-triangle tiles only (36 pairs), XCD-chunked: xcd = bid&7 owns
// k-slices {2*xcd, 2*xcd+1} so each XCD's B-working-set fits its private L2.
#define ZSPLIT_ 16
#define KSEG_   1024
#define NT_     (KSEG_ / 32)

__global__ __launch_bounds__(256) void k3_mfma(const ushort* __restrict__ zH,
                                               const ushort* __restrict__ zR,
                                               float* __restrict__ gpart) {
    __shared__ __align__(16) ushort AH[128][40];
    __shared__ __align__(16) ushort AR[128][40];
    __shared__ __align__(16) ushort BH[128][40];
    __shared__ __align__(16) ushort BR[128][40];

    int bid = blockIdx.x;
    int xcd = bid & 7, w = bid >> 3;           // w in 0..71
    int ksl = 2 * xcd + (w >= NTRI_);
    int t = (w >= NTRI_) ? w - NTRI_ : w;
    int ti = 0, tt = t;
    while (tt >= 8 - ti) { tt -= 8 - ti; ++ti; }
    int tj = ti + tt;
    int i0 = ti * 128, j0 = tj * 128;
    int kb = ksl * KSEG_;

    int tid = threadIdx.x;
    int lane = tid & 63;
    int wid = tid >> 6;
    int wr = wid >> 1, wc = wid & 1;
    int fr = lane & 15;
    int g8 = lane >> 4;

    f32x4 acc[4][4];
#pragma unroll
    for (int m = 0; m < 4; ++m)
#pragma unroll
        for (int n = 0; n < 4; ++n) acc[m][n] = (f32x4){0.f, 0.f, 0.f, 0.f};

    int srow = tid >> 2;
    int sseg = tid & 3;

    uint4 pv[8];
    auto stage_load = [&](int kt) {
        int k0 = kb + kt * 32;
#pragma unroll
        for (int s = 0; s < 8; ++s) {
            int tile = s >> 1, rep = s & 1;
            int row = srow + rep * 64;
            int grow = ((tile < 2) ? i0 : j0) + row;
            const ushort* src = (tile & 1) ? zR : zH;
            uint4 v = {0u, 0u, 0u, 0u};
            if (grow < CH_)
                v = *(const uint4*)(src + (size_t)grow * KBL_ + k0 + sseg * 8);
            pv[s] = v;
        }
    };
    auto stage_write = [&]() {
#pragma unroll
        for (int s = 0; s < 8; ++s) {
            int tile = s >> 1, rep = s & 1;
            int row = srow + rep * 64;
            ushort* dst = (tile == 0) ? &AH[row][sseg * 8]
                        : (tile == 1) ? &AR[row][sseg * 8]
                        : (tile == 2) ? &BH[row][sseg * 8]
                                      : &BR[row][sseg * 8];
            *(uint4*)dst = pv[s];
        }
    };

    stage_load(0);
    for (int t2 = 0; t2 < NT_; ++t2) {
        __syncthreads();
        stage_write();
        __syncthreads();
        if (t2 + 1 < NT_) stage_load(t2 + 1);

        bf16x8 ah[4], ar[4];
#pragma unroll
        for (int m = 0; m < 4; ++m) {
            ah[m] = *(const bf16x8*)&AH[wr * 64 + m * 16 + fr][g8 * 8];
            ar[m] = *(const bf16x8*)&AR[wr * 64 + m * 16 + fr][g8 * 8];
        }
#pragma unroll
        for (int n = 0; n < 4; ++n) {
            bf16x8 bh = *(const bf16x8*)&BH[wc * 64 + n * 16 + fr][g8 * 8];
            bf16x8 br = *(const bf16x8*)&BR[wc * 64 + n * 16 + fr][g8 * 8];
#pragma unroll
            for (int m = 0; m < 4; ++m) {
                acc[m][n] = __builtin_amdgcn_mfma_f32_16x16x32_bf16(ah[m], bh, acc[m][n], 0, 0, 0);
                acc[m][n] = __builtin_amdgcn_mfma_f32_16x16x32_bf16(ah[m], br, acc[m][n], 0, 0, 0);
                acc[m][n] = __builtin_amdgcn_mfma_f32_16x16x32_bf16(ar[m], bh, acc[m][n], 0, 0, 0);
            }
        }
    }

    // tile-local store: gpart[(ksl*NTRI_ + t)][r][c]
    float* gp = gpart + ((size_t)ksl * NTRI_ + t) * 16384;
#pragma unroll
    for (int m = 0; m < 4; ++m) {
        int rb = wr * 64 + m * 16 + g8 * 4;
#pragma unroll
        for (int n = 0; n < 4; ++n) {
            int c = wc * 64 + n * 16 + fr;
#pragma unroll
            for (int q = 0; q < 4; ++q)
                gp[(size_t)(rb + q) * 128 + c] = acc[m][n][q];
        }
    }
}

// ---------------- K3b: reduce 16 partials per tile, write G + mirror --------
__global__ __launch_bounds__(256) void k3b_sym(const float* __restrict__ gpart,
                                               float* __restrict__ g) {
    int t = blockIdx.x;          // 0..35
    int seg = blockIdx.y;        // 0..3
    int ti = 0, tt = t;
    while (tt >= 8 - ti) { tt -= 8 - ti; ++ti; }
    int tj = ti + tt;
    int i0 = ti * 128, j0 = tj * 128;
    int tid = threadIdx.x;
    int e0 = seg * 4096 + tid * 16;          // 16 consecutive floats, one row
    int r = e0 >> 7, c0 = e0 & 127;

    float4 s[4];
#pragma unroll
    for (int j = 0; j < 4; ++j) s[j] = (float4){0.f, 0.f, 0.f, 0.f};
#pragma unroll
    for (int p = 0; p < ZSPLIT_; ++p) {
        const float* src = gpart + ((size_t)p * NTRI_ + t) * 16384 + e0;
#pragma unroll
        for (int j = 0; j < 4; ++j) {
            float4 v = *(const float4*)(src + j * 4);
            s[j].x += v.x; s[j].y += v.y; s[j].z += v.z; s[j].w += v.w;
        }
    }
    int i = i0 + r;
    if (i < CH_) {
#pragma unroll
        for (int j = 0; j < 4; ++j) {
            int jc = j0 + c0 + j * 4;
            if (jc + 3 < CH_) {
                *(float4*)(g + (size_t)i * CH_ + jc) = s[j];
            } else {
#pragma unroll
                for (int e = 0; e < 4; ++e)
                    if (jc + e < CH_) g[(size_t)i * CH_ + jc + e] = ((const float*)&s[j])[e];
            }
        }
        if (ti != tj) {   // mirror into lower triangle
#pragma unroll
            for (int j = 0; j < 4; ++j) {
#pragma unroll
                for (int e = 0; e < 4; ++e) {
                    int jc = j0 + c0 + j * 4 + e;
                    if (jc < CH_) g[(size_t)jc * CH_ + i] = ((const float*)&s[j])[e];
                }
            }
        }
    }
}

// ---------------- K4: cooperative k-means on the Gram matrix ----------------
// 32 blocks x 512 threads (32 points/block, 16 lanes/point).
__global__ __launch_bounds__(512) void k4_kmeans(const float* __restrict__ g,
                                                 int* __restrict__ labels,
                                                 float* __restrict__ tg,
                                                 int* __restrict__ changed) {
    cg::grid_group grid = cg::this_grid();
    __shared__ int   labl[1000];
    __shared__ float sED[32][4];
    __shared__ int   plab[32];
    __shared__ int   cntS[4];
    __shared__ float red[3][512];

    int tid = threadIdx.x;
    int base = blockIdx.x * 32;
    int pt = tid >> 4, sub = tid & 15;
    int i = base + pt;
    bool own = (i < CH_);

    if (tid < 32) plab[tid] = -1;
    if (own && sub == 0) {
        sED[pt][0] = g[(size_t)i * CH_ + 0];
        sED[pt][1] = g[(size_t)i * CH_ + 1];
        sED[pt][2] = g[(size_t)i * CH_ + 2];
    }
    float cc0 = g[0], cc1 = g[1 * CH_ + 1], cc2 = g[2 * CH_ + 2];
    __syncthreads();

    for (int it = 1; it <= ITERS_; ++it) {
        if (own && sub == 0) {
            float d0 = cc0 - 2.f * sED[pt][0];
            float d1 = cc1 - 2.f * sED[pt][1];
            float d2 = cc2 - 2.f * sED[pt][2];
            int nl = 0; float dm = d0;
            if (d1 < dm) { dm = d1; nl = 1; }
            if (d2 < dm) { dm = d2; nl = 2; }
            if (nl != plab[pt]) atomicAdd(&changed[it], 1);
            plab[pt] = nl;
            labels[i] = nl;
        }
        grid.sync();

        if (tid < 4) cntS[tid] = 0;
        __syncthreads();
        for (int idx = tid; idx < CH_; idx += 512) {
            int lb = labels[idx];
            labl[idx] = lb;
            atomicAdd(&cntS[lb], 1);
        }
        __syncthreads();

        float a0 = 0.f, a1 = 0.f, a2 = 0.f;
        if (own) {
            const float* gr = g + (size_t)i * CH_;
            for (int j = sub; j < CH_; j += 16) {
                float gv = gr[j];
                int lb = labl[j];
                a0 += (lb == 0) ? gv : 0.f;
                a1 += (lb == 1) ? gv : 0.f;
                a2 += (lb == 2) ? gv : 0.f;
            }
#pragma unroll
            for (int msk = 1; msk < 16; msk <<= 1) {
                a0 += __shfl_xor(a0, msk, 16);
                a1 += __shfl_xor(a1, msk, 16);
                a2 += __shfl_xor(a2, msk, 16);
            }
            if (sub == 0) {
                tg[i * 4 + 0] = a0; tg[i * 4 + 1] = a1; tg[i * 4 + 2] = a2;
            }
        }
        grid.sync();

        int chg = changed[it];
        int n0c = cntS[0], n1c = cntS[1], n2c = cntS[2];

        float p0 = 0.f, p1 = 0.f, p2 = 0.f;
        for (int idx = tid; idx < CH_; idx += 512) {
            int lb = labl[idx];
            float tv = tg[idx * 4 + lb];
            if (lb == 0) p0 += tv; else if (lb == 1) p1 += tv; else p2 += tv;
        }
        red[0][tid] = p0; red[1][tid] = p1; red[2][tid] = p2;
        __syncthreads();
        for (int off = 256; off > 0; off >>= 1) {
            if (tid < off) {
                red[0][tid] += red[0][tid + off];
                red[1][tid] += red[1][tid + off];
                red[2][tid] += red[2][tid + off];
            }
            __syncthreads();
        }
        float s0 = red[0][0], s1 = red[1][0], s2 = red[2][0];

        if (n0c > 0) cc0 = s0 / ((float)n0c * (float)n0c);
        if (n1c > 0) cc1 = s1 / ((float)n1c * (float)n1c);
        if (n2c > 0) cc2 = s2 / ((float)n2c * (float)n2c);
        if (own && sub == 0) {
            if (n0c > 0) sED[pt][0] = a0 / (float)n0c;
            if (n1c > 0) sED[pt][1] = a1 / (float)n1c;
            if (n2c > 0) sED[pt][2] = a2 / (float)n2c;
        }
        __syncthreads();

        if (chg == 0 && it > 1) break;
    }

    if (own && sub == 0) {
        float d0 = cc0 - 2.f * sED[pt][0];
        float d1 = cc1 - 2.f * sED[pt][1];
        float d2 = cc2 - 2.f * sED[pt][2];
        int nl = 0; float dm = d0;
        if (d1 < dm) { dm = d1; nl = 1; }
        if (d2 < dm) { dm = d2; nl = 2; }
        labels[i] = nl;
    }
}

// ---------------- K4b: build label-sorted channel permutation ---------------
__global__ __launch_bounds__(256) void k4b_perm(const int* __restrict__ labels,
                                                int* __restrict__ chlist,
                                                int* __restrict__ chpos,
                                                int* __restrict__ slabel) {
    __shared__ int cnt[3], st[4], c2[3];
    int tid = threadIdx.x;
    if (tid < 3) { cnt[tid] = 0; c2[tid] = 0; }
    __syncthreads();
    for (int n = tid; n < CH_; n += 256) atomicAdd(&cnt[labels[n]], 1);
    __syncthreads();
    if (tid == 0) {
        st[0] = 0;
        st[1] = ((cnt[0] + 3) >> 2) << 2;
        st[2] = st[1] + (((cnt[1] + 3) >> 2) << 2);
        st[3] = st[2] + (((cnt[2] + 3) >> 2) << 2);
    }
    __syncthreads();
    for (int s = tid; s < SLOTS_; s += 256) chlist[s] = 0;
    for (int t = tid; t < NTILES_; t += 256) {
        int s = t * 4;
        slabel[t] = (s < st[1]) ? 0 : (s < st[2]) ? 1 : (s < st[3]) ? 2 : 0;
    }
    __syncthreads();
    for (int n = tid; n < CH_; n += 256) {
        int lb = labels[n];
        int r = atomicAdd(&c2[lb], 1);
        int slot = st[lb] + r;
        chlist[slot] = n;
        chpos[n] = slot;
    }
}

// ---------------- K5: grouped GEMM  C[sb=128][p=64] = Z_tile . WB2[lab]^T ---
__global__ __launch_bounds__(256) void k5_grouped(const ushort* __restrict__ zLH,
                                                  const ushort* __restrict__ zUH,
                                                  const ushort* __restrict__ WB2,
                                                  const int* __restrict__ chlist,
                                                  const int* __restrict__ slabel,
                                                  const float* __restrict__ bg,
                                                  const float* __restrict__ bu,
                                                  const float* __restrict__ meanT,
                                                  const float* __restrict__ sstdT,
                                                  float* __restrict__ outP) {
    __shared__ __align__(16) ushort ZT[128][40];
    __shared__ __align__(16) ushort WT[64][40];
    __shared__ int sch[4];

    int tile = blockIdx.x;
    int p0 = blockIdx.y * 64;
    int tid = threadIdx.x;
    if (tid < 4) sch[tid] = chlist[tile * 4 + tid];
    int lab = slabel[tile];
    __syncthreads();

    int lane = tid & 63, wid = tid >> 6;
    int wr = wid >> 1, wc = wid & 1;
    int fr = lane & 15, g8 = lane >> 4;

    int srow = tid >> 2, sseg = tid & 3;   // srow 0..63
    size_t zb0, zb1;
    {
        int r0 = srow;      zb0 = (size_t)sch[r0 >> 5] * KBL_ + (size_t)(r0 & 31) * LH_;
        int r1 = srow + 64; zb1 = (size_t)sch[r1 >> 5] * KBL_ + (size_t)(r1 & 31) * LH_;
    }
    const ushort* wrow = WB2 + (size_t)(lab * PRED_ + p0 + srow) * 1024;

    f32x4 acc[4][2];
#pragma unroll
    for (int m = 0; m < 4; ++m)
#pragma unroll
        for (int n = 0; n < 2; ++n) acc[m][n] = (f32x4){0.f, 0.f, 0.f, 0.f};

    uint4 pz0, pz1, pw;
    auto stage_load = [&](int t) {
        const ushort* zsrc = (t < 16) ? zLH : zUH;
        int ko = ((t & 15) * 32) + sseg * 8;
        pz0 = *(const uint4*)(zsrc + zb0 + ko);
        pz1 = *(const uint4*)(zsrc + zb1 + ko);
        pw  = *(const uint4*)(wrow + t * 32 + sseg * 8);
    };
    auto stage_write = [&]() {
        *(uint4*)&ZT[srow][sseg * 8] = pz0;
        *(uint4*)&ZT[srow + 64][sseg * 8] = pz1;
        *(uint4*)&WT[srow][sseg * 8] = pw;
    };

    stage_load(0);
    for (int t = 0; t < 32; ++t) {
        __syncthreads();
        stage_write();
        __syncthreads();
        if (t + 1 < 32) stage_load(t + 1);

        bf16x8 a[4];
#pragma unroll
        for (int m = 0; m < 4; ++m)
            a[m] = *(const bf16x8*)&ZT[wr * 64 + m * 16 + fr][g8 * 8];
#pragma unroll
        for (int nf = 0; nf < 2; ++nf) {
            bf16x8 bv = *(const bf16x8*)&WT[wc * 32 + nf * 16 + fr][g8 * 8];
#pragma unroll
            for (int m = 0; m < 4; ++m)
                acc[m][nf] = __builtin_amdgcn_mfma_f32_16x16x32_bf16(a[m], bv, acc[m][nf], 0, 0, 0);
        }
    }

#pragma unroll
    for (int m = 0; m < 4; ++m) {
#pragma unroll
        for (int q = 0; q < 4; ++q) {
            int sb = wr * 64 + m * 16 + g8 * 4 + q;
            int sl = sb >> 5, b = sb & 31;
            int n = sch[sl];
            float sd = sstdT[n * B_ + b], mu = meanT[n * B_ + b];
            size_t obase = ((size_t)(tile * 4 + sl) * B_ + b) * PRED_;
#pragma unroll
            for (int nf = 0; nf < 2; ++nf) {
                int p = p0 + wc * 32 + nf * 16 + fr;
                float v = acc[m][nf][q] + bg[lab * PRED_ + p] + bu[p];
                outP[obase + p] = v * sd + mu;
            }
        }
    }
}

// ---------------- K7: unpermute outP -> out[b][p][n] ------------------------
__global__ __launch_bounds__(256) void k7_unperm(const float* __restrict__ outP,
                                                 const int* __restrict__ chpos,
                                                 float* __restrict__ out) {
    int n = blockIdx.x * 256 + threadIdx.x;
    int p0 = blockIdx.y * 32;
    int b = blockIdx.z;
    if (n >= CH_) return;
    const float* src = outP + ((size_t)chpos[n] * B_ + b) * PRED_ + p0;
    float4 v[8];
#pragma unroll
    for (int j = 0; j < 8; ++j) v[j] = *(const float4*)(src + j * 4);
#pragma unroll
    for (int j = 0; j < 8; ++j) {
#pragma unroll
        for (int e = 0; e < 4; ++e) {
            int p = p0 + j * 4 + e;
            out[((size_t)b * PRED_ + p) * CH_ + n] = ((const float*)&v[j])[e];
        }
    }
}

extern "C" void kernel_launch(void* const* d_in, const int* in_sizes, int n_in,
                              void* d_out, int out_size, void* d_ws, size_t ws_size,
                              hipStream_t stream) {
    const float* x  = (const float*)d_in[0];
    const float* Wg = (const float*)d_in[4];
    const float* bg = (const float*)d_in[5];
    const float* Wu = (const float*)d_in[6];
    const float* bu = (const float*)d_in[7];
    float* out = (float*)d_out;
    (void)in_sizes; (void)n_in; (void)out_size; (void)ws_size;

    char* ws = (char*)d_ws;
    size_t off = 0;
    auto alloc = [&](size_t bytes) {
        void* p = ws + off;
        off = (off + bytes + 255) & ~(size_t)255;
        return p;
    };
    ushort* zLH  = (ushort*)alloc((size_t)16384000 * 2);
    ushort* zLR  = (ushort*)alloc((size_t)16384000 * 2);
    ushort* zUH  = (ushort*)alloc((size_t)16384000 * 2);
    float*  G    = (float*)alloc((size_t)1000000 * 4);
    ushort* WB2  = (ushort*)alloc((size_t)576 * 1024 * 2);
    float*  meanT = (float*)alloc((size_t)32000 * 4);
    float*  sstdT = (float*)alloc((size_t)32000 * 4);
    float*  invT  = (float*)alloc((size_t)32000 * 4);
    int*    labels  = (int*)alloc((size_t)1024 * 4);
    float*  tg   = (float*)alloc((size_t)4096 * 4);
    int*    changed = (int*)alloc((size_t)64 * 4);
    int*    chlist = (int*)alloc((size_t)SLOTS_ * 4);
    int*    chpos  = (int*)alloc((size_t)1024 * 4);
    int*    slabel = (int*)alloc((size_t)256 * 4);
    // union region: Gp (16*36*16384*4 = 37.7 MB, dead after k3b) then outP (24.9 MB)
    char* unionBase = (char*)alloc((size_t)ZSPLIT_ * NTRI_ * 16384 * 4);
    float* Gp   = (float*)unionBase;
    float* outP = (float*)unionBase;

    hipMemsetAsync(changed, 0, 64 * 4, stream);
    k1_stats<<<dim3(4, 32), 256, 0, stream>>>(x, meanT, sstdT, invT);
    k2_build<<<dim3(32, 16, 32), 256, 0, stream>>>(x, meanT, invT, zLH, zLR, zUH);
    k0_wprep<<<576, 256, 0, stream>>>(Wg, Wu, WB2);
    k3_mfma<<<8 * NTRI_ * 2, 256, 0, stream>>>(zLH, zLR, Gp);
    k3b_sym<<<dim3(NTRI_, 4), 256, 0, stream>>>(Gp, G);
    void* args[] = { (void*)&G, (void*)&labels, (void*)&tg, (void*)&changed };
    hipLaunchCooperativeKernel((void*)k4_kmeans, dim3(32), dim3(512), args, 0, stream);
    k4b_perm<<<1, 256, 0, stream>>>(labels, chlist, chpos, slabel);
    k5_grouped<<<dim3(NTILES_, 3), 256, 0, stream>>>(zLH, zUH, WB2, chlist, slabel,
                                                     bg, bu, meanT, sstdT, outP);
    k7_unperm<<<dim3(4, 6, 32), 256, 0, stream>>>(outP, chpos, out);
}

// Round 6
// 307.663 us; speedup vs baseline: 7.6506x; 1.1259x over previous
//
#include <hip/hip_runtime.h>
#include <hip/hip_bf16.h>
#include <hip/hip_cooperative_groups.h>

namespace cg = cooperative_groups;

#define B_   32
#define L_   1024
#define LH_  512
#define CH_  1000
#define PRED_ 192
#define ITERS_ 50
#define KBL_ 16384   // B_*LH_
#define SLOTS_ 1012
#define NTILES_ 253
#define NTRI_ 36     // upper-triangle 8x8 tile pairs
#define SEG_ 16      // L-segments for stats partials

typedef __attribute__((ext_vector_type(8))) short bf16x8;
typedef __attribute__((ext_vector_type(4))) float f32x4;

// ---------------- K1a: partial sums over 64-row segments --------------------
__global__ __launch_bounds__(256) void k1_partial(const float* __restrict__ x,
                                                  float* __restrict__ pS,
                                                  float* __restrict__ pSS) {
    int seg = blockIdx.x;        // 0..15
    int b = blockIdx.y;          // 0..31
    int t = threadIdx.x;
    if (t >= 250) return;
    int c4 = t * 4;
    const float* xp = x + (size_t)b * L_ * CH_ + (size_t)seg * 64 * CH_ + c4;
    float4 s = {0.f, 0.f, 0.f, 0.f}, ss = {0.f, 0.f, 0.f, 0.f};
#pragma unroll 4
    for (int l = 0; l < 64; ++l) {
        float4 v = *(const float4*)(xp + (size_t)l * CH_);
        s.x += v.x; s.y += v.y; s.z += v.z; s.w += v.w;
        ss.x += v.x * v.x; ss.y += v.y * v.y; ss.z += v.z * v.z; ss.w += v.w * v.w;
    }
    size_t o = ((size_t)seg * B_ + b) * CH_ + c4;
    *(float4*)(pS + o) = s;
    *(float4*)(pSS + o) = ss;
}

// ---------------- K1b: reduce partials -> mean / std ------------------------
__global__ __launch_bounds__(256) void k1b_reduce(const float* __restrict__ pS,
                                                  const float* __restrict__ pSS,
                                                  float* __restrict__ meanT,
                                                  float* __restrict__ sstdT,
                                                  float* __restrict__ invT) {
    int idx = blockIdx.x * 256 + threadIdx.x;
    if (idx >= B_ * CH_) return;
    int c = idx % CH_;
    int b = idx / CH_;
    float s = 0.f, ss = 0.f;
#pragma unroll
    for (int seg = 0; seg < SEG_; ++seg) {
        size_t o = ((size_t)seg * B_ + b) * CH_ + c;
        s += pS[o];
        ss += pSS[o];
    }
    float m = s * (1.0f / L_);
    float var = (ss - (float)L_ * m * m) * (1.0f / (L_ - 1)) + 1e-5f;
    float sd = sqrtf(var);
    meanT[c * B_ + b] = m;
    sstdT[c * B_ + b] = sd;
    invT[c * B_ + b] = 1.0f / sd;
}

// ---------------- K2: build bf16 z_L (split) + z_U in [n][b][lh] layout -----
__global__ __launch_bounds__(256) void k2_build(const float* __restrict__ x,
                                                const float* __restrict__ meanT,
                                                const float* __restrict__ invT,
                                                ushort* __restrict__ zLH,
                                                ushort* __restrict__ zLR,
                                                ushort* __restrict__ zUH) {
    __shared__ float Ls[32][33];
    __shared__ float Us[32][33];
    int tid = threadIdx.x;
    int tx = tid & 31, ty = tid >> 5;
    int n0 = blockIdx.x * 32;
    int lh0 = blockIdx.y * 32;
    int b = blockIdx.z;
    int n = n0 + tx;
    float m = 0.f, iv = 0.f;
    if (n < CH_) { m = meanT[n * B_ + b]; iv = invT[n * B_ + b]; }
    for (int r = 0; r < 4; ++r) {
        int lh = lh0 + ty + 8 * r;
        float v0 = 0.f, v1 = 0.f;
        if (n < CH_) {
            v0 = x[((size_t)b * L_ + 2 * lh) * CH_ + n];
            v1 = x[((size_t)b * L_ + 2 * lh + 1) * CH_ + n];
        }
        float a = (v0 - m) * iv * 0.5f;
        float c2 = (v1 - m) * iv * 0.5f;
        Ls[ty + 8 * r][tx] = a + c2;
        Us[ty + 8 * r][tx] = a - c2;
    }
    __syncthreads();
    for (int r = 0; r < 4; ++r) {
        int nl = ty + 8 * r;
        int nn = n0 + nl;
        if (nn < CH_) {
            size_t dst = (size_t)nn * KBL_ + (size_t)b * LH_ + lh0 + tx;
            float lv = Ls[tx][nl];
            float uv = Us[tx][nl];
            __hip_bfloat16 h = __float2bfloat16(lv);
            float hf = __bfloat162float(h);
            __hip_bfloat16 rr = __float2bfloat16(lv - hf);
            __hip_bfloat16 uh = __float2bfloat16(uv);
            zLH[dst] = *(ushort*)&h;
            zLR[dst] = *(ushort*)&rr;
            zUH[dst] = *(ushort*)&uh;
        }
    }
}

// ---------------- K0w: stacked weights WB2[lab][192][1024] = [Wg[lab]|Wu] ---
__global__ __launch_bounds__(256) void k0_wprep(const float* __restrict__ Wg,
                                                const float* __restrict__ Wu,
                                                ushort* __restrict__ WB2) {
    int r = blockIdx.x;          // 0..575 = lab*192+p
    int p = r % PRED_;
    int tid = threadIdx.x;
#pragma unroll
    for (int i = 0; i < 4; ++i) {
        int k = i * 256 + tid;   // 0..1023
        float w = (k < 512) ? Wg[(size_t)r * LH_ + k]
                            : Wu[(size_t)p * LH_ + (k - 512)];
        __hip_bfloat16 h = __float2bfloat16(w);
        WB2[(size_t)r * 1024 + k] = *(ushort*)&h;
    }
}

// ---------------- K3: symmetric Gram via split-bf16 MFMA --------------------
#define ZSPLIT_ 16
#define KSEG_   1024
#define NT_     (KSEG_ / 32)

__global__ __launch_bounds__(256) void k3_mfma(const ushort* __restrict__ zH,
                                               const ushort* __restrict__ zR,
                                               float* __restrict__ gpart) {
    __shared__ __align__(16) ushort AH[128][40];
    __shared__ __align__(16) ushort AR[128][40];
    __shared__ __align__(16) ushort BH[128][40];
    __shared__ __align__(16) ushort BR[128][40];

    int bid = blockIdx.x;
    int xcd = bid & 7, w = bid >> 3;           // w in 0..71
    int ksl = 2 * xcd + (w >= NTRI_);
    int t = (w >= NTRI_) ? w - NTRI_ : w;
    int ti = 0, tt = t;
    while (tt >= 8 - ti) { tt -= 8 - ti; ++ti; }
    int tj = ti + tt;
    int i0 = ti * 128, j0 = tj * 128;
    int kb = ksl * KSEG_;

    int tid = threadIdx.x;
    int lane = tid & 63;
    int wid = tid >> 6;
    int wr = wid >> 1, wc = wid & 1;
    int fr = lane & 15;
    int g8 = lane >> 4;

    f32x4 acc[4][4];
#pragma unroll
    for (int m = 0; m < 4; ++m)
#pragma unroll
        for (int n = 0; n < 4; ++n) acc[m][n] = (f32x4){0.f, 0.f, 0.f, 0.f};

    int srow = tid >> 2;
    int sseg = tid & 3;

    uint4 pv[8];
    auto stage_load = [&](int kt) {
        int k0 = kb + kt * 32;
#pragma unroll
        for (int s = 0; s < 8; ++s) {
            int tile = s >> 1, rep = s & 1;
            int row = srow + rep * 64;
            int grow = ((tile < 2) ? i0 : j0) + row;
            const ushort* src = (tile & 1) ? zR : zH;
            uint4 v = {0u, 0u, 0u, 0u};
            if (grow < CH_)
                v = *(const uint4*)(src + (size_t)grow * KBL_ + k0 + sseg * 8);
            pv[s] = v;
        }
    };
    auto stage_write = [&]() {
#pragma unroll
        for (int s = 0; s < 8; ++s) {
            int tile = s >> 1, rep = s & 1;
            int row = srow + rep * 64;
            ushort* dst = (tile == 0) ? &AH[row][sseg * 8]
                        : (tile == 1) ? &AR[row][sseg * 8]
                        : (tile == 2) ? &BH[row][sseg * 8]
                                      : &BR[row][sseg * 8];
            *(uint4*)dst = pv[s];
        }
    };

    stage_load(0);
    for (int t2 = 0; t2 < NT_; ++t2) {
        __syncthreads();
        stage_write();
        __syncthreads();
        if (t2 + 1 < NT_) stage_load(t2 + 1);

        bf16x8 ah[4], ar[4];
#pragma unroll
        for (int m = 0; m < 4; ++m) {
            ah[m] = *(const bf16x8*)&AH[wr * 64 + m * 16 + fr][g8 * 8];
            ar[m] = *(const bf16x8*)&AR[wr * 64 + m * 16 + fr][g8 * 8];
        }
#pragma unroll
        for (int n = 0; n < 4; ++n) {
            bf16x8 bh = *(const bf16x8*)&BH[wc * 64 + n * 16 + fr][g8 * 8];
            bf16x8 br = *(const bf16x8*)&BR[wc * 64 + n * 16 + fr][g8 * 8];
#pragma unroll
            for (int m = 0; m < 4; ++m) {
                acc[m][n] = __builtin_amdgcn_mfma_f32_16x16x32_bf16(ah[m], bh, acc[m][n], 0, 0, 0);
                acc[m][n] = __builtin_amdgcn_mfma_f32_16x16x32_bf16(ah[m], br, acc[m][n], 0, 0, 0);
                acc[m][n] = __builtin_amdgcn_mfma_f32_16x16x32_bf16(ar[m], bh, acc[m][n], 0, 0, 0);
            }
        }
    }

    float* gp = gpart + ((size_t)ksl * NTRI_ + t) * 16384;
#pragma unroll
    for (int m = 0; m < 4; ++m) {
        int rb = wr * 64 + m * 16 + g8 * 4;
#pragma unroll
        for (int n = 0; n < 4; ++n) {
            int c = wc * 64 + n * 16 + fr;
#pragma unroll
            for (int q = 0; q < 4; ++q)
                gp[(size_t)(rb + q) * 128 + c] = acc[m][n][q];
        }
    }
}

// ---------------- K3b: reduce 16 partials per tile, write G + mirror --------
__global__ __launch_bounds__(256) void k3b_sym(const float* __restrict__ gpart,
                                               float* __restrict__ g) {
    int t = blockIdx.x;          // 0..35
    int seg = blockIdx.y;        // 0..3
    int ti = 0, tt = t;
    while (tt >= 8 - ti) { tt -= 8 - ti; ++ti; }
    int tj = ti + tt;
    int i0 = ti * 128, j0 = tj * 128;
    int tid = threadIdx.x;
    int e0 = seg * 4096 + tid * 16;
    int r = e0 >> 7, c0 = e0 & 127;

    float4 s[4];
#pragma unroll
    for (int j = 0; j < 4; ++j) s[j] = (float4){0.f, 0.f, 0.f, 0.f};
#pragma unroll
    for (int p = 0; p < ZSPLIT_; ++p) {
        const float* src = gpart + ((size_t)p * NTRI_ + t) * 16384 + e0;
#pragma unroll
        for (int j = 0; j < 4; ++j) {
            float4 v = *(const float4*)(src + j * 4);
            s[j].x += v.x; s[j].y += v.y; s[j].z += v.z; s[j].w += v.w;
        }
    }
    int i = i0 + r;
    if (i < CH_) {
#pragma unroll
        for (int j = 0; j < 4; ++j) {
            int jc = j0 + c0 + j * 4;
            if (jc + 3 < CH_) {
                *(float4*)(g + (size_t)i * CH_ + jc) = s[j];
            } else {
#pragma unroll
                for (int e = 0; e < 4; ++e)
                    if (jc + e < CH_) g[(size_t)i * CH_ + jc + e] = ((const float*)&s[j])[e];
            }
        }
        if (ti != tj) {
#pragma unroll
            for (int j = 0; j < 4; ++j) {
#pragma unroll
                for (int e = 0; e < 4; ++e) {
                    int jc = j0 + c0 + j * 4 + e;
                    if (jc < CH_) g[(size_t)jc * CH_ + i] = ((const float*)&s[j])[e];
                }
            }
        }
    }
}

// ---------------- K4: cooperative k-means on the Gram matrix ----------------
__global__ __launch_bounds__(512) void k4_kmeans(const float* __restrict__ g,
                                                 int* __restrict__ labels,
                                                 float* __restrict__ tg,
                                                 int* __restrict__ changed) {
    cg::grid_group grid = cg::this_grid();
    __shared__ int   labl[1000];
    __shared__ float sED[32][4];
    __shared__ int   plab[32];
    __shared__ int   cntS[4];
    __shared__ float red[3][512];

    int tid = threadIdx.x;
    int base = blockIdx.x * 32;
    int pt = tid >> 4, sub = tid & 15;
    int i = base + pt;
    bool own = (i < CH_);

    if (tid < 32) plab[tid] = -1;
    if (own && sub == 0) {
        sED[pt][0] = g[(size_t)i * CH_ + 0];
        sED[pt][1] = g[(size_t)i * CH_ + 1];
        sED[pt][2] = g[(size_t)i * CH_ + 2];
    }
    float cc0 = g[0], cc1 = g[1 * CH_ + 1], cc2 = g[2 * CH_ + 2];
    __syncthreads();

    for (int it = 1; it <= ITERS_; ++it) {
        if (own && sub == 0) {
            float d0 = cc0 - 2.f * sED[pt][0];
            float d1 = cc1 - 2.f * sED[pt][1];
            float d2 = cc2 - 2.f * sED[pt][2];
            int nl = 0; float dm = d0;
            if (d1 < dm) { dm = d1; nl = 1; }
            if (d2 < dm) { dm = d2; nl = 2; }
            if (nl != plab[pt]) atomicAdd(&changed[it], 1);
            plab[pt] = nl;
            labels[i] = nl;
        }
        grid.sync();

        if (tid < 4) cntS[tid] = 0;
        __syncthreads();
        for (int idx = tid; idx < CH_; idx += 512) {
            int lb = labels[idx];
            labl[idx] = lb;
            atomicAdd(&cntS[lb], 1);
        }
        __syncthreads();

        float a0 = 0.f, a1 = 0.f, a2 = 0.f;
        if (own) {
            const float* gr = g + (size_t)i * CH_;
            for (int j = sub; j < CH_; j += 16) {
                float gv = gr[j];
                int lb = labl[j];
                a0 += (lb == 0) ? gv : 0.f;
                a1 += (lb == 1) ? gv : 0.f;
                a2 += (lb == 2) ? gv : 0.f;
            }
#pragma unroll
            for (int msk = 1; msk < 16; msk <<= 1) {
                a0 += __shfl_xor(a0, msk, 16);
                a1 += __shfl_xor(a1, msk, 16);
                a2 += __shfl_xor(a2, msk, 16);
            }
            if (sub == 0) {
                tg[i * 4 + 0] = a0; tg[i * 4 + 1] = a1; tg[i * 4 + 2] = a2;
            }
        }
        grid.sync();

        int chg = changed[it];
        int n0c = cntS[0], n1c = cntS[1], n2c = cntS[2];

        float p0 = 0.f, p1 = 0.f, p2 = 0.f;
        for (int idx = tid; idx < CH_; idx += 512) {
            int lb = labl[idx];
            float tv = tg[idx * 4 + lb];
            if (lb == 0) p0 += tv; else if (lb == 1) p1 += tv; else p2 += tv;
        }
        red[0][tid] = p0; red[1][tid] = p1; red[2][tid] = p2;
        __syncthreads();
        for (int off = 256; off > 0; off >>= 1) {
            if (tid < off) {
                red[0][tid] += red[0][tid + off];
                red[1][tid] += red[1][tid + off];
                red[2][tid] += red[2][tid + off];
            }
            __syncthreads();
        }
        float s0 = red[0][0], s1 = red[1][0], s2 = red[2][0];

        if (n0c > 0) cc0 = s0 / ((float)n0c * (float)n0c);
        if (n1c > 0) cc1 = s1 / ((float)n1c * (float)n1c);
        if (n2c > 0) cc2 = s2 / ((float)n2c * (float)n2c);
        if (own && sub == 0) {
            if (n0c > 0) sED[pt][0] = a0 / (float)n0c;
            if (n1c > 0) sED[pt][1] = a1 / (float)n1c;
            if (n2c > 0) sED[pt][2] = a2 / (float)n2c;
        }
        __syncthreads();

        if (chg == 0 && it > 1) break;
    }

    if (own && sub == 0) {
        float d0 = cc0 - 2.f * sED[pt][0];
        float d1 = cc1 - 2.f * sED[pt][1];
        float d2 = cc2 - 2.f * sED[pt][2];
        int nl = 0; float dm = d0;
        if (d1 < dm) { dm = d1; nl = 1; }
        if (d2 < dm) { dm = d2; nl = 2; }
        labels[i] = nl;
    }
}

// ---------------- K4b: build label-sorted channel permutation ---------------
__global__ __launch_bounds__(256) void k4b_perm(const int* __restrict__ labels,
                                                int* __restrict__ chlist,
                                                int* __restrict__ chpos,
                                                int* __restrict__ slabel) {
    __shared__ int cnt[3], st[4], c2[3];
    int tid = threadIdx.x;
    if (tid < 3) { cnt[tid] = 0; c2[tid] = 0; }
    __syncthreads();
    for (int n = tid; n < CH_; n += 256) atomicAdd(&cnt[labels[n]], 1);
    __syncthreads();
    if (tid == 0) {
        st[0] = 0;
        st[1] = ((cnt[0] + 3) >> 2) << 2;
        st[2] = st[1] + (((cnt[1] + 3) >> 2) << 2);
        st[3] = st[2] + (((cnt[2] + 3) >> 2) << 2);
    }
    __syncthreads();
    for (int s = tid; s < SLOTS_; s += 256) chlist[s] = 0;
    for (int t = tid; t < NTILES_; t += 256) {
        int s = t * 4;
        slabel[t] = (s < st[1]) ? 0 : (s < st[2]) ? 1 : (s < st[3]) ? 2 : 0;
    }
    __syncthreads();
    for (int n = tid; n < CH_; n += 256) {
        int lb = labels[n];
        int r = atomicAdd(&c2[lb], 1);
        int slot = st[lb] + r;
        chlist[slot] = n;
        chpos[n] = slot;
    }
}

// ---------------- K5: grouped GEMM  C[sb=128][p=64] = Z_tile . WB2[lab]^T ---
__global__ __launch_bounds__(256) void k5_grouped(const ushort* __restrict__ zLH,
                                                  const ushort* __restrict__ zUH,
                                                  const ushort* __restrict__ WB2,
                                                  const int* __restrict__ chlist,
                                                  const int* __restrict__ slabel,
                                                  const float* __restrict__ bg,
                                                  const float* __restrict__ bu,
                                                  const float* __restrict__ meanT,
                                                  const float* __restrict__ sstdT,
                                                  float* __restrict__ outP) {
    __shared__ __align__(16) ushort ZT[128][40];
    __shared__ __align__(16) ushort WT[64][40];
    __shared__ int sch[4];

    int tile = blockIdx.x;
    int p0 = blockIdx.y * 64;
    int tid = threadIdx.x;
    if (tid < 4) sch[tid] = chlist[tile * 4 + tid];
    int lab = slabel[tile];
    __syncthreads();

    int lane = tid & 63, wid = tid >> 6;
    int wr = wid >> 1, wc = wid & 1;
    int fr = lane & 15, g8 = lane >> 4;

    int srow = tid >> 2, sseg = tid & 3;
    size_t zb0, zb1;
    {
        int r0 = srow;      zb0 = (size_t)sch[r0 >> 5] * KBL_ + (size_t)(r0 & 31) * LH_;
        int r1 = srow + 64; zb1 = (size_t)sch[r1 >> 5] * KBL_ + (size_t)(r1 & 31) * LH_;
    }
    const ushort* wrow = WB2 + (size_t)(lab * PRED_ + p0 + srow) * 1024;

    f32x4 acc[4][2];
#pragma unroll
    for (int m = 0; m < 4; ++m)
#pragma unroll
        for (int n = 0; n < 2; ++n) acc[m][n] = (f32x4){0.f, 0.f, 0.f, 0.f};

    uint4 pz0, pz1, pw;
    auto stage_load = [&](int t) {
        const ushort* zsrc = (t < 16) ? zLH : zUH;
        int ko = ((t & 15) * 32) + sseg * 8;
        pz0 = *(const uint4*)(zsrc + zb0 + ko);
        pz1 = *(const uint4*)(zsrc + zb1 + ko);
        pw  = *(const uint4*)(wrow + t * 32 + sseg * 8);
    };
    auto stage_write = [&]() {
        *(uint4*)&ZT[srow][sseg * 8] = pz0;
        *(uint4*)&ZT[srow + 64][sseg * 8] = pz1;
        *(uint4*)&WT[srow][sseg * 8] = pw;
    };

    stage_load(0);
    for (int t = 0; t < 32; ++t) {
        __syncthreads();
        stage_write();
        __syncthreads();
        if (t + 1 < 32) stage_load(t + 1);

        bf16x8 a[4];
#pragma unroll
        for (int m = 0; m < 4; ++m)
            a[m] = *(const bf16x8*)&ZT[wr * 64 + m * 16 + fr][g8 * 8];
#pragma unroll
        for (int nf = 0; nf < 2; ++nf) {
            bf16x8 bv = *(const bf16x8*)&WT[wc * 32 + nf * 16 + fr][g8 * 8];
#pragma unroll
            for (int m = 0; m < 4; ++m)
                acc[m][nf] = __builtin_amdgcn_mfma_f32_16x16x32_bf16(a[m], bv, acc[m][nf], 0, 0, 0);
        }
    }

#pragma unroll
    for (int m = 0; m < 4; ++m) {
#pragma unroll
        for (int q = 0; q < 4; ++q) {
            int sb = wr * 64 + m * 16 + g8 * 4 + q;
            int sl = sb >> 5, b = sb & 31;
            int n = sch[sl];
            float sd = sstdT[n * B_ + b], mu = meanT[n * B_ + b];
            size_t obase = ((size_t)(tile * 4 + sl) * B_ + b) * PRED_;
#pragma unroll
            for (int nf = 0; nf < 2; ++nf) {
                int p = p0 + wc * 32 + nf * 16 + fr;
                float v = acc[m][nf][q] + bg[lab * PRED_ + p] + bu[p];
                outP[obase + p] = v * sd + mu;
            }
        }
    }
}

// ---------------- K7: unpermute outP -> out[b][p][n] ------------------------
__global__ __launch_bounds__(256) void k7_unperm(const float* __restrict__ outP,
                                                 const int* __restrict__ chpos,
                                                 float* __restrict__ out) {
    int n = blockIdx.x * 256 + threadIdx.x;
    int p0 = blockIdx.y * 32;
    int b = blockIdx.z;
    if (n >= CH_) return;
    const float* src = outP + ((size_t)chpos[n] * B_ + b) * PRED_ + p0;
    float4 v[8];
#pragma unroll
    for (int j = 0; j < 8; ++j) v[j] = *(const float4*)(src + j * 4);
#pragma unroll
    for (int j = 0; j < 8; ++j) {
#pragma unroll
        for (int e = 0; e < 4; ++e) {
            int p = p0 + j * 4 + e;
            out[((size_t)b * PRED_ + p) * CH_ + n] = ((const float*)&v[j])[e];
        }
    }
}

extern "C" void kernel_launch(void* const* d_in, const int* in_sizes, int n_in,
                              void* d_out, int out_size, void* d_ws, size_t ws_size,
                              hipStream_t stream) {
    const float* x  = (const float*)d_in[0];
    const float* Wg = (const float*)d_in[4];
    const float* bg = (const float*)d_in[5];
    const float* Wu = (const float*)d_in[6];
    const float* bu = (const float*)d_in[7];
    float* out = (float*)d_out;
    (void)in_sizes; (void)n_in; (void)out_size; (void)ws_size;

    char* ws = (char*)d_ws;
    size_t off = 0;
    auto alloc = [&](size_t bytes) {
        void* p = ws + off;
        off = (off + bytes + 255) & ~(size_t)255;
        return p;
    };
    ushort* zLH  = (ushort*)alloc((size_t)16384000 * 2);
    ushort* zLR  = (ushort*)alloc((size_t)16384000 * 2);
    ushort* zUH  = (ushort*)alloc((size_t)16384000 * 2);
    float*  G    = (float*)alloc((size_t)1000000 * 4);
    ushort* WB2  = (ushort*)alloc((size_t)576 * 1024 * 2);
    float*  meanT = (float*)alloc((size_t)32000 * 4);
    float*  sstdT = (float*)alloc((size_t)32000 * 4);
    float*  invT  = (float*)alloc((size_t)32000 * 4);
    float*  pS   = (float*)alloc((size_t)SEG_ * B_ * CH_ * 4);
    float*  pSS  = (float*)alloc((size_t)SEG_ * B_ * CH_ * 4);
    int*    labels  = (int*)alloc((size_t)1024 * 4);
    float*  tg   = (float*)alloc((size_t)4096 * 4);
    int*    changed = (int*)alloc((size_t)64 * 4);
    int*    chlist = (int*)alloc((size_t)SLOTS_ * 4);
    int*    chpos  = (int*)alloc((size_t)1024 * 4);
    int*    slabel = (int*)alloc((size_t)256 * 4);
    // union region: Gp (16*36*16384*4 = 37.7 MB, dead after k3b) then outP (24.9 MB)
    char* unionBase = (char*)alloc((size_t)ZSPLIT_ * NTRI_ * 16384 * 4);
    float* Gp   = (float*)unionBase;
    float* outP = (float*)unionBase;

    hipMemsetAsync(changed, 0, 64 * 4, stream);
    k1_partial<<<dim3(SEG_, 32), 256, 0, stream>>>(x, pS, pSS);
    k1b_reduce<<<125, 256, 0, stream>>>(pS, pSS, meanT, sstdT, invT);
    k2_build<<<dim3(32, 16, 32), 256, 0, stream>>>(x, meanT, invT, zLH, zLR, zUH);
    k0_wprep<<<576, 256, 0, stream>>>(Wg, Wu, WB2);
    k3_mfma<<<8 * NTRI_ * 2, 256, 0, stream>>>(zLH, zLR, Gp);
    k3b_sym<<<dim3(NTRI_, 4), 256, 0, stream>>>(Gp, G);
    void* args[] = { (void*)&G, (void*)&labels, (void*)&tg, (void*)&changed };
    hipLaunchCooperativeKernel((void*)k4_kmeans, dim3(32), dim3(512), args, 0, stream);
    k4b_perm<<<1, 256, 0, stream>>>(labels, chlist, chpos, slabel);
    k5_grouped<<<dim3(NTILES_, 3), 256, 0, stream>>>(zLH, zUH, WB2, chlist, slabel,
                                                     bg, bu, meanT, sstdT, outP);
    k7_unperm<<<dim3(4, 6, 32), 256, 0, stream>>>(outP, chpos, out);
}

// Round 7
// 277.451 us; speedup vs baseline: 8.4837x; 1.1089x over previous
//
#include <hip/hip_runtime.h>
#include <hip/hip_bf16.h>
#include <hip/hip_cooperative_groups.h>

namespace cg = cooperative_groups;

#define B_   32
#define L_   1024
#define LH_  512
#define CH_  1000
#define PRED_ 192
#define ITERS_ 50
#define KBL_ 16384   // B_*LH_
#define SLOTS_ 1012
#define NTILES_ 253
#define NT2_ 506     // 2-slot tiles for k5
#define NTRI_ 36     // upper-triangle 8x8 tile pairs
#define SEG_ 16      // L-segments for stats partials

typedef __attribute__((ext_vector_type(8))) short bf16x8;
typedef __attribute__((ext_vector_type(4))) float f32x4;

// ---------------- K1a: partial sums over 64-row segments --------------------
__global__ __launch_bounds__(256) void k1_partial(const float* __restrict__ x,
                                                  float* __restrict__ pS,
                                                  float* __restrict__ pSS) {
    int seg = blockIdx.x;        // 0..15
    int b = blockIdx.y;          // 0..31
    int t = threadIdx.x;
    if (t >= 250) return;
    int c4 = t * 4;
    const float* xp = x + (size_t)b * L_ * CH_ + (size_t)seg * 64 * CH_ + c4;
    float4 s = {0.f, 0.f, 0.f, 0.f}, ss = {0.f, 0.f, 0.f, 0.f};
#pragma unroll 4
    for (int l = 0; l < 64; ++l) {
        float4 v = *(const float4*)(xp + (size_t)l * CH_);
        s.x += v.x; s.y += v.y; s.z += v.z; s.w += v.w;
        ss.x += v.x * v.x; ss.y += v.y * v.y; ss.z += v.z * v.z; ss.w += v.w * v.w;
    }
    size_t o = ((size_t)seg * B_ + b) * CH_ + c4;
    *(float4*)(pS + o) = s;
    *(float4*)(pSS + o) = ss;
}

// ---------------- K1b: reduce partials -> mean / std ------------------------
__global__ __launch_bounds__(256) void k1b_reduce(const float* __restrict__ pS,
                                                  const float* __restrict__ pSS,
                                                  float* __restrict__ meanT,
                                                  float* __restrict__ sstdT,
                                                  float* __restrict__ invT) {
    int idx = blockIdx.x * 256 + threadIdx.x;
    if (idx >= B_ * CH_) return;
    int c = idx % CH_;
    int b = idx / CH_;
    float s = 0.f, ss = 0.f;
#pragma unroll
    for (int seg = 0; seg < SEG_; ++seg) {
        size_t o = ((size_t)seg * B_ + b) * CH_ + c;
        s += pS[o];
        ss += pSS[o];
    }
    float m = s * (1.0f / L_);
    float var = (ss - (float)L_ * m * m) * (1.0f / (L_ - 1)) + 1e-5f;
    float sd = sqrtf(var);
    meanT[c * B_ + b] = m;
    sstdT[c * B_ + b] = sd;
    invT[c * B_ + b] = 1.0f / sd;
}

// ---------------- K2: build bf16 z_L (split) + z_U in [n][b][lh] layout -----
__global__ __launch_bounds__(256) void k2_build(const float* __restrict__ x,
                                                const float* __restrict__ meanT,
                                                const float* __restrict__ invT,
                                                ushort* __restrict__ zLH,
                                                ushort* __restrict__ zLR,
                                                ushort* __restrict__ zUH) {
    __shared__ float Ls[32][33];
    __shared__ float Us[32][33];
    int tid = threadIdx.x;
    int tx = tid & 31, ty = tid >> 5;
    int n0 = blockIdx.x * 32;
    int lh0 = blockIdx.y * 32;
    int b = blockIdx.z;
    int n = n0 + tx;
    float m = 0.f, iv = 0.f;
    if (n < CH_) { m = meanT[n * B_ + b]; iv = invT[n * B_ + b]; }
    for (int r = 0; r < 4; ++r) {
        int lh = lh0 + ty + 8 * r;
        float v0 = 0.f, v1 = 0.f;
        if (n < CH_) {
            v0 = x[((size_t)b * L_ + 2 * lh) * CH_ + n];
            v1 = x[((size_t)b * L_ + 2 * lh + 1) * CH_ + n];
        }
        float a = (v0 - m) * iv * 0.5f;
        float c2 = (v1 - m) * iv * 0.5f;
        Ls[ty + 8 * r][tx] = a + c2;
        Us[ty + 8 * r][tx] = a - c2;
    }
    __syncthreads();
    for (int r = 0; r < 4; ++r) {
        int nl = ty + 8 * r;
        int nn = n0 + nl;
        if (nn < CH_) {
            size_t dst = (size_t)nn * KBL_ + (size_t)b * LH_ + lh0 + tx;
            float lv = Ls[tx][nl];
            float uv = Us[tx][nl];
            __hip_bfloat16 h = __float2bfloat16(lv);
            float hf = __bfloat162float(h);
            __hip_bfloat16 rr = __float2bfloat16(lv - hf);
            __hip_bfloat16 uh = __float2bfloat16(uv);
            zLH[dst] = *(ushort*)&h;
            zLR[dst] = *(ushort*)&rr;
            zUH[dst] = *(ushort*)&uh;
        }
    }
}

// ---------------- K0w: stacked weights WB2[lab][192][1024] = [Wg[lab]|Wu] ---
__global__ __launch_bounds__(256) void k0_wprep(const float* __restrict__ Wg,
                                                const float* __restrict__ Wu,
                                                ushort* __restrict__ WB2) {
    int r = blockIdx.x;          // 0..575 = lab*192+p
    int p = r % PRED_;
    int tid = threadIdx.x;
#pragma unroll
    for (int i = 0; i < 4; ++i) {
        int k = i * 256 + tid;   // 0..1023
        float w = (k < 512) ? Wg[(size_t)r * LH_ + k]
                            : Wu[(size_t)p * LH_ + (k - 512)];
        __hip_bfloat16 h = __float2bfloat16(w);
        WB2[(size_t)r * 1024 + k] = *(ushort*)&h;
    }
}

// ---------------- K3: symmetric Gram via split-bf16 MFMA --------------------
#define ZSPLIT_ 16
#define KSEG_   1024
#define NT_     (KSEG_ / 32)

__global__ __launch_bounds__(256) void k3_mfma(const ushort* __restrict__ zH,
                                               const ushort* __restrict__ zR,
                                               float* __restrict__ gpart) {
    __shared__ __align__(16) ushort AH[128][40];
    __shared__ __align__(16) ushort AR[128][40];
    __shared__ __align__(16) ushort BH[128][40];
    __shared__ __align__(16) ushort BR[128][40];

    int bid = blockIdx.x;
    int xcd = bid & 7, w = bid >> 3;           // w in 0..71
    int ksl = 2 * xcd + (w >= NTRI_);
    int t = (w >= NTRI_) ? w - NTRI_ : w;
    int ti = 0, tt = t;
    while (tt >= 8 - ti) { tt -= 8 - ti; ++ti; }
    int tj = ti + tt;
    int i0 = ti * 128, j0 = tj * 128;
    int kb = ksl * KSEG_;

    int tid = threadIdx.x;
    int lane = tid & 63;
    int wid = tid >> 6;
    int wr = wid >> 1, wc = wid & 1;
    int fr = lane & 15;
    int g8 = lane >> 4;

    f32x4 acc[4][4];
#pragma unroll
    for (int m = 0; m < 4; ++m)
#pragma unroll
        for (int n = 0; n < 4; ++n) acc[m][n] = (f32x4){0.f, 0.f, 0.f, 0.f};

    int srow = tid >> 2;
    int sseg = tid & 3;

    uint4 pv[8];
    auto stage_load = [&](int kt) {
        int k0 = kb + kt * 32;
#pragma unroll
        for (int s = 0; s < 8; ++s) {
            int tile = s >> 1, rep = s & 1;
            int row = srow + rep * 64;
            int grow = ((tile < 2) ? i0 : j0) + row;
            const ushort* src = (tile & 1) ? zR : zH;
            uint4 v = {0u, 0u, 0u, 0u};
            if (grow < CH_)
                v = *(const uint4*)(src + (size_t)grow * KBL_ + k0 + sseg * 8);
            pv[s] = v;
        }
    };
    auto stage_write = [&]() {
#pragma unroll
        for (int s = 0; s < 8; ++s) {
            int tile = s >> 1, rep = s & 1;
            int row = srow + rep * 64;
            ushort* dst = (tile == 0) ? &AH[row][sseg * 8]
                        : (tile == 1) ? &AR[row][sseg * 8]
                        : (tile == 2) ? &BH[row][sseg * 8]
                                      : &BR[row][sseg * 8];
            *(uint4*)dst = pv[s];
        }
    };

    stage_load(0);
    for (int t2 = 0; t2 < NT_; ++t2) {
        __syncthreads();
        stage_write();
        __syncthreads();
        if (t2 + 1 < NT_) stage_load(t2 + 1);

        bf16x8 ah[4], ar[4];
#pragma unroll
        for (int m = 0; m < 4; ++m) {
            ah[m] = *(const bf16x8*)&AH[wr * 64 + m * 16 + fr][g8 * 8];
            ar[m] = *(const bf16x8*)&AR[wr * 64 + m * 16 + fr][g8 * 8];
        }
#pragma unroll
        for (int n = 0; n < 4; ++n) {
            bf16x8 bh = *(const bf16x8*)&BH[wc * 64 + n * 16 + fr][g8 * 8];
            bf16x8 br = *(const bf16x8*)&BR[wc * 64 + n * 16 + fr][g8 * 8];
#pragma unroll
            for (int m = 0; m < 4; ++m) {
                acc[m][n] = __builtin_amdgcn_mfma_f32_16x16x32_bf16(ah[m], bh, acc[m][n], 0, 0, 0);
                acc[m][n] = __builtin_amdgcn_mfma_f32_16x16x32_bf16(ah[m], br, acc[m][n], 0, 0, 0);
                acc[m][n] = __builtin_amdgcn_mfma_f32_16x16x32_bf16(ar[m], bh, acc[m][n], 0, 0, 0);
            }
        }
    }

    float* gp = gpart + ((size_t)ksl * NTRI_ + t) * 16384;
#pragma unroll
    for (int m = 0; m < 4; ++m) {
        int rb = wr * 64 + m * 16 + g8 * 4;
#pragma unroll
        for (int n = 0; n < 4; ++n) {
            int c = wc * 64 + n * 16 + fr;
#pragma unroll
            for (int q = 0; q < 4; ++q)
                gp[(size_t)(rb + q) * 128 + c] = acc[m][n][q];
        }
    }
}

// ---------------- K3b: reduce 16 partials per tile, write G + mirror --------
__global__ __launch_bounds__(256) void k3b_sym(const float* __restrict__ gpart,
                                               float* __restrict__ g) {
    int t = blockIdx.x;          // 0..35
    int seg = blockIdx.y;        // 0..3
    int ti = 0, tt = t;
    while (tt >= 8 - ti) { tt -= 8 - ti; ++ti; }
    int tj = ti + tt;
    int i0 = ti * 128, j0 = tj * 128;
    int tid = threadIdx.x;
    int e0 = seg * 4096 + tid * 16;
    int r = e0 >> 7, c0 = e0 & 127;

    float4 s[4];
#pragma unroll
    for (int j = 0; j < 4; ++j) s[j] = (float4){0.f, 0.f, 0.f, 0.f};
#pragma unroll
    for (int p = 0; p < ZSPLIT_; ++p) {
        const float* src = gpart + ((size_t)p * NTRI_ + t) * 16384 + e0;
#pragma unroll
        for (int j = 0; j < 4; ++j) {
            float4 v = *(const float4*)(src + j * 4);
            s[j].x += v.x; s[j].y += v.y; s[j].z += v.z; s[j].w += v.w;
        }
    }
    int i = i0 + r;
    if (i < CH_) {
#pragma unroll
        for (int j = 0; j < 4; ++j) {
            int jc = j0 + c0 + j * 4;
            if (jc + 3 < CH_) {
                *(float4*)(g + (size_t)i * CH_ + jc) = s[j];
            } else {
#pragma unroll
                for (int e = 0; e < 4; ++e)
                    if (jc + e < CH_) g[(size_t)i * CH_ + jc + e] = ((const float*)&s[j])[e];
            }
        }
        if (ti != tj) {
#pragma unroll
            for (int j = 0; j < 4; ++j) {
#pragma unroll
                for (int e = 0; e < 4; ++e) {
                    int jc = j0 + c0 + j * 4 + e;
                    if (jc < CH_) g[(size_t)jc * CH_ + i] = ((const float*)&s[j])[e];
                }
            }
        }
    }
}

// ---------------- K4a: init s[i][k] = G[i][k], ccG = diag -------------------
__global__ __launch_bounds__(256) void k4a_init(const float* __restrict__ g,
                                                float* __restrict__ sbuf,
                                                float* __restrict__ ccG) {
    int i = blockIdx.x * 256 + threadIdx.x;
    if (i < CH_) {
        sbuf[i * 3 + 0] = g[(size_t)i * CH_ + 0];
        sbuf[i * 3 + 1] = g[(size_t)i * CH_ + 1];
        sbuf[i * 3 + 2] = g[(size_t)i * CH_ + 2];
    }
    if (i < 3) ccG[i] = g[(size_t)i * CH_ + i];
}

// ---------------- K4: cooperative k-means, ONE grid.sync per iter -----------
// Every block redundantly computes all 1000 labels (identical deterministic
// arithmetic) from double-buffered global s[par][i][k]; only the t-update
// crosses blocks (via the parity-flipped buffer, separated by grid.sync).
__global__ __launch_bounds__(1024) void k4_kmeans(const float* __restrict__ g,
                                                  float* __restrict__ sbuf,
                                                  float* __restrict__ ccG,
                                                  int* __restrict__ labels) {
    cg::grid_group grid = cg::this_grid();
    __shared__ int   lab[1024];
    __shared__ float red[3][1024];
    __shared__ int   cnt[4], cnt2[4], chgS;

    int tid = threadIdx.x;
    int bpt0 = blockIdx.x * 64;
    lab[tid] = (tid < 3) ? tid : 3;     // sentinel 3 = unassigned
    __syncthreads();

    int par = 0;
    for (int it = 1; it <= ITERS_ + 1; ++it) {
        const float* sp = sbuf + par * 3 * CH_;
        // ---- phase 1: counts of prev labels + cc reduction ----
        if (tid < 4) { cnt[tid] = 0; cnt2[tid] = 0; }
        if (tid == 0) chgS = 0;
        __syncthreads();
        float c0 = 0.f, c1 = 0.f, c2 = 0.f;
        int lbp = 3;
        if (tid < CH_) {
            lbp = lab[tid];
            atomicAdd(&cnt[lbp], 1);
            if (lbp < 3) {
                float sv = sp[tid * 3 + lbp];
                if (lbp == 0) c0 = sv; else if (lbp == 1) c1 = sv; else c2 = sv;
            }
        }
        red[0][tid] = c0; red[1][tid] = c1; red[2][tid] = c2;
        __syncthreads();
        for (int off = 512; off > 0; off >>= 1) {
            if (tid < off) {
                red[0][tid] += red[0][tid + off];
                red[1][tid] += red[1][tid + off];
                red[2][tid] += red[2][tid + off];
            }
            __syncthreads();
        }
        int n0 = cnt[0], n1 = cnt[1], n2 = cnt[2];
        float cc0 = (n0 > 0) ? red[0][0] / (float)n0 : ccG[par * 3 + 0];
        float cc1 = (n1 > 0) ? red[1][0] / (float)n1 : ccG[par * 3 + 1];
        float cc2 = (n2 > 0) ? red[2][0] / (float)n2 : ccG[par * 3 + 2];
        if (tid == 0) ccG[(par ^ 1) * 3 + 0] = cc0;
        if (tid == 1) ccG[(par ^ 1) * 3 + 1] = cc1;
        if (tid == 2) ccG[(par ^ 1) * 3 + 2] = cc2;

        // ---- assign all points (redundant in every block) ----
        int myNew = -1;
        if (tid < CH_) {
            float d0 = cc0 - 2.f * sp[tid * 3 + 0];
            float d1 = cc1 - 2.f * sp[tid * 3 + 1];
            float d2 = cc2 - 2.f * sp[tid * 3 + 2];
            int nl = 0; float dm = d0;
            if (d1 < dm) { dm = d1; nl = 1; }
            if (d2 < dm) { dm = d2; nl = 2; }
            if (nl != lbp) atomicAdd(&chgS, 1);
            myNew = nl;
        }
        __syncthreads();
        if (tid < CH_) { lab[tid] = myNew; atomicAdd(&cnt2[myNew], 1); }
        __syncthreads();

        if (it == ITERS_ + 1) break;          // 51st (final) assign done
        if (chgS == 0 && it > 1) break;       // converged: labels stable

        // ---- phase 3: update own 64 points' t/n into other buffer ----
        int n0n = cnt2[0], n1n = cnt2[1], n2n = cnt2[2];
        float* sq = sbuf + (par ^ 1) * 3 * CH_;
        int i = bpt0 + (tid >> 4);
        int sub = tid & 15;
        if (i < CH_) {
            const float* gr = g + (size_t)i * CH_;
            float a0 = 0.f, a1 = 0.f, a2 = 0.f;
            for (int j = sub; j < CH_; j += 16) {
                float gv = gr[j];
                int lb = lab[j];
                a0 += (lb == 0) ? gv : 0.f;
                a1 += (lb == 1) ? gv : 0.f;
                a2 += (lb == 2) ? gv : 0.f;
            }
#pragma unroll
            for (int msk = 1; msk < 16; msk <<= 1) {
                a0 += __shfl_xor(a0, msk, 16);
                a1 += __shfl_xor(a1, msk, 16);
                a2 += __shfl_xor(a2, msk, 16);
            }
            if (sub == 0) {
                sq[i * 3 + 0] = (n0n > 0) ? a0 / (float)n0n : sp[i * 3 + 0];
                sq[i * 3 + 1] = (n1n > 0) ? a1 / (float)n1n : sp[i * 3 + 1];
                sq[i * 3 + 2] = (n2n > 0) ? a2 / (float)n2n : sp[i * 3 + 2];
            }
        }
        par ^= 1;
        grid.sync();
    }

    // ---- write final labels (own range; lab identical in all blocks) ----
    if (tid < 64) {
        int i = bpt0 + tid;
        if (i < CH_) labels[i] = lab[i];
    }
}

// ---------------- K4b: build label-sorted channel permutation ---------------
__global__ __launch_bounds__(256) void k4b_perm(const int* __restrict__ labels,
                                                int* __restrict__ chlist,
                                                int* __restrict__ chpos,
                                                int* __restrict__ slabel) {
    __shared__ int cnt[3], st[4], c2[3];
    int tid = threadIdx.x;
    if (tid < 3) { cnt[tid] = 0; c2[tid] = 0; }
    __syncthreads();
    for (int n = tid; n < CH_; n += 256) atomicAdd(&cnt[labels[n]], 1);
    __syncthreads();
    if (tid == 0) {
        st[0] = 0;
        st[1] = ((cnt[0] + 3) >> 2) << 2;
        st[2] = st[1] + (((cnt[1] + 3) >> 2) << 2);
        st[3] = st[2] + (((cnt[2] + 3) >> 2) << 2);
    }
    __syncthreads();
    for (int s = tid; s < SLOTS_; s += 256) chlist[s] = 0;
    for (int t = tid; t < NTILES_; t += 256) {
        int s = t * 4;
        slabel[t] = (s < st[1]) ? 0 : (s < st[2]) ? 1 : (s < st[3]) ? 2 : 0;
    }
    __syncthreads();
    for (int n = tid; n < CH_; n += 256) {
        int lb = labels[n];
        int r = atomicAdd(&c2[lb], 1);
        int slot = st[lb] + r;
        chlist[slot] = n;
        chpos[n] = slot;
    }
}

// ---------------- K5: grouped GEMM  C[64 sb][192 p] = Z_tile . WB2[lab]^T ---
// 2-slot tiles (506 blocks); Z staged once, full-p per block; fused epilogue.
__global__ __launch_bounds__(256) void k5_grouped(const ushort* __restrict__ zLH,
                                                  const ushort* __restrict__ zUH,
                                                  const ushort* __restrict__ WB2,
                                                  const int* __restrict__ chlist,
                                                  const int* __restrict__ slabel,
                                                  const float* __restrict__ bg,
                                                  const float* __restrict__ bu,
                                                  const float* __restrict__ meanT,
                                                  const float* __restrict__ sstdT,
                                                  float* __restrict__ outP) {
    __shared__ __align__(16) ushort ZT[64][40];
    __shared__ __align__(16) ushort WT[192][40];
    __shared__ int sch[2];

    int tile = blockIdx.x;               // 0..505
    int tid = threadIdx.x;
    if (tid < 2) sch[tid] = chlist[tile * 2 + tid];
    int lab = slabel[tile >> 1];
    __syncthreads();

    int lane = tid & 63, wid = tid >> 6; // wid = p-quarter (48 p each)
    int fr = lane & 15, g8 = lane >> 4;

    int srow = tid >> 2, sseg = tid & 3; // srow 0..63
    size_t zb = (size_t)sch[srow >> 5] * KBL_ + (size_t)(srow & 31) * LH_;
    const ushort* wbase = WB2 + (size_t)(lab * PRED_) * 1024;

    f32x4 acc[4][3];
#pragma unroll
    for (int m = 0; m < 4; ++m)
#pragma unroll
        for (int n = 0; n < 3; ++n) acc[m][n] = (f32x4){0.f, 0.f, 0.f, 0.f};

    uint4 pz, pw0, pw1, pw2;
    auto stage_load = [&](int t) {
        const ushort* zsrc = (t < 16) ? zLH : zUH;
        int ko = ((t & 15) * 32) + sseg * 8;
        pz  = *(const uint4*)(zsrc + zb + ko);
        int kw = t * 32 + sseg * 8;
        pw0 = *(const uint4*)(wbase + (size_t)srow * 1024 + kw);
        pw1 = *(const uint4*)(wbase + (size_t)(srow + 64) * 1024 + kw);
        pw2 = *(const uint4*)(wbase + (size_t)(srow + 128) * 1024 + kw);
    };
    auto stage_write = [&]() {
        *(uint4*)&ZT[srow][sseg * 8] = pz;
        *(uint4*)&WT[srow][sseg * 8] = pw0;
        *(uint4*)&WT[srow + 64][sseg * 8] = pw1;
        *(uint4*)&WT[srow + 128][sseg * 8] = pw2;
    };

    stage_load(0);
    for (int t = 0; t < 32; ++t) {
        __syncthreads();
        stage_write();
        __syncthreads();
        if (t + 1 < 32) stage_load(t + 1);

        bf16x8 a[4];
#pragma unroll
        for (int m = 0; m < 4; ++m)
            a[m] = *(const bf16x8*)&ZT[m * 16 + fr][g8 * 8];
#pragma unroll
        for (int nf = 0; nf < 3; ++nf) {
            bf16x8 bv = *(const bf16x8*)&WT[wid * 48 + nf * 16 + fr][g8 * 8];
#pragma unroll
            for (int m = 0; m < 4; ++m)
                acc[m][nf] = __builtin_amdgcn_mfma_f32_16x16x32_bf16(a[m], bv, acc[m][nf], 0, 0, 0);
        }
    }

#pragma unroll
    for (int m = 0; m < 4; ++m) {
#pragma unroll
        for (int q = 0; q < 4; ++q) {
            int sb = m * 16 + g8 * 4 + q;
            int sl = sb >> 5, b = sb & 31;
            int n = sch[sl];
            float sd = sstdT[n * B_ + b], mu = meanT[n * B_ + b];
            size_t obase = ((size_t)(tile * 2 + sl) * B_ + b) * PRED_;
#pragma unroll
            for (int nf = 0; nf < 3; ++nf) {
                int p = wid * 48 + nf * 16 + fr;
                float v = acc[m][nf][q] + bg[lab * PRED_ + p] + bu[p];
                outP[obase + p] = v * sd + mu;
            }
        }
    }
}

// ---------------- K7: unpermute outP -> out[b][p][n] ------------------------
__global__ __launch_bounds__(256) void k7_unperm(const float* __restrict__ outP,
                                                 const int* __restrict__ chpos,
                                                 float* __restrict__ out) {
    int n = blockIdx.x * 256 + threadIdx.x;
    int p0 = blockIdx.y * 32;
    int b = blockIdx.z;
    if (n >= CH_) return;
    const float* src = outP + ((size_t)chpos[n] * B_ + b) * PRED_ + p0;
    float4 v[8];
#pragma unroll
    for (int j = 0; j < 8; ++j) v[j] = *(const float4*)(src + j * 4);
#pragma unroll
    for (int j = 0; j < 8; ++j) {
#pragma unroll
        for (int e = 0; e < 4; ++e) {
            int p = p0 + j * 4 + e;
            out[((size_t)b * PRED_ + p) * CH_ + n] = ((const float*)&v[j])[e];
        }
    }
}

extern "C" void kernel_launch(void* const* d_in, const int* in_sizes, int n_in,
                              void* d_out, int out_size, void* d_ws, size_t ws_size,
                              hipStream_t stream) {
    const float* x  = (const float*)d_in[0];
    const float* Wg = (const float*)d_in[4];
    const float* bg = (const float*)d_in[5];
    const float* Wu = (const float*)d_in[6];
    const float* bu = (const float*)d_in[7];
    float* out = (float*)d_out;
    (void)in_sizes; (void)n_in; (void)out_size; (void)ws_size;

    char* ws = (char*)d_ws;
    size_t off = 0;
    auto alloc = [&](size_t bytes) {
        void* p = ws + off;
        off = (off + bytes + 255) & ~(size_t)255;
        return p;
    };
    ushort* zLH  = (ushort*)alloc((size_t)16384000 * 2);
    ushort* zLR  = (ushort*)alloc((size_t)16384000 * 2);
    ushort* zUH  = (ushort*)alloc((size_t)16384000 * 2);
    float*  G    = (float*)alloc((size_t)1000000 * 4);
    ushort* WB2  = (ushort*)alloc((size_t)576 * 1024 * 2);
    float*  meanT = (float*)alloc((size_t)32000 * 4);
    float*  sstdT = (float*)alloc((size_t)32000 * 4);
    float*  invT  = (float*)alloc((size_t)32000 * 4);
    float*  pS   = (float*)alloc((size_t)SEG_ * B_ * CH_ * 4);
    float*  pSS  = (float*)alloc((size_t)SEG_ * B_ * CH_ * 4);
    int*    labels  = (int*)alloc((size_t)1024 * 4);
    float*  sbuf = (float*)alloc((size_t)2 * 3 * CH_ * 4);
    float*  ccG  = (float*)alloc((size_t)8 * 4);
    int*    chlist = (int*)alloc((size_t)SLOTS_ * 4);
    int*    chpos  = (int*)alloc((size_t)1024 * 4);
    int*    slabel = (int*)alloc((size_t)256 * 4);
    // union region: Gp (16*36*16384*4 = 37.7 MB, dead after k3b) then outP (24.9 MB)
    char* unionBase = (char*)alloc((size_t)ZSPLIT_ * NTRI_ * 16384 * 4);
    float* Gp   = (float*)unionBase;
    float* outP = (float*)unionBase;

    k1_partial<<<dim3(SEG_, 32), 256, 0, stream>>>(x, pS, pSS);
    k1b_reduce<<<125, 256, 0, stream>>>(pS, pSS, meanT, sstdT, invT);
    k2_build<<<dim3(32, 16, 32), 256, 0, stream>>>(x, meanT, invT, zLH, zLR, zUH);
    k0_wprep<<<576, 256, 0, stream>>>(Wg, Wu, WB2);
    k3_mfma<<<8 * NTRI_ * 2, 256, 0, stream>>>(zLH, zLR, Gp);
    k3b_sym<<<dim3(NTRI_, 4), 256, 0, stream>>>(Gp, G);
    k4a_init<<<4, 256, 0, stream>>>(G, sbuf, ccG);
    void* args[] = { (void*)&G, (void*)&sbuf, (void*)&ccG, (void*)&labels };
    hipLaunchCooperativeKernel((void*)k4_kmeans, dim3(16), dim3(1024), args, 0, stream);
    k4b_perm<<<1, 256, 0, stream>>>(labels, chlist, chpos, slabel);
    k5_grouped<<<NT2_, 256, 0, stream>>>(zLH, zUH, WB2, chlist, slabel,
                                         bg, bu, meanT, sstdT, outP);
    k7_unperm<<<dim3(4, 6, 32), 256, 0, stream>>>(outP, chpos, out);
}

// Round 8
// 223.288 us; speedup vs baseline: 10.5416x; 1.2426x over previous
//
#include <hip/hip_runtime.h>
#include <hip/hip_bf16.h>
#include <hip/hip_cooperative_groups.h>

namespace cg = cooperative_groups;

#define B_   32
#define L_   1024
#define LH_  512
#define CH_  1000
#define PRED_ 192
#define ITERS_ 50
#define KBL_ 16384   // B_*LH_
#define SLOTS_ 1012
#define NTILES_ 253
#define NT2_ 506     // 2-slot tiles for k5
#define NTRI_ 36     // upper-triangle 8x8 tile pairs
#define SEG_ 16      // L-segments for stats partials

typedef __attribute__((ext_vector_type(8))) _Float16 f16x8;
typedef __attribute__((ext_vector_type(4))) float f32x4;

__device__ inline ushort f2h(float x) {
    union { _Float16 h; ushort u; } c;
    c.h = (_Float16)x;
    return c.u;
}

// ---------------- K1a: partial sums over 64-row segments --------------------
__global__ __launch_bounds__(256) void k1_partial(const float* __restrict__ x,
                                                  float* __restrict__ pS,
                                                  float* __restrict__ pSS) {
    int seg = blockIdx.x;        // 0..15
    int b = blockIdx.y;          // 0..31
    int t = threadIdx.x;
    if (t >= 250) return;
    int c4 = t * 4;
    const float* xp = x + (size_t)b * L_ * CH_ + (size_t)seg * 64 * CH_ + c4;
    float4 s = {0.f, 0.f, 0.f, 0.f}, ss = {0.f, 0.f, 0.f, 0.f};
#pragma unroll 4
    for (int l = 0; l < 64; ++l) {
        float4 v = *(const float4*)(xp + (size_t)l * CH_);
        s.x += v.x; s.y += v.y; s.z += v.z; s.w += v.w;
        ss.x += v.x * v.x; ss.y += v.y * v.y; ss.z += v.z * v.z; ss.w += v.w * v.w;
    }
    size_t o = ((size_t)seg * B_ + b) * CH_ + c4;
    *(float4*)(pS + o) = s;
    *(float4*)(pSS + o) = ss;
}

// ---------------- K1b: reduce partials -> mean / std ------------------------
__global__ __launch_bounds__(256) void k1b_reduce(const float* __restrict__ pS,
                                                  const float* __restrict__ pSS,
                                                  float* __restrict__ meanT,
                                                  float* __restrict__ sstdT,
                                                  float* __restrict__ invT) {
    int idx = blockIdx.x * 256 + threadIdx.x;
    if (idx >= B_ * CH_) return;
    int c = idx % CH_;
    int b = idx / CH_;
    float s = 0.f, ss = 0.f;
#pragma unroll
    for (int seg = 0; seg < SEG_; ++seg) {
        size_t o = ((size_t)seg * B_ + b) * CH_ + c;
        s += pS[o];
        ss += pSS[o];
    }
    float m = s * (1.0f / L_);
    float var = (ss - (float)L_ * m * m) * (1.0f / (L_ - 1)) + 1e-5f;
    float sd = sqrtf(var);
    meanT[c * B_ + b] = m;
    sstdT[c * B_ + b] = sd;
    invT[c * B_ + b] = 1.0f / sd;
}

// ---------------- K2: build fp16 z_L + z_U in [n][b][lh] layout -------------
__global__ __launch_bounds__(256) void k2_build(const float* __restrict__ x,
                                                const float* __restrict__ meanT,
                                                const float* __restrict__ invT,
                                                ushort* __restrict__ zLF,
                                                ushort* __restrict__ zUF) {
    __shared__ float Ls[32][33];
    __shared__ float Us[32][33];
    int tid = threadIdx.x;
    int tx = tid & 31, ty = tid >> 5;
    int n0 = blockIdx.x * 32;
    int lh0 = blockIdx.y * 32;
    int b = blockIdx.z;
    int n = n0 + tx;
    float m = 0.f, iv = 0.f;
    if (n < CH_) { m = meanT[n * B_ + b]; iv = invT[n * B_ + b]; }
    for (int r = 0; r < 4; ++r) {
        int lh = lh0 + ty + 8 * r;
        float v0 = 0.f, v1 = 0.f;
        if (n < CH_) {
            v0 = x[((size_t)b * L_ + 2 * lh) * CH_ + n];
            v1 = x[((size_t)b * L_ + 2 * lh + 1) * CH_ + n];
        }
        float a = (v0 - m) * iv * 0.5f;
        float c2 = (v1 - m) * iv * 0.5f;
        Ls[ty + 8 * r][tx] = a + c2;
        Us[ty + 8 * r][tx] = a - c2;
    }
    __syncthreads();
    for (int r = 0; r < 4; ++r) {
        int nl = ty + 8 * r;
        int nn = n0 + nl;
        if (nn < CH_) {
            size_t dst = (size_t)nn * KBL_ + (size_t)b * LH_ + lh0 + tx;
            zLF[dst] = f2h(Ls[tx][nl]);
            zUF[dst] = f2h(Us[tx][nl]);
        }
    }
}

// ---------------- K0w: stacked weights WF2[lab][192][1024] = [Wg[lab]|Wu] ---
__global__ __launch_bounds__(256) void k0_wprep(const float* __restrict__ Wg,
                                                const float* __restrict__ Wu,
                                                ushort* __restrict__ WF2) {
    int r = blockIdx.x;          // 0..575 = lab*192+p
    int p = r % PRED_;
    int tid = threadIdx.x;
#pragma unroll
    for (int i = 0; i < 4; ++i) {
        int k = i * 256 + tid;   // 0..1023
        float w = (k < 512) ? Wg[(size_t)r * LH_ + k]
                            : Wu[(size_t)p * LH_ + (k - 512)];
        WF2[(size_t)r * 1024 + k] = f2h(w);
    }
}

// ---------------- K3: symmetric Gram via fp16 MFMA (single-pass) ------------
#define ZSPLIT_ 16
#define KSEG_   1024
#define NT_     (KSEG_ / 32)

__global__ __launch_bounds__(256) void k3_mfma(const ushort* __restrict__ zF,
                                               float* __restrict__ gpart) {
    __shared__ __align__(16) ushort AH[128][40];
    __shared__ __align__(16) ushort BH[128][40];

    int bid = blockIdx.x;
    int xcd = bid & 7, w = bid >> 3;           // w in 0..71
    int ksl = 2 * xcd + (w >= NTRI_);
    int t = (w >= NTRI_) ? w - NTRI_ : w;
    int ti = 0, tt = t;
    while (tt >= 8 - ti) { tt -= 8 - ti; ++ti; }
    int tj = ti + tt;
    int i0 = ti * 128, j0 = tj * 128;
    int kb = ksl * KSEG_;

    int tid = threadIdx.x;
    int lane = tid & 63;
    int wid = tid >> 6;
    int wr = wid >> 1, wc = wid & 1;
    int fr = lane & 15;
    int g8 = lane >> 4;

    f32x4 acc[4][4];
#pragma unroll
    for (int m = 0; m < 4; ++m)
#pragma unroll
        for (int n = 0; n < 4; ++n) acc[m][n] = (f32x4){0.f, 0.f, 0.f, 0.f};

    int srow = tid >> 2;
    int sseg = tid & 3;

    uint4 pv[4];
    auto stage_load = [&](int kt) {
        int k0 = kb + kt * 32;
#pragma unroll
        for (int s = 0; s < 4; ++s) {
            int tile = s >> 1, rep = s & 1;
            int row = srow + rep * 64;
            int grow = ((tile == 0) ? i0 : j0) + row;
            uint4 v = {0u, 0u, 0u, 0u};
            if (grow < CH_)
                v = *(const uint4*)(zF + (size_t)grow * KBL_ + k0 + sseg * 8);
            pv[s] = v;
        }
    };
    auto stage_write = [&]() {
#pragma unroll
        for (int s = 0; s < 4; ++s) {
            int tile = s >> 1, rep = s & 1;
            int row = srow + rep * 64;
            ushort* dst = (tile == 0) ? &AH[row][sseg * 8] : &BH[row][sseg * 8];
            *(uint4*)dst = pv[s];
        }
    };

    stage_load(0);
    for (int t2 = 0; t2 < NT_; ++t2) {
        __syncthreads();
        stage_write();
        __syncthreads();
        if (t2 + 1 < NT_) stage_load(t2 + 1);

        f16x8 a[4];
#pragma unroll
        for (int m = 0; m < 4; ++m)
            a[m] = *(const f16x8*)&AH[wr * 64 + m * 16 + fr][g8 * 8];
#pragma unroll
        for (int n = 0; n < 4; ++n) {
            f16x8 bv = *(const f16x8*)&BH[wc * 64 + n * 16 + fr][g8 * 8];
#pragma unroll
            for (int m = 0; m < 4; ++m)
                acc[m][n] = __builtin_amdgcn_mfma_f32_16x16x32_f16(a[m], bv, acc[m][n], 0, 0, 0);
        }
    }

    float* gp = gpart + ((size_t)ksl * NTRI_ + t) * 16384;
#pragma unroll
    for (int m = 0; m < 4; ++m) {
        int rb = wr * 64 + m * 16 + g8 * 4;
#pragma unroll
        for (int n = 0; n < 4; ++n) {
            int c = wc * 64 + n * 16 + fr;
#pragma unroll
            for (int q = 0; q < 4; ++q)
                gp[(size_t)(rb + q) * 128 + c] = acc[m][n][q];
        }
    }
}

// ---------------- K3b: reduce 16 partials per tile, write G + mirror --------
__global__ __launch_bounds__(256) void k3b_sym(const float* __restrict__ gpart,
                                               float* __restrict__ g) {
    int t = blockIdx.x;          // 0..35
    int seg = blockIdx.y;        // 0..3
    int ti = 0, tt = t;
    while (tt >= 8 - ti) { tt -= 8 - ti; ++ti; }
    int tj = ti + tt;
    int i0 = ti * 128, j0 = tj * 128;
    int tid = threadIdx.x;
    int e0 = seg * 4096 + tid * 16;
    int r = e0 >> 7, c0 = e0 & 127;

    float4 s[4];
#pragma unroll
    for (int j = 0; j < 4; ++j) s[j] = (float4){0.f, 0.f, 0.f, 0.f};
#pragma unroll
    for (int p = 0; p < ZSPLIT_; ++p) {
        const float* src = gpart + ((size_t)p * NTRI_ + t) * 16384 + e0;
#pragma unroll
        for (int j = 0; j < 4; ++j) {
            float4 v = *(const float4*)(src + j * 4);
            s[j].x += v.x; s[j].y += v.y; s[j].z += v.z; s[j].w += v.w;
        }
    }
    int i = i0 + r;
    if (i < CH_) {
#pragma unroll
        for (int j = 0; j < 4; ++j) {
            int jc = j0 + c0 + j * 4;
            if (jc + 3 < CH_) {
                *(float4*)(g + (size_t)i * CH_ + jc) = s[j];
            } else {
#pragma unroll
                for (int e = 0; e < 4; ++e)
                    if (jc + e < CH_) g[(size_t)i * CH_ + jc + e] = ((const float*)&s[j])[e];
            }
        }
        if (ti != tj) {
#pragma unroll
            for (int j = 0; j < 4; ++j) {
#pragma unroll
                for (int e = 0; e < 4; ++e) {
                    int jc = j0 + c0 + j * 4 + e;
                    if (jc < CH_) g[(size_t)jc * CH_ + i] = ((const float*)&s[j])[e];
                }
            }
        }
    }
}

// ---------------- K4a: init s[i][k] = G[i][k], ccG = diag -------------------
__global__ __launch_bounds__(256) void k4a_init(const float* __restrict__ g,
                                                float* __restrict__ sbuf,
                                                float* __restrict__ ccG) {
    int i = blockIdx.x * 256 + threadIdx.x;
    if (i < CH_) {
        sbuf[i * 3 + 0] = g[(size_t)i * CH_ + 0];
        sbuf[i * 3 + 1] = g[(size_t)i * CH_ + 1];
        sbuf[i * 3 + 2] = g[(size_t)i * CH_ + 2];
    }
    if (i < 3) ccG[i] = g[(size_t)i * CH_ + i];
}

// ---------------- K4: cooperative k-means, ONE grid.sync per iter -----------
__global__ __launch_bounds__(1024) void k4_kmeans(const float* __restrict__ g,
                                                  float* __restrict__ sbuf,
                                                  float* __restrict__ ccG,
                                                  int* __restrict__ labels) {
    cg::grid_group grid = cg::this_grid();
    __shared__ int   lab[1024];
    __shared__ float red[3][1024];
    __shared__ int   cnt[4], cnt2[4], chgS;

    int tid = threadIdx.x;
    int bpt0 = blockIdx.x * 64;
    lab[tid] = (tid < 3) ? tid : 3;     // sentinel 3 = unassigned
    __syncthreads();

    int par = 0;
    for (int it = 1; it <= ITERS_ + 1; ++it) {
        const float* sp = sbuf + par * 3 * CH_;
        if (tid < 4) { cnt[tid] = 0; cnt2[tid] = 0; }
        if (tid == 0) chgS = 0;
        __syncthreads();
        float c0 = 0.f, c1 = 0.f, c2 = 0.f;
        int lbp = 3;
        if (tid < CH_) {
            lbp = lab[tid];
            atomicAdd(&cnt[lbp], 1);
            if (lbp < 3) {
                float sv = sp[tid * 3 + lbp];
                if (lbp == 0) c0 = sv; else if (lbp == 1) c1 = sv; else c2 = sv;
            }
        }
        red[0][tid] = c0; red[1][tid] = c1; red[2][tid] = c2;
        __syncthreads();
        for (int off = 512; off > 0; off >>= 1) {
            if (tid < off) {
                red[0][tid] += red[0][tid + off];
                red[1][tid] += red[1][tid + off];
                red[2][tid] += red[2][tid + off];
            }
            __syncthreads();
        }
        int n0 = cnt[0], n1 = cnt[1], n2 = cnt[2];
        float cc0 = (n0 > 0) ? red[0][0] / (float)n0 : ccG[par * 3 + 0];
        float cc1 = (n1 > 0) ? red[1][0] / (float)n1 : ccG[par * 3 + 1];
        float cc2 = (n2 > 0) ? red[2][0] / (float)n2 : ccG[par * 3 + 2];
        if (tid == 0) ccG[(par ^ 1) * 3 + 0] = cc0;
        if (tid == 1) ccG[(par ^ 1) * 3 + 1] = cc1;
        if (tid == 2) ccG[(par ^ 1) * 3 + 2] = cc2;

        int myNew = -1;
        if (tid < CH_) {
            float d0 = cc0 - 2.f * sp[tid * 3 + 0];
            float d1 = cc1 - 2.f * sp[tid * 3 + 1];
            float d2 = cc2 - 2.f * sp[tid * 3 + 2];
            int nl = 0; float dm = d0;
            if (d1 < dm) { dm = d1; nl = 1; }
            if (d2 < dm) { dm = d2; nl = 2; }
            if (nl != lbp) atomicAdd(&chgS, 1);
            myNew = nl;
        }
        __syncthreads();
        if (tid < CH_) { lab[tid] = myNew; atomicAdd(&cnt2[myNew], 1); }
        __syncthreads();

        if (it == ITERS_ + 1) break;
        if (chgS == 0 && it > 1) break;

        int n0n = cnt2[0], n1n = cnt2[1], n2n = cnt2[2];
        float* sq = sbuf + (par ^ 1) * 3 * CH_;
        int i = bpt0 + (tid >> 4);
        int sub = tid & 15;
        if (i < CH_) {
            const float* gr = g + (size_t)i * CH_;
            float a0 = 0.f, a1 = 0.f, a2 = 0.f;
            for (int j = sub; j < CH_; j += 16) {
                float gv = gr[j];
                int lb = lab[j];
                a0 += (lb == 0) ? gv : 0.f;
                a1 += (lb == 1) ? gv : 0.f;
                a2 += (lb == 2) ? gv : 0.f;
            }
#pragma unroll
            for (int msk = 1; msk < 16; msk <<= 1) {
                a0 += __shfl_xor(a0, msk, 16);
                a1 += __shfl_xor(a1, msk, 16);
                a2 += __shfl_xor(a2, msk, 16);
            }
            if (sub == 0) {
                sq[i * 3 + 0] = (n0n > 0) ? a0 / (float)n0n : sp[i * 3 + 0];
                sq[i * 3 + 1] = (n1n > 0) ? a1 / (float)n1n : sp[i * 3 + 1];
                sq[i * 3 + 2] = (n2n > 0) ? a2 / (float)n2n : sp[i * 3 + 2];
            }
        }
        par ^= 1;
        grid.sync();
    }

    if (tid < 64) {
        int i = bpt0 + tid;
        if (i < CH_) labels[i] = lab[i];
    }
}

// ---------------- K4b: build label-sorted channel permutation ---------------
__global__ __launch_bounds__(256) void k4b_perm(const int* __restrict__ labels,
                                                int* __restrict__ chlist,
                                                int* __restrict__ chpos,
                                                int* __restrict__ slabel) {
    __shared__ int cnt[3], st[4], c2[3];
    int tid = threadIdx.x;
    if (tid < 3) { cnt[tid] = 0; c2[tid] = 0; }
    __syncthreads();
    for (int n = tid; n < CH_; n += 256) atomicAdd(&cnt[labels[n]], 1);
    __syncthreads();
    if (tid == 0) {
        st[0] = 0;
        st[1] = ((cnt[0] + 3) >> 2) << 2;
        st[2] = st[1] + (((cnt[1] + 3) >> 2) << 2);
        st[3] = st[2] + (((cnt[2] + 3) >> 2) << 2);
    }
    __syncthreads();
    for (int s = tid; s < SLOTS_; s += 256) chlist[s] = 0;
    for (int t = tid; t < NTILES_; t += 256) {
        int s = t * 4;
        slabel[t] = (s < st[1]) ? 0 : (s < st[2]) ? 1 : (s < st[3]) ? 2 : 0;
    }
    __syncthreads();
    for (int n = tid; n < CH_; n += 256) {
        int lb = labels[n];
        int r = atomicAdd(&c2[lb], 1);
        int slot = st[lb] + r;
        chlist[slot] = n;
        chpos[n] = slot;
    }
}

// ---------------- K5: grouped GEMM  C[64 sb][192 p] = Z_tile . WF2[lab]^T ---
__global__ __launch_bounds__(256) void k5_grouped(const ushort* __restrict__ zLF,
                                                  const ushort* __restrict__ zUF,
                                                  const ushort* __restrict__ WF2,
                                                  const int* __restrict__ chlist,
                                                  const int* __restrict__ slabel,
                                                  const float* __restrict__ bg,
                                                  const float* __restrict__ bu,
                                                  const float* __restrict__ meanT,
                                                  const float* __restrict__ sstdT,
                                                  float* __restrict__ outP) {
    __shared__ __align__(16) ushort ZT[64][40];
    __shared__ __align__(16) ushort WT[192][40];
    __shared__ int sch[2];

    int tile = blockIdx.x;               // 0..505
    int tid = threadIdx.x;
    if (tid < 2) sch[tid] = chlist[tile * 2 + tid];
    int lab = slabel[tile >> 1];
    __syncthreads();

    int lane = tid & 63, wid = tid >> 6; // wid = p-quarter (48 p each)
    int fr = lane & 15, g8 = lane >> 4;

    int srow = tid >> 2, sseg = tid & 3; // srow 0..63
    size_t zb = (size_t)sch[srow >> 5] * KBL_ + (size_t)(srow & 31) * LH_;
    const ushort* wbase = WF2 + (size_t)(lab * PRED_) * 1024;

    f32x4 acc[4][3];
#pragma unroll
    for (int m = 0; m < 4; ++m)
#pragma unroll
        for (int n = 0; n < 3; ++n) acc[m][n] = (f32x4){0.f, 0.f, 0.f, 0.f};

    uint4 pz, pw0, pw1, pw2;
    auto stage_load = [&](int t) {
        const ushort* zsrc = (t < 16) ? zLF : zUF;
        int ko = ((t & 15) * 32) + sseg * 8;
        pz  = *(const uint4*)(zsrc + zb + ko);
        int kw = t * 32 + sseg * 8;
        pw0 = *(const uint4*)(wbase + (size_t)srow * 1024 + kw);
        pw1 = *(const uint4*)(wbase + (size_t)(srow + 64) * 1024 + kw);
        pw2 = *(const uint4*)(wbase + (size_t)(srow + 128) * 1024 + kw);
    };
    auto stage_write = [&]() {
        *(uint4*)&ZT[srow][sseg * 8] = pz;
        *(uint4*)&WT[srow][sseg * 8] = pw0;
        *(uint4*)&WT[srow + 64][sseg * 8] = pw1;
        *(uint4*)&WT[srow + 128][sseg * 8] = pw2;
    };

    stage_load(0);
    for (int t = 0; t < 32; ++t) {
        __syncthreads();
        stage_write();
        __syncthreads();
        if (t + 1 < 32) stage_load(t + 1);

        f16x8 a[4];
#pragma unroll
        for (int m = 0; m < 4; ++m)
            a[m] = *(const f16x8*)&ZT[m * 16 + fr][g8 * 8];
#pragma unroll
        for (int nf = 0; nf < 3; ++nf) {
            f16x8 bv = *(const f16x8*)&WT[wid * 48 + nf * 16 + fr][g8 * 8];
#pragma unroll
            for (int m = 0; m < 4; ++m)
                acc[m][nf] = __builtin_amdgcn_mfma_f32_16x16x32_f16(a[m], bv, acc[m][nf], 0, 0, 0);
        }
    }

#pragma unroll
    for (int m = 0; m < 4; ++m) {
#pragma unroll
        for (int q = 0; q < 4; ++q) {
            int sb = m * 16 + g8 * 4 + q;
            int sl = sb >> 5, b = sb & 31;
            int n = sch[sl];
            float sd = sstdT[n * B_ + b], mu = meanT[n * B_ + b];
            size_t obase = ((size_t)(tile * 2 + sl) * B_ + b) * PRED_;
#pragma unroll
            for (int nf = 0; nf < 3; ++nf) {
                int p = wid * 48 + nf * 16 + fr;
                float v = acc[m][nf][q] + bg[lab * PRED_ + p] + bu[p];
                outP[obase + p] = v * sd + mu;
            }
        }
    }
}

// ---------------- K7: unpermute outP -> out[b][p][n] ------------------------
__global__ __launch_bounds__(256) void k7_unperm(const float* __restrict__ outP,
                                                 const int* __restrict__ chpos,
                                                 float* __restrict__ out) {
    int n = blockIdx.x * 256 + threadIdx.x;
    int p0 = blockIdx.y * 32;
    int b = blockIdx.z;
    if (n >= CH_) return;
    const float* src = outP + ((size_t)chpos[n] * B_ + b) * PRED_ + p0;
    float4 v[8];
#pragma unroll
    for (int j = 0; j < 8; ++j) v[j] = *(const float4*)(src + j * 4);
#pragma unroll
    for (int j = 0; j < 8; ++j) {
#pragma unroll
        for (int e = 0; e < 4; ++e) {
            int p = p0 + j * 4 + e;
            out[((size_t)b * PRED_ + p) * CH_ + n] = ((const float*)&v[j])[e];
        }
    }
}

extern "C" void kernel_launch(void* const* d_in, const int* in_sizes, int n_in,
                              void* d_out, int out_size, void* d_ws, size_t ws_size,
                              hipStream_t stream) {
    const float* x  = (const float*)d_in[0];
    const float* Wg = (const float*)d_in[4];
    const float* bg = (const float*)d_in[5];
    const float* Wu = (const float*)d_in[6];
    const float* bu = (const float*)d_in[7];
    float* out = (float*)d_out;
    (void)in_sizes; (void)n_in; (void)out_size; (void)ws_size;

    char* ws = (char*)d_ws;
    size_t off = 0;
    auto alloc = [&](size_t bytes) {
        void* p = ws + off;
        off = (off + bytes + 255) & ~(size_t)255;
        return p;
    };
    ushort* zLF  = (ushort*)alloc((size_t)16384000 * 2);
    ushort* zUF  = (ushort*)alloc((size_t)16384000 * 2);
    float*  G    = (float*)alloc((size_t)1000000 * 4);
    ushort* WF2  = (ushort*)alloc((size_t)576 * 1024 * 2);
    float*  meanT = (float*)alloc((size_t)32000 * 4);
    float*  sstdT = (float*)alloc((size_t)32000 * 4);
    float*  invT  = (float*)alloc((size_t)32000 * 4);
    float*  pS   = (float*)alloc((size_t)SEG_ * B_ * CH_ * 4);
    float*  pSS  = (float*)alloc((size_t)SEG_ * B_ * CH_ * 4);
    int*    labels  = (int*)alloc((size_t)1024 * 4);
    float*  sbuf = (float*)alloc((size_t)2 * 3 * CH_ * 4);
    float*  ccG  = (float*)alloc((size_t)8 * 4);
    int*    chlist = (int*)alloc((size_t)SLOTS_ * 4);
    int*    chpos  = (int*)alloc((size_t)1024 * 4);
    int*    slabel = (int*)alloc((size_t)256 * 4);
    // union region: Gp (16*36*16384*4 = 37.7 MB, dead after k3b) then outP (24.9 MB)
    char* unionBase = (char*)alloc((size_t)ZSPLIT_ * NTRI_ * 16384 * 4);
    float* Gp   = (float*)unionBase;
    float* outP = (float*)unionBase;

    k1_partial<<<dim3(SEG_, 32), 256, 0, stream>>>(x, pS, pSS);
    k1b_reduce<<<125, 256, 0, stream>>>(pS, pSS, meanT, sstdT, invT);
    k2_build<<<dim3(32, 16, 32), 256, 0, stream>>>(x, meanT, invT, zLF, zUF);
    k0_wprep<<<576, 256, 0, stream>>>(Wg, Wu, WF2);
    k3_mfma<<<8 * NTRI_ * 2, 256, 0, stream>>>(zLF, Gp);
    k3b_sym<<<dim3(NTRI_, 4), 256, 0, stream>>>(Gp, G);
    k4a_init<<<4, 256, 0, stream>>>(G, sbuf, ccG);
    void* args[] = { (void*)&G, (void*)&sbuf, (void*)&ccG, (void*)&labels };
    hipLaunchCooperativeKernel((void*)k4_kmeans, dim3(16), dim3(1024), args, 0, stream);
    k4b_perm<<<1, 256, 0, stream>>>(labels, chlist, chpos, slabel);
    k5_grouped<<<NT2_, 256, 0, stream>>>(zLF, zUF, WF2, chlist, slabel,
                                         bg, bu, meanT, sstdT, outP);
    k7_unperm<<<dim3(4, 6, 32), 256, 0, stream>>>(outP, chpos, out);
}

// Round 9
// 214.202 us; speedup vs baseline: 10.9887x; 1.0424x over previous
//
#include <hip/hip_runtime.h>
#include <hip/hip_bf16.h>
#include <hip/hip_cooperative_groups.h>

namespace cg = cooperative_groups;

#define B_   32
#define L_   1024
#define LH_  512
#define CH_  1000
#define PRED_ 192
#define ITERS_ 50
#define KBL_ 16384   // B_*LH_
#define SLOTS_ 1012
#define NTILES_ 253
#define NT2_ 506     // 2-slot tiles for k5
#define NTRI_ 36     // upper-triangle 8x8 tile pairs
#define SEG_ 16      // L-segments for stats partials

typedef __attribute__((ext_vector_type(8))) _Float16 f16x8;
typedef __attribute__((ext_vector_type(4))) float f32x4;

__device__ inline ushort f2h(float x) {
    union { _Float16 h; ushort u; } c;
    c.h = (_Float16)x;
    return c.u;
}

// ---------------- K1a: partial sums over 64-row segments --------------------
__global__ __launch_bounds__(256) void k1_partial(const float* __restrict__ x,
                                                  float* __restrict__ pS,
                                                  float* __restrict__ pSS) {
    int seg = blockIdx.x;        // 0..15
    int b = blockIdx.y;          // 0..31
    int t = threadIdx.x;
    if (t >= 250) return;
    int c4 = t * 4;
    const float* xp = x + (size_t)b * L_ * CH_ + (size_t)seg * 64 * CH_ + c4;
    float4 s = {0.f, 0.f, 0.f, 0.f}, ss = {0.f, 0.f, 0.f, 0.f};
#pragma unroll 4
    for (int l = 0; l < 64; ++l) {
        float4 v = *(const float4*)(xp + (size_t)l * CH_);
        s.x += v.x; s.y += v.y; s.z += v.z; s.w += v.w;
        ss.x += v.x * v.x; ss.y += v.y * v.y; ss.z += v.z * v.z; ss.w += v.w * v.w;
    }
    size_t o = ((size_t)seg * B_ + b) * CH_ + c4;
    *(float4*)(pS + o) = s;
    *(float4*)(pSS + o) = ss;
}

// ---------------- K1b: reduce partials -> mean / std ------------------------
__global__ __launch_bounds__(256) void k1b_reduce(const float* __restrict__ pS,
                                                  const float* __restrict__ pSS,
                                                  float* __restrict__ meanT,
                                                  float* __restrict__ sstdT,
                                                  float* __restrict__ invT) {
    int idx = blockIdx.x * 256 + threadIdx.x;
    if (idx >= B_ * CH_) return;
    int c = idx % CH_;
    int b = idx / CH_;
    float s = 0.f, ss = 0.f;
#pragma unroll
    for (int seg = 0; seg < SEG_; ++seg) {
        size_t o = ((size_t)seg * B_ + b) * CH_ + c;
        s += pS[o];
        ss += pSS[o];
    }
    float m = s * (1.0f / L_);
    float var = (ss - (float)L_ * m * m) * (1.0f / (L_ - 1)) + 1e-5f;
    float sd = sqrtf(var);
    meanT[c * B_ + b] = m;
    sstdT[c * B_ + b] = sd;
    invT[c * B_ + b] = 1.0f / sd;
}

// ---------------- K2: build fp16 z_L + z_U in [n][b][lh] layout -------------
__global__ __launch_bounds__(256) void k2_build(const float* __restrict__ x,
                                                const float* __restrict__ meanT,
                                                const float* __restrict__ invT,
                                                ushort* __restrict__ zLF,
                                                ushort* __restrict__ zUF) {
    __shared__ float Ls[32][33];
    __shared__ float Us[32][33];
    int tid = threadIdx.x;
    int tx = tid & 31, ty = tid >> 5;
    int n0 = blockIdx.x * 32;
    int lh0 = blockIdx.y * 32;
    int b = blockIdx.z;
    int n = n0 + tx;
    float m = 0.f, iv = 0.f;
    if (n < CH_) { m = meanT[n * B_ + b]; iv = invT[n * B_ + b]; }
    for (int r = 0; r < 4; ++r) {
        int lh = lh0 + ty + 8 * r;
        float v0 = 0.f, v1 = 0.f;
        if (n < CH_) {
            v0 = x[((size_t)b * L_ + 2 * lh) * CH_ + n];
            v1 = x[((size_t)b * L_ + 2 * lh + 1) * CH_ + n];
        }
        float a = (v0 - m) * iv * 0.5f;
        float c2 = (v1 - m) * iv * 0.5f;
        Ls[ty + 8 * r][tx] = a + c2;
        Us[ty + 8 * r][tx] = a - c2;
    }
    __syncthreads();
    for (int r = 0; r < 4; ++r) {
        int nl = ty + 8 * r;
        int nn = n0 + nl;
        if (nn < CH_) {
            size_t dst = (size_t)nn * KBL_ + (size_t)b * LH_ + lh0 + tx;
            zLF[dst] = f2h(Ls[tx][nl]);
            zUF[dst] = f2h(Us[tx][nl]);
        }
    }
}

// ---------------- K0w: stacked weights WF2[lab][192][1024] = [Wg[lab]|Wu] ---
__global__ __launch_bounds__(256) void k0_wprep(const float* __restrict__ Wg,
                                                const float* __restrict__ Wu,
                                                ushort* __restrict__ WF2) {
    int r = blockIdx.x;          // 0..575 = lab*192+p
    int p = r % PRED_;
    int tid = threadIdx.x;
#pragma unroll
    for (int i = 0; i < 4; ++i) {
        int k = i * 256 + tid;   // 0..1023
        float w = (k < 512) ? Wg[(size_t)r * LH_ + k]
                            : Wu[(size_t)p * LH_ + (k - 512)];
        WF2[(size_t)r * 1024 + k] = f2h(w);
    }
}

// ---------------- K3: symmetric Gram via fp16 MFMA (single-pass) ------------
#define ZSPLIT_ 16
#define KSEG_   1024
#define NT_     (KSEG_ / 32)

__global__ __launch_bounds__(256) void k3_mfma(const ushort* __restrict__ zF,
                                               float* __restrict__ gpart) {
    __shared__ __align__(16) ushort AH[128][40];
    __shared__ __align__(16) ushort BH[128][40];

    int bid = blockIdx.x;
    int xcd = bid & 7, w = bid >> 3;           // w in 0..71
    int ksl = 2 * xcd + (w >= NTRI_);
    int t = (w >= NTRI_) ? w - NTRI_ : w;
    int ti = 0, tt = t;
    while (tt >= 8 - ti) { tt -= 8 - ti; ++ti; }
    int tj = ti + tt;
    int i0 = ti * 128, j0 = tj * 128;
    int kb = ksl * KSEG_;

    int tid = threadIdx.x;
    int lane = tid & 63;
    int wid = tid >> 6;
    int wr = wid >> 1, wc = wid & 1;
    int fr = lane & 15;
    int g8 = lane >> 4;

    f32x4 acc[4][4];
#pragma unroll
    for (int m = 0; m < 4; ++m)
#pragma unroll
        for (int n = 0; n < 4; ++n) acc[m][n] = (f32x4){0.f, 0.f, 0.f, 0.f};

    int srow = tid >> 2;
    int sseg = tid & 3;

    uint4 pv[4];
    auto stage_load = [&](int kt) {
        int k0 = kb + kt * 32;
#pragma unroll
        for (int s = 0; s < 4; ++s) {
            int tile = s >> 1, rep = s & 1;
            int row = srow + rep * 64;
            int grow = ((tile == 0) ? i0 : j0) + row;
            uint4 v = {0u, 0u, 0u, 0u};
            if (grow < CH_)
                v = *(const uint4*)(zF + (size_t)grow * KBL_ + k0 + sseg * 8);
            pv[s] = v;
        }
    };
    auto stage_write = [&]() {
#pragma unroll
        for (int s = 0; s < 4; ++s) {
            int tile = s >> 1, rep = s & 1;
            int row = srow + rep * 64;
            ushort* dst = (tile == 0) ? &AH[row][sseg * 8] : &BH[row][sseg * 8];
            *(uint4*)dst = pv[s];
        }
    };

    stage_load(0);
    for (int t2 = 0; t2 < NT_; ++t2) {
        __syncthreads();
        stage_write();
        __syncthreads();
        if (t2 + 1 < NT_) stage_load(t2 + 1);

        f16x8 a[4];
#pragma unroll
        for (int m = 0; m < 4; ++m)
            a[m] = *(const f16x8*)&AH[wr * 64 + m * 16 + fr][g8 * 8];
#pragma unroll
        for (int n = 0; n < 4; ++n) {
            f16x8 bv = *(const f16x8*)&BH[wc * 64 + n * 16 + fr][g8 * 8];
#pragma unroll
            for (int m = 0; m < 4; ++m)
                acc[m][n] = __builtin_amdgcn_mfma_f32_16x16x32_f16(a[m], bv, acc[m][n], 0, 0, 0);
        }
    }

    float* gp = gpart + ((size_t)ksl * NTRI_ + t) * 16384;
#pragma unroll
    for (int m = 0; m < 4; ++m) {
        int rb = wr * 64 + m * 16 + g8 * 4;
#pragma unroll
        for (int n = 0; n < 4; ++n) {
            int c = wc * 64 + n * 16 + fr;
#pragma unroll
            for (int q = 0; q < 4; ++q)
                gp[(size_t)(rb + q) * 128 + c] = acc[m][n][q];
        }
    }
}

// ---------------- K3b: reduce 16 partials per tile, write G + mirror --------
__global__ __launch_bounds__(256) void k3b_sym(const float* __restrict__ gpart,
                                               float* __restrict__ g) {
    int t = blockIdx.x;          // 0..35
    int seg = blockIdx.y;        // 0..3
    int ti = 0, tt = t;
    while (tt >= 8 - ti) { tt -= 8 - ti; ++ti; }
    int tj = ti + tt;
    int i0 = ti * 128, j0 = tj * 128;
    int tid = threadIdx.x;
    int e0 = seg * 4096 + tid * 16;
    int r = e0 >> 7, c0 = e0 & 127;

    float4 s[4];
#pragma unroll
    for (int j = 0; j < 4; ++j) s[j] = (float4){0.f, 0.f, 0.f, 0.f};
#pragma unroll
    for (int p = 0; p < ZSPLIT_; ++p) {
        const float* src = gpart + ((size_t)p * NTRI_ + t) * 16384 + e0;
#pragma unroll
        for (int j = 0; j < 4; ++j) {
            float4 v = *(const float4*)(src + j * 4);
            s[j].x += v.x; s[j].y += v.y; s[j].z += v.z; s[j].w += v.w;
        }
    }
    int i = i0 + r;
    if (i < CH_) {
#pragma unroll
        for (int j = 0; j < 4; ++j) {
            int jc = j0 + c0 + j * 4;
            if (jc + 3 < CH_) {
                *(float4*)(g + (size_t)i * CH_ + jc) = s[j];
            } else {
#pragma unroll
                for (int e = 0; e < 4; ++e)
                    if (jc + e < CH_) g[(size_t)i * CH_ + jc + e] = ((const float*)&s[j])[e];
            }
        }
        if (ti != tj) {
#pragma unroll
            for (int j = 0; j < 4; ++j) {
#pragma unroll
                for (int e = 0; e < 4; ++e) {
                    int jc = j0 + c0 + j * 4 + e;
                    if (jc < CH_) g[(size_t)jc * CH_ + i] = ((const float*)&s[j])[e];
                }
            }
        }
    }
}

// ---------------- K4: cooperative k-means (ballot/shuffle, fused init+perm) -
// Every block redundantly holds all labels; one grid.sync per iteration; the
// t-update keeps R7/R8's exact 16-lane summation order (bit-identical labels).
// Block 0 computes the channel permutation at the end (slot order within a
// label group is atomic-order nondeterministic but value-neutral: each
// channel's output is independent of its slot; pad slots are never read).
__global__ __launch_bounds__(1024) void k4_kmeans(const float* __restrict__ g,
                                                  float* __restrict__ sbuf,
                                                  int* __restrict__ chlist,
                                                  int* __restrict__ chpos,
                                                  int* __restrict__ slabel) {
    cg::grid_group grid = cg::this_grid();
    __shared__ int   lab[1024];
    __shared__ float wred[16][3];
    __shared__ float ccS[3];
    __shared__ float ccPrev[3];
    __shared__ int   cntPrev[3];
    __shared__ int   cnt2[3];
    __shared__ int   chgS;
    __shared__ int   st[4], c2r[3];

    int tid = threadIdx.x;
    int wv = tid >> 6, ln = tid & 63;
    int bpt0 = blockIdx.x * 64;

    int lbp = (tid < 3) ? tid : 3;      // sentinel 3 = unassigned
    lab[tid] = lbp;
    if (tid < 3) {
        cntPrev[tid] = 1;
        ccPrev[tid] = g[(size_t)tid * CH_ + tid];
    }
    __syncthreads();

    int par = 0;
    for (int it = 1; it <= ITERS_ + 1; ++it) {
        const float* sp = sbuf + par * 3 * CH_;
        // own point's s-values (iter 1 reads straight from G columns)
        float s0 = 0.f, s1 = 0.f, s2 = 0.f;
        if (tid < CH_) {
            if (it == 1) {
                const float* gr = g + (size_t)tid * CH_;
                s0 = gr[0]; s1 = gr[1]; s2 = gr[2];
            } else {
                s0 = sp[tid * 3 + 0]; s1 = sp[tid * 3 + 1]; s2 = sp[tid * 3 + 2];
            }
        }
        // ---- phase A: cc_k = (sum_{lab==k} s_k) / n_k, wave-shuffle reduce -
        float c0 = (lbp == 0) ? s0 : 0.f;
        float c1 = (lbp == 1) ? s1 : 0.f;
        float c2 = (lbp == 2) ? s2 : 0.f;
#pragma unroll
        for (int m = 1; m < 64; m <<= 1) {
            c0 += __shfl_xor(c0, m);
            c1 += __shfl_xor(c1, m);
            c2 += __shfl_xor(c2, m);
        }
        if (ln == 0) { wred[wv][0] = c0; wred[wv][1] = c1; wred[wv][2] = c2; }
        if (tid == 0) { cnt2[0] = 0; cnt2[1] = 0; cnt2[2] = 0; chgS = 0; }
        __syncthreads();
        if (tid < 3) {
            float sacc = 0.f;
#pragma unroll
            for (int w2 = 0; w2 < 16; ++w2) sacc += wred[w2][tid];
            int n = cntPrev[tid];
            float cc = (n > 0) ? sacc / (float)n : ccPrev[tid];
            ccS[tid] = cc;
            ccPrev[tid] = cc;
        }
        __syncthreads();
        float cc0 = ccS[0], cc1 = ccS[1], cc2 = ccS[2];

        // ---- phase B: assign + ballot counts ----
        int nl = lbp;
        if (tid < CH_) {
            float d0 = cc0 - 2.f * s0;
            float d1 = cc1 - 2.f * s1;
            float d2 = cc2 - 2.f * s2;
            nl = 0; float dm = d0;
            if (d1 < dm) { dm = d1; nl = 1; }
            if (d2 < dm) { dm = d2; nl = 2; }
        }
        bool act = (tid < CH_);
        unsigned long long b0 = __ballot(act && nl == 0);
        unsigned long long b1 = __ballot(act && nl == 1);
        unsigned long long b2 = __ballot(act && nl == 2);
        unsigned long long bc = __ballot(act && nl != lbp);
        if (ln == 0) {
            if (b0) atomicAdd(&cnt2[0], (int)__popcll(b0));
            if (b1) atomicAdd(&cnt2[1], (int)__popcll(b1));
            if (b2) atomicAdd(&cnt2[2], (int)__popcll(b2));
            if (bc) atomicAdd(&chgS, (int)__popcll(bc));
        }
        lab[tid] = nl;
        lbp = nl;
        __syncthreads();

        if (it == ITERS_ + 1) break;           // 51st (final) assign done
        if (chgS == 0 && it > 1) break;        // converged: labels stable

        // ---- phase C: t-update for own 64 points (same order as before) ---
        int n0n = cnt2[0], n1n = cnt2[1], n2n = cnt2[2];
        float* sq = sbuf + (par ^ 1) * 3 * CH_;
        int i = bpt0 + (tid >> 4);
        int sub = tid & 15;
        if (i < CH_) {
            const float* gr = g + (size_t)i * CH_;
            float a0 = 0.f, a1 = 0.f, a2 = 0.f;
            for (int j = sub; j < CH_; j += 16) {
                float gv = gr[j];
                int lb = lab[j];
                a0 += (lb == 0) ? gv : 0.f;
                a1 += (lb == 1) ? gv : 0.f;
                a2 += (lb == 2) ? gv : 0.f;
            }
#pragma unroll
            for (int msk = 1; msk < 16; msk <<= 1) {
                a0 += __shfl_xor(a0, msk, 16);
                a1 += __shfl_xor(a1, msk, 16);
                a2 += __shfl_xor(a2, msk, 16);
            }
            if (sub == 0) {
                float f0, f1, f2;
                if (it == 1) { f0 = gr[0]; f1 = gr[1]; f2 = gr[2]; }
                else { f0 = sp[i * 3 + 0]; f1 = sp[i * 3 + 1]; f2 = sp[i * 3 + 2]; }
                sq[i * 3 + 0] = (n0n > 0) ? a0 / (float)n0n : f0;
                sq[i * 3 + 1] = (n1n > 0) ? a1 / (float)n1n : f1;
                sq[i * 3 + 2] = (n2n > 0) ? a2 / (float)n2n : f2;
            }
        }
        if (tid < 3) cntPrev[tid] = cnt2[tid];
        par ^= 1;
        grid.sync();
    }

    // ---- block 0: build label-sorted channel permutation ----
    if (blockIdx.x == 0) {
        if (tid == 0) {
            st[0] = 0;
            st[1] = ((cnt2[0] + 3) >> 2) << 2;
            st[2] = st[1] + (((cnt2[1] + 3) >> 2) << 2);
            st[3] = st[2] + (((cnt2[2] + 3) >> 2) << 2);
            c2r[0] = 0; c2r[1] = 0; c2r[2] = 0;
        }
        __syncthreads();
        if (tid < SLOTS_) chlist[tid] = 0;
        if (tid < NTILES_) {
            int s = tid * 4;
            slabel[tid] = (s < st[1]) ? 0 : (s < st[2]) ? 1 : (s < st[3]) ? 2 : 0;
        }
        __syncthreads();
        if (tid < CH_) {
            int lb = lab[tid];
            int r = atomicAdd(&c2r[lb], 1);
            int slot = st[lb] + r;
            chlist[slot] = tid;
            chpos[tid] = slot;
        }
    }
}

// ---------------- K5: grouped GEMM  C[64 sb][192 p] = Z_tile . WF2[lab]^T ---
__global__ __launch_bounds__(256) void k5_grouped(const ushort* __restrict__ zLF,
                                                  const ushort* __restrict__ zUF,
                                                  const ushort* __restrict__ WF2,
                                                  const int* __restrict__ chlist,
                                                  const int* __restrict__ slabel,
                                                  const float* __restrict__ bg,
                                                  const float* __restrict__ bu,
                                                  const float* __restrict__ meanT,
                                                  const float* __restrict__ sstdT,
                                                  float* __restrict__ outP) {
    __shared__ __align__(16) ushort ZT[64][40];
    __shared__ __align__(16) ushort WT[192][40];
    __shared__ int sch[2];

    int tile = blockIdx.x;               // 0..505
    int tid = threadIdx.x;
    if (tid < 2) sch[tid] = chlist[tile * 2 + tid];
    int lab = slabel[tile >> 1];
    __syncthreads();

    int lane = tid & 63, wid = tid >> 6; // wid = p-quarter (48 p each)
    int fr = lane & 15, g8 = lane >> 4;

    int srow = tid >> 2, sseg = tid & 3; // srow 0..63
    size_t zb = (size_t)sch[srow >> 5] * KBL_ + (size_t)(srow & 31) * LH_;
    const ushort* wbase = WF2 + (size_t)(lab * PRED_) * 1024;

    f32x4 acc[4][3];
#pragma unroll
    for (int m = 0; m < 4; ++m)
#pragma unroll
        for (int n = 0; n < 3; ++n) acc[m][n] = (f32x4){0.f, 0.f, 0.f, 0.f};

    uint4 pz, pw0, pw1, pw2;
    auto stage_load = [&](int t) {
        const ushort* zsrc = (t < 16) ? zLF : zUF;
        int ko = ((t & 15) * 32) + sseg * 8;
        pz  = *(const uint4*)(zsrc + zb + ko);
        int kw = t * 32 + sseg * 8;
        pw0 = *(const uint4*)(wbase + (size_t)srow * 1024 + kw);
        pw1 = *(const uint4*)(wbase + (size_t)(srow + 64) * 1024 + kw);
        pw2 = *(const uint4*)(wbase + (size_t)(srow + 128) * 1024 + kw);
    };
    auto stage_write = [&]() {
        *(uint4*)&ZT[srow][sseg * 8] = pz;
        *(uint4*)&WT[srow][sseg * 8] = pw0;
        *(uint4*)&WT[srow + 64][sseg * 8] = pw1;
        *(uint4*)&WT[srow + 128][sseg * 8] = pw2;
    };

    stage_load(0);
    for (int t = 0; t < 32; ++t) {
        __syncthreads();
        stage_write();
        __syncthreads();
        if (t + 1 < 32) stage_load(t + 1);

        f16x8 a[4];
#pragma unroll
        for (int m = 0; m < 4; ++m)
            a[m] = *(const f16x8*)&ZT[m * 16 + fr][g8 * 8];
#pragma unroll
        for (int nf = 0; nf < 3; ++nf) {
            f16x8 bv = *(const f16x8*)&WT[wid * 48 + nf * 16 + fr][g8 * 8];
#pragma unroll
            for (int m = 0; m < 4; ++m)
                acc[m][nf] = __builtin_amdgcn_mfma_f32_16x16x32_f16(a[m], bv, acc[m][nf], 0, 0, 0);
        }
    }

#pragma unroll
    for (int m = 0; m < 4; ++m) {
#pragma unroll
        for (int q = 0; q < 4; ++q) {
            int sb = m * 16 + g8 * 4 + q;
            int sl = sb >> 5, b = sb & 31;
            int n = sch[sl];
            float sd = sstdT[n * B_ + b], mu = meanT[n * B_ + b];
            size_t obase = ((size_t)(tile * 2 + sl) * B_ + b) * PRED_;
#pragma unroll
            for (int nf = 0; nf < 3; ++nf) {
                int p = wid * 48 + nf * 16 + fr;
                float v = acc[m][nf][q] + bg[lab * PRED_ + p] + bu[p];
                outP[obase + p] = v * sd + mu;
            }
        }
    }
}

// ---------------- K7: unpermute outP -> out[b][p][n] ------------------------
__global__ __launch_bounds__(256) void k7_unperm(const float* __restrict__ outP,
                                                 const int* __restrict__ chpos,
                                                 float* __restrict__ out) {
    int n = blockIdx.x * 256 + threadIdx.x;
    int p0 = blockIdx.y * 32;
    int b = blockIdx.z;
    if (n >= CH_) return;
    const float* src = outP + ((size_t)chpos[n] * B_ + b) * PRED_ + p0;
    float4 v[8];
#pragma unroll
    for (int j = 0; j < 8; ++j) v[j] = *(const float4*)(src + j * 4);
#pragma unroll
    for (int j = 0; j < 8; ++j) {
#pragma unroll
        for (int e = 0; e < 4; ++e) {
            int p = p0 + j * 4 + e;
            out[((size_t)b * PRED_ + p) * CH_ + n] = ((const float*)&v[j])[e];
        }
    }
}

extern "C" void kernel_launch(void* const* d_in, const int* in_sizes, int n_in,
                              void* d_out, int out_size, void* d_ws, size_t ws_size,
                              hipStream_t stream) {
    const float* x  = (const float*)d_in[0];
    const float* Wg = (const float*)d_in[4];
    const float* bg = (const float*)d_in[5];
    const float* Wu = (const float*)d_in[6];
    const float* bu = (const float*)d_in[7];
    float* out = (float*)d_out;
    (void)in_sizes; (void)n_in; (void)out_size; (void)ws_size;

    char* ws = (char*)d_ws;
    size_t off = 0;
    auto alloc = [&](size_t bytes) {
        void* p = ws + off;
        off = (off + bytes + 255) & ~(size_t)255;
        return p;
    };
    ushort* zLF  = (ushort*)alloc((size_t)16384000 * 2);
    ushort* zUF  = (ushort*)alloc((size_t)16384000 * 2);
    float*  G    = (float*)alloc((size_t)1000000 * 4);
    ushort* WF2  = (ushort*)alloc((size_t)576 * 1024 * 2);
    float*  meanT = (float*)alloc((size_t)32000 * 4);
    float*  sstdT = (float*)alloc((size_t)32000 * 4);
    float*  invT  = (float*)alloc((size_t)32000 * 4);
    float*  pS   = (float*)alloc((size_t)SEG_ * B_ * CH_ * 4);
    float*  pSS  = (float*)alloc((size_t)SEG_ * B_ * CH_ * 4);
    float*  sbuf = (float*)alloc((size_t)2 * 3 * CH_ * 4);
    int*    chlist = (int*)alloc((size_t)SLOTS_ * 4);
    int*    chpos  = (int*)alloc((size_t)1024 * 4);
    int*    slabel = (int*)alloc((size_t)256 * 4);
    // union region: Gp (16*36*16384*4 = 37.7 MB, dead after k3b) then outP (24.9 MB)
    char* unionBase = (char*)alloc((size_t)ZSPLIT_ * NTRI_ * 16384 * 4);
    float* Gp   = (float*)unionBase;
    float* outP = (float*)unionBase;

    k1_partial<<<dim3(SEG_, 32), 256, 0, stream>>>(x, pS, pSS);
    k1b_reduce<<<125, 256, 0, stream>>>(pS, pSS, meanT, sstdT, invT);
    k2_build<<<dim3(32, 16, 32), 256, 0, stream>>>(x, meanT, invT, zLF, zUF);
    k0_wprep<<<576, 256, 0, stream>>>(Wg, Wu, WF2);
    k3_mfma<<<8 * NTRI_ * 2, 256, 0, stream>>>(zLF, Gp);
    k3b_sym<<<dim3(NTRI_, 4), 256, 0, stream>>>(Gp, G);
    void* args[] = { (void*)&G, (void*)&sbuf, (void*)&chlist, (void*)&chpos, (void*)&slabel };
    hipLaunchCooperativeKernel((void*)k4_kmeans, dim3(16), dim3(1024), args, 0, stream);
    k5_grouped<<<NT2_, 256, 0, stream>>>(zLF, zUF, WF2, chlist, slabel,
                                         bg, bu, meanT, sstdT, outP);
    k7_unperm<<<dim3(4, 6, 32), 256, 0, stream>>>(outP, chpos, out);
}

// Round 10
// 199.387 us; speedup vs baseline: 11.8053x; 1.0743x over previous
//
#include <hip/hip_runtime.h>
#include <hip/hip_bf16.h>
#include <hip/hip_cooperative_groups.h>

namespace cg = cooperative_groups;

#define B_   32
#define L_   1024
#define LH_  512
#define CH_  1000
#define PRED_ 192
#define ITERS_ 50
#define KBL_ 16384   // B_*LH_
#define SLOTS_ 1012
#define NTILES_ 253
#define NT2_ 506     // 2-slot tiles for k5
#define NTRI_ 36     // upper-triangle 8x8 tile pairs
#define SEG_ 16      // L-segments for stats partials
#define KMB_ 32      // k-means blocks
#define KMP_ 32      // points per k-means block

typedef __attribute__((ext_vector_type(8))) _Float16 f16x8;
typedef __attribute__((ext_vector_type(4))) float f32x4;

__device__ inline ushort f2h(float x) {
    union { _Float16 h; ushort u; } c;
    c.h = (_Float16)x;
    return c.u;
}

// ---------------- K1a: partial sums over 64-row segments --------------------
__global__ __launch_bounds__(256) void k1_partial(const float* __restrict__ x,
                                                  float* __restrict__ pS,
                                                  float* __restrict__ pSS) {
    int seg = blockIdx.x;        // 0..15
    int b = blockIdx.y;          // 0..31
    int t = threadIdx.x;
    if (t >= 250) return;
    int c4 = t * 4;
    const float* xp = x + (size_t)b * L_ * CH_ + (size_t)seg * 64 * CH_ + c4;
    float4 s = {0.f, 0.f, 0.f, 0.f}, ss = {0.f, 0.f, 0.f, 0.f};
#pragma unroll 4
    for (int l = 0; l < 64; ++l) {
        float4 v = *(const float4*)(xp + (size_t)l * CH_);
        s.x += v.x; s.y += v.y; s.z += v.z; s.w += v.w;
        ss.x += v.x * v.x; ss.y += v.y * v.y; ss.z += v.z * v.z; ss.w += v.w * v.w;
    }
    size_t o = ((size_t)seg * B_ + b) * CH_ + c4;
    *(float4*)(pS + o) = s;
    *(float4*)(pSS + o) = ss;
}

// ---------------- K1b+K0w merged: stats reduce (blocks 0..124) + weight pack
__global__ __launch_bounds__(256) void k1b_wprep(const float* __restrict__ pS,
                                                 const float* __restrict__ pSS,
                                                 float* __restrict__ meanT,
                                                 float* __restrict__ sstdT,
                                                 float* __restrict__ invT,
                                                 const float* __restrict__ Wg,
                                                 const float* __restrict__ Wu,
                                                 ushort* __restrict__ WF2) {
    int bx = blockIdx.x;
    int tid = threadIdx.x;
    if (bx < 125) {
        int idx = bx * 256 + tid;
        if (idx >= B_ * CH_) return;
        int c = idx % CH_;
        int b = idx / CH_;
        float s = 0.f, ss = 0.f;
#pragma unroll
        for (int seg = 0; seg < SEG_; ++seg) {
            size_t o = ((size_t)seg * B_ + b) * CH_ + c;
            s += pS[o];
            ss += pSS[o];
        }
        float m = s * (1.0f / L_);
        float var = (ss - (float)L_ * m * m) * (1.0f / (L_ - 1)) + 1e-5f;
        float sd = sqrtf(var);
        meanT[c * B_ + b] = m;
        sstdT[c * B_ + b] = sd;
        invT[c * B_ + b] = 1.0f / sd;
    } else {
        int r = bx - 125;            // 0..575 = lab*192+p
        int p = r % PRED_;
#pragma unroll
        for (int i = 0; i < 4; ++i) {
            int k = i * 256 + tid;   // 0..1023
            float w = (k < 512) ? Wg[(size_t)r * LH_ + k]
                                : Wu[(size_t)p * LH_ + (k - 512)];
            WF2[(size_t)r * 1024 + k] = f2h(w);
        }
    }
}

// ---------------- K2: build fp16 z_L + z_U in [n][b][lh] layout -------------
__global__ __launch_bounds__(256) void k2_build(const float* __restrict__ x,
                                                const float* __restrict__ meanT,
                                                const float* __restrict__ invT,
                                                ushort* __restrict__ zLF,
                                                ushort* __restrict__ zUF) {
    __shared__ float Ls[32][33];
    __shared__ float Us[32][33];
    int tid = threadIdx.x;
    int tx = tid & 31, ty = tid >> 5;
    int n0 = blockIdx.x * 32;
    int lh0 = blockIdx.y * 32;
    int b = blockIdx.z;
    int n = n0 + tx;
    float m = 0.f, iv = 0.f;
    if (n < CH_) { m = meanT[n * B_ + b]; iv = invT[n * B_ + b]; }
    for (int r = 0; r < 4; ++r) {
        int lh = lh0 + ty + 8 * r;
        float v0 = 0.f, v1 = 0.f;
        if (n < CH_) {
            v0 = x[((size_t)b * L_ + 2 * lh) * CH_ + n];
            v1 = x[((size_t)b * L_ + 2 * lh + 1) * CH_ + n];
        }
        float a = (v0 - m) * iv * 0.5f;
        float c2 = (v1 - m) * iv * 0.5f;
        Ls[ty + 8 * r][tx] = a + c2;
        Us[ty + 8 * r][tx] = a - c2;
    }
    __syncthreads();
    for (int r = 0; r < 4; ++r) {
        int nl = ty + 8 * r;
        int nn = n0 + nl;
        if (nn < CH_) {
            size_t dst = (size_t)nn * KBL_ + (size_t)b * LH_ + lh0 + tx;
            zLF[dst] = f2h(Ls[tx][nl]);
            zUF[dst] = f2h(Us[tx][nl]);
        }
    }
}

// ---------------- K3: symmetric Gram via fp16 MFMA (single-pass) ------------
#define ZSPLIT_ 16
#define KSEG_   1024
#define NT_     (KSEG_ / 32)

__global__ __launch_bounds__(256) void k3_mfma(const ushort* __restrict__ zF,
                                               float* __restrict__ gpart) {
    __shared__ __align__(16) ushort AH[128][40];
    __shared__ __align__(16) ushort BH[128][40];

    int bid = blockIdx.x;
    int xcd = bid & 7, w = bid >> 3;           // w in 0..71
    int ksl = 2 * xcd + (w >= NTRI_);
    int t = (w >= NTRI_) ? w - NTRI_ : w;
    int ti = 0, tt = t;
    while (tt >= 8 - ti) { tt -= 8 - ti; ++ti; }
    int tj = ti + tt;
    int i0 = ti * 128, j0 = tj * 128;
    int kb = ksl * KSEG_;

    int tid = threadIdx.x;
    int lane = tid & 63;
    int wid = tid >> 6;
    int wr = wid >> 1, wc = wid & 1;
    int fr = lane & 15;
    int g8 = lane >> 4;

    f32x4 acc[4][4];
#pragma unroll
    for (int m = 0; m < 4; ++m)
#pragma unroll
        for (int n = 0; n < 4; ++n) acc[m][n] = (f32x4){0.f, 0.f, 0.f, 0.f};

    int srow = tid >> 2;
    int sseg = tid & 3;

    uint4 pv[4];
    auto stage_load = [&](int kt) {
        int k0 = kb + kt * 32;
#pragma unroll
        for (int s = 0; s < 4; ++s) {
            int tile = s >> 1, rep = s & 1;
            int row = srow + rep * 64;
            int grow = ((tile == 0) ? i0 : j0) + row;
            uint4 v = {0u, 0u, 0u, 0u};
            if (grow < CH_)
                v = *(const uint4*)(zF + (size_t)grow * KBL_ + k0 + sseg * 8);
            pv[s] = v;
        }
    };
    auto stage_write = [&]() {
#pragma unroll
        for (int s = 0; s < 4; ++s) {
            int tile = s >> 1, rep = s & 1;
            int row = srow + rep * 64;
            ushort* dst = (tile == 0) ? &AH[row][sseg * 8] : &BH[row][sseg * 8];
            *(uint4*)dst = pv[s];
        }
    };

    stage_load(0);
    for (int t2 = 0; t2 < NT_; ++t2) {
        __syncthreads();
        stage_write();
        __syncthreads();
        if (t2 + 1 < NT_) stage_load(t2 + 1);

        f16x8 a[4];
#pragma unroll
        for (int m = 0; m < 4; ++m)
            a[m] = *(const f16x8*)&AH[wr * 64 + m * 16 + fr][g8 * 8];
#pragma unroll
        for (int n = 0; n < 4; ++n) {
            f16x8 bv = *(const f16x8*)&BH[wc * 64 + n * 16 + fr][g8 * 8];
#pragma unroll
            for (int m = 0; m < 4; ++m)
                acc[m][n] = __builtin_amdgcn_mfma_f32_16x16x32_f16(a[m], bv, acc[m][n], 0, 0, 0);
        }
    }

    float* gp = gpart + ((size_t)ksl * NTRI_ + t) * 16384;
#pragma unroll
    for (int m = 0; m < 4; ++m) {
        int rb = wr * 64 + m * 16 + g8 * 4;
#pragma unroll
        for (int n = 0; n < 4; ++n) {
            int c = wc * 64 + n * 16 + fr;
#pragma unroll
            for (int q = 0; q < 4; ++q)
                gp[(size_t)(rb + q) * 128 + c] = acc[m][n][q];
        }
    }
}

// ---------------- K3b: reduce 16 partials per tile, write G + mirror --------
__global__ __launch_bounds__(256) void k3b_sym(const float* __restrict__ gpart,
                                               float* __restrict__ g) {
    int t = blockIdx.x;          // 0..35
    int seg = blockIdx.y;        // 0..3
    int ti = 0, tt = t;
    while (tt >= 8 - ti) { tt -= 8 - ti; ++ti; }
    int tj = ti + tt;
    int i0 = ti * 128, j0 = tj * 128;
    int tid = threadIdx.x;
    int e0 = seg * 4096 + tid * 16;
    int r = e0 >> 7, c0 = e0 & 127;

    float4 s[4];
#pragma unroll
    for (int j = 0; j < 4; ++j) s[j] = (float4){0.f, 0.f, 0.f, 0.f};
#pragma unroll
    for (int p = 0; p < ZSPLIT_; ++p) {
        const float* src = gpart + ((size_t)p * NTRI_ + t) * 16384 + e0;
#pragma unroll
        for (int j = 0; j < 4; ++j) {
            float4 v = *(const float4*)(src + j * 4);
            s[j].x += v.x; s[j].y += v.y; s[j].z += v.z; s[j].w += v.w;
        }
    }
    int i = i0 + r;
    if (i < CH_) {
#pragma unroll
        for (int j = 0; j < 4; ++j) {
            int jc = j0 + c0 + j * 4;
            if (jc + 3 < CH_) {
                *(float4*)(g + (size_t)i * CH_ + jc) = s[j];
            } else {
#pragma unroll
                for (int e = 0; e < 4; ++e)
                    if (jc + e < CH_) g[(size_t)i * CH_ + jc + e] = ((const float*)&s[j])[e];
            }
        }
        if (ti != tj) {
#pragma unroll
            for (int j = 0; j < 4; ++j) {
#pragma unroll
                for (int e = 0; e < 4; ++e) {
                    int jc = j0 + c0 + j * 4 + e;
                    if (jc < CH_) g[(size_t)jc * CH_ + i] = ((const float*)&s[j])[e];
                }
            }
        }
    }
}

// ---------------- K4: cooperative k-means, G rows LDS-cached ----------------
// 32 blocks x 1024 threads, 32 points/block; each block preloads its 32
// G-rows (125 KB) into LDS once. Every block redundantly computes all 1000
// labels; one grid.sync per iteration. t-update now 32 lanes/point (summation
// order change is ulp-level; labels survived fp16-G perturbation ~1e-3, so
// 1e-7 reorder noise cannot flip them). Block 0 emits the permutation.
__global__ __launch_bounds__(1024) void k4_kmeans(const float* __restrict__ g,
                                                  float* __restrict__ sbuf,
                                                  int* __restrict__ chlist,
                                                  int* __restrict__ chpos,
                                                  int* __restrict__ slabel) {
    cg::grid_group grid = cg::this_grid();
    __shared__ float gl[KMP_ * CH_];     // 125 KB: this block's 32 G rows
    __shared__ int   lab[1024];
    __shared__ float wred[16][3];
    __shared__ float ccS[3];
    __shared__ float ccPrev[3];
    __shared__ int   cntPrev[3];
    __shared__ int   cnt2[3];
    __shared__ int   chgS;
    __shared__ int   st[4], c2r[3];

    int tid = threadIdx.x;
    int wv = tid >> 6, ln64 = tid & 63;
    int bpt0 = blockIdx.x * KMP_;

    // preload own G rows into LDS (contiguous rows -> coalesced float4)
    {
        int nrow = CH_ - bpt0;
        if (nrow > KMP_) nrow = KMP_;
        if (nrow < 0) nrow = 0;
        int nf4 = nrow * (CH_ / 4);
        const float4* gsrc = (const float4*)(g + (size_t)bpt0 * CH_);
        float4* gdst = (float4*)gl;
        for (int i = tid; i < nf4; i += 1024) gdst[i] = gsrc[i];
    }

    int lbp = (tid < 3) ? tid : 3;      // sentinel 3 = unassigned
    lab[tid] = lbp;
    if (tid < 3) {
        cntPrev[tid] = 1;
        ccPrev[tid] = g[(size_t)tid * CH_ + tid];
    }
    __syncthreads();

    int par = 0;
    for (int it = 1; it <= ITERS_ + 1; ++it) {
        const float* sp = sbuf + par * 3 * CH_;
        // own point's s-values (iter 1 reads straight from G columns)
        float s0 = 0.f, s1 = 0.f, s2 = 0.f;
        if (tid < CH_) {
            if (it == 1) {
                const float* gr = g + (size_t)tid * CH_;
                s0 = gr[0]; s1 = gr[1]; s2 = gr[2];
            } else {
                s0 = sp[tid * 3 + 0]; s1 = sp[tid * 3 + 1]; s2 = sp[tid * 3 + 2];
            }
        }
        // ---- phase A: cc_k = (sum_{lab==k} s_k) / n_k, wave-shuffle reduce -
        float c0 = (lbp == 0) ? s0 : 0.f;
        float c1 = (lbp == 1) ? s1 : 0.f;
        float c2 = (lbp == 2) ? s2 : 0.f;
#pragma unroll
        for (int m = 1; m < 64; m <<= 1) {
            c0 += __shfl_xor(c0, m);
            c1 += __shfl_xor(c1, m);
            c2 += __shfl_xor(c2, m);
        }
        if (ln64 == 0) { wred[wv][0] = c0; wred[wv][1] = c1; wred[wv][2] = c2; }
        if (tid == 0) { cnt2[0] = 0; cnt2[1] = 0; cnt2[2] = 0; chgS = 0; }
        __syncthreads();
        if (tid < 3) {
            float sacc = 0.f;
#pragma unroll
            for (int w2 = 0; w2 < 16; ++w2) sacc += wred[w2][tid];
            int n = cntPrev[tid];
            float cc = (n > 0) ? sacc / (float)n : ccPrev[tid];
            ccS[tid] = cc;
            ccPrev[tid] = cc;
        }
        __syncthreads();
        float cc0 = ccS[0], cc1 = ccS[1], cc2 = ccS[2];

        // ---- phase B: assign + ballot counts ----
        int nl = lbp;
        if (tid < CH_) {
            float d0 = cc0 - 2.f * s0;
            float d1 = cc1 - 2.f * s1;
            float d2 = cc2 - 2.f * s2;
            nl = 0; float dm = d0;
            if (d1 < dm) { dm = d1; nl = 1; }
            if (d2 < dm) { dm = d2; nl = 2; }
        }
        bool act = (tid < CH_);
        unsigned long long b0 = __ballot(act && nl == 0);
        unsigned long long b1 = __ballot(act && nl == 1);
        unsigned long long b2 = __ballot(act && nl == 2);
        unsigned long long bc = __ballot(act && nl != lbp);
        if (ln64 == 0) {
            if (b0) atomicAdd(&cnt2[0], (int)__popcll(b0));
            if (b1) atomicAdd(&cnt2[1], (int)__popcll(b1));
            if (b2) atomicAdd(&cnt2[2], (int)__popcll(b2));
            if (bc) atomicAdd(&chgS, (int)__popcll(bc));
        }
        lab[tid] = nl;
        lbp = nl;
        __syncthreads();

        if (it == ITERS_ + 1) break;           // 51st (final) assign done
        if (chgS == 0 && it > 1) break;        // converged: labels stable

        // ---- phase C: t-update for own 32 points from LDS-cached G --------
        int n0n = cnt2[0], n1n = cnt2[1], n2n = cnt2[2];
        float* sq = sbuf + (par ^ 1) * 3 * CH_;
        int pl = tid >> 5;
        int ln = tid & 31;
        int i = bpt0 + pl;
        if (i < CH_) {
            const float* gr = gl + pl * CH_;
            float a0 = 0.f, a1 = 0.f, a2 = 0.f;
            for (int j = ln; j < CH_; j += 32) {
                float gv = gr[j];
                int lb = lab[j];
                a0 += (lb == 0) ? gv : 0.f;
                a1 += (lb == 1) ? gv : 0.f;
                a2 += (lb == 2) ? gv : 0.f;
            }
#pragma unroll
            for (int msk = 1; msk < 32; msk <<= 1) {
                a0 += __shfl_xor(a0, msk, 32);
                a1 += __shfl_xor(a1, msk, 32);
                a2 += __shfl_xor(a2, msk, 32);
            }
            if (ln == 0) {
                float f0, f1, f2;
                if (it == 1) { f0 = gr[0]; f1 = gr[1]; f2 = gr[2]; }
                else { f0 = sp[i * 3 + 0]; f1 = sp[i * 3 + 1]; f2 = sp[i * 3 + 2]; }
                sq[i * 3 + 0] = (n0n > 0) ? a0 / (float)n0n : f0;
                sq[i * 3 + 1] = (n1n > 0) ? a1 / (float)n1n : f1;
                sq[i * 3 + 2] = (n2n > 0) ? a2 / (float)n2n : f2;
            }
        }
        if (tid < 3) cntPrev[tid] = cnt2[tid];
        par ^= 1;
        grid.sync();
    }

    // ---- block 0: build label-sorted channel permutation ----
    if (blockIdx.x == 0) {
        if (tid == 0) {
            st[0] = 0;
            st[1] = ((cnt2[0] + 3) >> 2) << 2;
            st[2] = st[1] + (((cnt2[1] + 3) >> 2) << 2);
            st[3] = st[2] + (((cnt2[2] + 3) >> 2) << 2);
            c2r[0] = 0; c2r[1] = 0; c2r[2] = 0;
        }
        __syncthreads();
        if (tid < SLOTS_) chlist[tid] = 0;
        if (tid < NTILES_) {
            int s = tid * 4;
            slabel[tid] = (s < st[1]) ? 0 : (s < st[2]) ? 1 : (s < st[3]) ? 2 : 0;
        }
        __syncthreads();
        if (tid < CH_) {
            int lb = lab[tid];
            int r = atomicAdd(&c2r[lb], 1);
            int slot = st[lb] + r;
            chlist[slot] = tid;
            chpos[tid] = slot;
        }
    }
}

// ---------------- K5: grouped GEMM  C[64 sb][192 p] = Z_tile . WF2[lab]^T ---
__global__ __launch_bounds__(256) void k5_grouped(const ushort* __restrict__ zLF,
                                                  const ushort* __restrict__ zUF,
                                                  const ushort* __restrict__ WF2,
                                                  const int* __restrict__ chlist,
                                                  const int* __restrict__ slabel,
                                                  const float* __restrict__ bg,
                                                  const float* __restrict__ bu,
                                                  const float* __restrict__ meanT,
                                                  const float* __restrict__ sstdT,
                                                  float* __restrict__ outP) {
    __shared__ __align__(16) ushort ZT[64][40];
    __shared__ __align__(16) ushort WT[192][40];
    __shared__ int sch[2];

    int tile = blockIdx.x;               // 0..505
    int tid = threadIdx.x;
    if (tid < 2) sch[tid] = chlist[tile * 2 + tid];
    int lab = slabel[tile >> 1];
    __syncthreads();

    int lane = tid & 63, wid = tid >> 6; // wid = p-quarter (48 p each)
    int fr = lane & 15, g8 = lane >> 4;

    int srow = tid >> 2, sseg = tid & 3; // srow 0..63
    size_t zb = (size_t)sch[srow >> 5] * KBL_ + (size_t)(srow & 31) * LH_;
    const ushort* wbase = WF2 + (size_t)(lab * PRED_) * 1024;

    f32x4 acc[4][3];
#pragma unroll
    for (int m = 0; m < 4; ++m)
#pragma unroll
        for (int n = 0; n < 3; ++n) acc[m][n] = (f32x4){0.f, 0.f, 0.f, 0.f};

    uint4 pz, pw0, pw1, pw2;
    auto stage_load = [&](int t) {
        const ushort* zsrc = (t < 16) ? zLF : zUF;
        int ko = ((t & 15) * 32) + sseg * 8;
        pz  = *(const uint4*)(zsrc + zb + ko);
        int kw = t * 32 + sseg * 8;
        pw0 = *(const uint4*)(wbase + (size_t)srow * 1024 + kw);
        pw1 = *(const uint4*)(wbase + (size_t)(srow + 64) * 1024 + kw);
        pw2 = *(const uint4*)(wbase + (size_t)(srow + 128) * 1024 + kw);
    };
    auto stage_write = [&]() {
        *(uint4*)&ZT[srow][sseg * 8] = pz;
        *(uint4*)&WT[srow][sseg * 8] = pw0;
        *(uint4*)&WT[srow + 64][sseg * 8] = pw1;
        *(uint4*)&WT[srow + 128][sseg * 8] = pw2;
    };

    stage_load(0);
    for (int t = 0; t < 32; ++t) {
        __syncthreads();
        stage_write();
        __syncthreads();
        if (t + 1 < 32) stage_load(t + 1);

        f16x8 a[4];
#pragma unroll
        for (int m = 0; m < 4; ++m)
            a[m] = *(const f16x8*)&ZT[m * 16 + fr][g8 * 8];
#pragma unroll
        for (int nf = 0; nf < 3; ++nf) {
            f16x8 bv = *(const f16x8*)&WT[wid * 48 + nf * 16 + fr][g8 * 8];
#pragma unroll
            for (int m = 0; m < 4; ++m)
                acc[m][nf] = __builtin_amdgcn_mfma_f32_16x16x32_f16(a[m], bv, acc[m][nf], 0, 0, 0);
        }
    }

#pragma unroll
    for (int m = 0; m < 4; ++m) {
#pragma unroll
        for (int q = 0; q < 4; ++q) {
            int sb = m * 16 + g8 * 4 + q;
            int sl = sb >> 5, b = sb & 31;
            int n = sch[sl];
            float sd = sstdT[n * B_ + b], mu = meanT[n * B_ + b];
            size_t obase = ((size_t)(tile * 2 + sl) * B_ + b) * PRED_;
#pragma unroll
            for (int nf = 0; nf < 3; ++nf) {
                int p = wid * 48 + nf * 16 + fr;
                float v = acc[m][nf][q] + bg[lab * PRED_ + p] + bu[p];
                outP[obase + p] = v * sd + mu;
            }
        }
    }
}

// ---------------- K7: unpermute outP -> out[b][p][n] ------------------------
__global__ __launch_bounds__(256) void k7_unperm(const float* __restrict__ outP,
                                                 const int* __restrict__ chpos,
                                                 float* __restrict__ out) {
    int n = blockIdx.x * 256 + threadIdx.x;
    int p0 = blockIdx.y * 32;
    int b = blockIdx.z;
    if (n >= CH_) return;
    const float* src = outP + ((size_t)chpos[n] * B_ + b) * PRED_ + p0;
    float4 v[8];
#pragma unroll
    for (int j = 0; j < 8; ++j) v[j] = *(const float4*)(src + j * 4);
#pragma unroll
    for (int j = 0; j < 8; ++j) {
#pragma unroll
        for (int e = 0; e < 4; ++e) {
            int p = p0 + j * 4 + e;
            out[((size_t)b * PRED_ + p) * CH_ + n] = ((const float*)&v[j])[e];
        }
    }
}

extern "C" void kernel_launch(void* const* d_in, const int* in_sizes, int n_in,
                              void* d_out, int out_size, void* d_ws, size_t ws_size,
                              hipStream_t stream) {
    const float* x  = (const float*)d_in[0];
    const float* Wg = (const float*)d_in[4];
    const float* bg = (const float*)d_in[5];
    const float* Wu = (const float*)d_in[6];
    const float* bu = (const float*)d_in[7];
    float* out = (float*)d_out;
    (void)in_sizes; (void)n_in; (void)out_size; (void)ws_size;

    char* ws = (char*)d_ws;
    size_t off = 0;
    auto alloc = [&](size_t bytes) {
        void* p = ws + off;
        off = (off + bytes + 255) & ~(size_t)255;
        return p;
    };
    ushort* zLF  = (ushort*)alloc((size_t)16384000 * 2);
    ushort* zUF  = (ushort*)alloc((size_t)16384000 * 2);
    float*  G    = (float*)alloc((size_t)1000000 * 4);
    ushort* WF2  = (ushort*)alloc((size_t)576 * 1024 * 2);
    float*  meanT = (float*)alloc((size_t)32000 * 4);
    float*  sstdT = (float*)alloc((size_t)32000 * 4);
    float*  invT  = (float*)alloc((size_t)32000 * 4);
    float*  pS   = (float*)alloc((size_t)SEG_ * B_ * CH_ * 4);
    float*  pSS  = (float*)alloc((size_t)SEG_ * B_ * CH_ * 4);
    float*  sbuf = (float*)alloc((size_t)2 * 3 * CH_ * 4);
    int*    chlist = (int*)alloc((size_t)SLOTS_ * 4);
    int*    chpos  = (int*)alloc((size_t)1024 * 4);
    int*    slabel = (int*)alloc((size_t)256 * 4);
    // union region: Gp (16*36*16384*4 = 37.7 MB, dead after k3b) then outP (24.9 MB)
    char* unionBase = (char*)alloc((size_t)ZSPLIT_ * NTRI_ * 16384 * 4);
    float* Gp   = (float*)unionBase;
    float* outP = (float*)unionBase;

    k1_partial<<<dim3(SEG_, 32), 256, 0, stream>>>(x, pS, pSS);
    k1b_wprep<<<125 + 576, 256, 0, stream>>>(pS, pSS, meanT, sstdT, invT, Wg, Wu, WF2);
    k2_build<<<dim3(32, 16, 32), 256, 0, stream>>>(x, meanT, invT, zLF, zUF);
    k3_mfma<<<8 * NTRI_ * 2, 256, 0, stream>>>(zLF, Gp);
    k3b_sym<<<dim3(NTRI_, 4), 256, 0, stream>>>(Gp, G);
    void* args[] = { (void*)&G, (void*)&sbuf, (void*)&chlist, (void*)&chpos, (void*)&slabel };
    hipLaunchCooperativeKernel((void*)k4_kmeans, dim3(KMB_), dim3(1024), args, 0, stream);
    k5_grouped<<<NT2_, 256, 0, stream>>>(zLF, zUF, WF2, chlist, slabel,
                                         bg, bu, meanT, sstdT, outP);
    k7_unperm<<<dim3(4, 6, 32), 256, 0, stream>>>(outP, chpos, out);
}